// Round 12
// baseline (1342.771 us; speedup 1.0000x reference)
//
#include <hip/hip_runtime.h>
#include <hip/hip_bf16.h>

// ---------------------------------------------------------------------------
// IEGMN layer, MI355X round-20: edge GEMM1 factored through per-node
// projections. Hs[n]=h[n]@W1[0:256], Hd[n]=h[n]@W1[256:512] computed once
// (hproj); per-edge GEMM1 becomes gather-add(Hs[src]+Hd[dst]) + ONE MFMA
// K-step over [ef|rbf|0] @ W1tail. Per-block MFMA 264->136, W1 weight
// stream eliminated. Everything else identical to round-19.
// ---------------------------------------------------------------------------

#define N_LIG   4096
#define N_REC   16384
#define E_LIG_N 65536
#define E_REC_N 262144
#define HD      256
#define ORIGD   64
#define EFD     16
#define NSIG    15
#define EIN     543      // 2*HD + EFD + NSIG
#define XP      552      // edge sX pitch (bf16 elems), 544 used
#define XPN     584      // node sX pitch, 576 used
#define XPP     264      // proj sX pitch, 256 used
#define FP      264      // fp32 msg-dump pitch inside sX (floats)
#define FPH     276      // fp32 gather-sum pitch inside sX (floats) = XP/2

typedef __bf16 bf16x8 __attribute__((ext_vector_type(8)));
typedef float  f32x4  __attribute__((ext_vector_type(4)));

__device__ __forceinline__ float lrelu(float x) { return x > 0.f ? x : 0.01f * x; }
__device__ __forceinline__ unsigned short f2bu(float f) {
    __hip_bfloat16 h = __float2bfloat16(f);
    return *reinterpret_cast<unsigned short*>(&h);
}

// Direct global->LDS async copy, 16B per lane.
__device__ __forceinline__ void glds16(const void* g, void* l) {
    __builtin_amdgcn_global_load_lds(
        (const __attribute__((address_space(1))) void*)g,
        (__attribute__((address_space(3))) void*)l,
        16, 0, 0);
}

// Stage 16KB (one 32-key K or V tile) into LDS with 512 threads: 2 glds/thr.
__device__ __forceinline__ void stage_tile(
    const __hip_bfloat16* g, unsigned short* l, int wave, int lane)
{
    #pragma unroll
    for (int i = 0; i < 2; ++i) {
        const __hip_bfloat16* gp = g + (size_t)(i * 512 + wave * 64 + lane) * 8;
        unsigned short* lp = l + (i * 512 + wave * 64) * 8;  // wave-uniform base
        glds16(gp, lp);
    }
}

// ---------------------------------------------------------------------------
// Shared 32xKx256 GEMM core. Even/odd depth-2 pipeline (r19, proven).
__device__ __forceinline__ void mfma_gemm(
    const unsigned short* sA, int pitch,
    const __hip_bfloat16* Wswz, int KS, int lane, f32x4 acc[2][4])
{
    const int col = lane & 15, quad = lane >> 4;
    const unsigned short* a0p = sA + (size_t)col * pitch + quad * 8;
    const unsigned short* a1p = sA + (size_t)(16 + col) * pitch + quad * 8;
    const __hip_bfloat16* wp = Wswz + lane * 8;

    bf16x8 bE[4], bO[4], aE0, aE1, aO0, aO1;
    #pragma unroll
    for (int nt = 0; nt < 4; ++nt) {
        bE[nt] = *reinterpret_cast<const bf16x8*>(wp + (size_t)nt * KS * 512);
        bO[nt] = *reinterpret_cast<const bf16x8*>(wp + ((size_t)nt * KS + 1) * 512);
    }
    aE0 = *reinterpret_cast<const bf16x8*>(a0p);
    aE1 = *reinterpret_cast<const bf16x8*>(a1p);
    aO0 = *reinterpret_cast<const bf16x8*>(a0p + 32);
    aO1 = *reinterpret_cast<const bf16x8*>(a1p + 32);

    int ks = 0;
    for (; ks + 2 <= KS; ks += 2) {
        #pragma unroll
        for (int nt = 0; nt < 4; ++nt) {
            acc[0][nt] = __builtin_amdgcn_mfma_f32_16x16x32_bf16(aE0, bE[nt], acc[0][nt], 0, 0, 0);
            acc[1][nt] = __builtin_amdgcn_mfma_f32_16x16x32_bf16(aE1, bE[nt], acc[1][nt], 0, 0, 0);
        }
        if (ks + 2 < KS) {
            #pragma unroll
            for (int nt = 0; nt < 4; ++nt)
                bE[nt] = *reinterpret_cast<const bf16x8*>(
                    wp + ((size_t)nt * KS + ks + 2) * 512);
            aE0 = *reinterpret_cast<const bf16x8*>(a0p + (ks + 2) * 32);
            aE1 = *reinterpret_cast<const bf16x8*>(a1p + (ks + 2) * 32);
        }
        #pragma unroll
        for (int nt = 0; nt < 4; ++nt) {
            acc[0][nt] = __builtin_amdgcn_mfma_f32_16x16x32_bf16(aO0, bO[nt], acc[0][nt], 0, 0, 0);
            acc[1][nt] = __builtin_amdgcn_mfma_f32_16x16x32_bf16(aO1, bO[nt], acc[1][nt], 0, 0, 0);
        }
        if (ks + 3 < KS) {
            #pragma unroll
            for (int nt = 0; nt < 4; ++nt)
                bO[nt] = *reinterpret_cast<const bf16x8*>(
                    wp + ((size_t)nt * KS + ks + 3) * 512);
            aO0 = *reinterpret_cast<const bf16x8*>(a0p + (ks + 3) * 32);
            aO1 = *reinterpret_cast<const bf16x8*>(a1p + (ks + 3) * 32);
        }
    }
    if (ks < KS) {   // odd-KS tail (even slot)
        #pragma unroll
        for (int nt = 0; nt < 4; ++nt) {
            acc[0][nt] = __builtin_amdgcn_mfma_f32_16x16x32_bf16(aE0, bE[nt], acc[0][nt], 0, 0, 0);
            acc[1][nt] = __builtin_amdgcn_mfma_f32_16x16x32_bf16(aE1, bE[nt], acc[1][nt], 0, 0, 0);
        }
    }
}

// ---------------------------------------------------------------------------
__global__ void zero_kernel(float* __restrict__ p, int n) {
    int i = blockIdx.x * 256 + threadIdx.x;
    if (i < n) p[i] = 0.f;
}

// ---------------------------------------------------------------------------
// fp32 -> bf16 blob, 8 elems/thread (vectorized).
__global__ void f2b_kernel(const float* __restrict__ src,
                           __hip_bfloat16* __restrict__ dst, int n8) {
    const int i = blockIdx.x * 256 + threadIdx.x;
    if (i >= n8) return;
    const float4 a = *reinterpret_cast<const float4*>(src + (size_t)i * 8);
    const float4 b = *reinterpret_cast<const float4*>(src + (size_t)i * 8 + 4);
    ushort4 u0 = { f2bu(a.x), f2bu(a.y), f2bu(a.z), f2bu(a.w) };
    ushort4 u1 = { f2bu(b.x), f2bu(b.y), f2bu(b.z), f2bu(b.w) };
    unsigned short* d = (unsigned short*)dst + (size_t)i * 8;
    *reinterpret_cast<ushort4*>(d)     = u0;
    *reinterpret_cast<ushort4*>(d + 4) = u1;
}

// ---------------------------------------------------------------------------
// CSR build: histogram -> scan -> scatter (dst-sorted edge permutation).
__global__ void hist_kernel(const int* __restrict__ dst, int* __restrict__ hist, int n) {
    int i = blockIdx.x * 256 + threadIdx.x;
    if (i < n) atomicAdd(&hist[dst[i]], 1);
}

__global__ __launch_bounds__(256) void scan_kernel(
    const int* __restrict__ hist, int* __restrict__ cur,
    float* __restrict__ cntf, int n)
{
    __shared__ int part[256];
    const int tid = threadIdx.x;
    const int per = n >> 8;            // n is 4096 or 16384
    const int base = tid * per;
    int s = 0;
    for (int i = 0; i < per; ++i) s += hist[base + i];
    part[tid] = s;
    __syncthreads();
    #pragma unroll
    for (int off = 1; off < 256; off <<= 1) {
        int v = (tid >= off) ? part[tid - off] : 0;
        __syncthreads();
        part[tid] += v;
        __syncthreads();
    }
    int run = part[tid] - s;           // exclusive prefix of this chunk
    for (int i = 0; i < per; ++i) {
        const int h = hist[base + i];
        cur[base + i]  = run;
        cntf[base + i] = (float)h;
        run += h;
    }
}

__global__ void scatter_kernel(const int* __restrict__ dst, int* __restrict__ cur,
                               int* __restrict__ elist, int n) {
    int i = blockIdx.x * 256 + threadIdx.x;
    if (i < n) { int p = atomicAdd(&cur[dst[i]], 1); elist[p] = i; }
}

// ---------------------------------------------------------------------------
__global__ void wt_swz(const float* __restrict__ src,
                       __hip_bfloat16* __restrict__ dst, int K, int KS) {
    const int g  = blockIdx.x / KS;
    const int ks = blockIdx.x % KS;
    for (int i = threadIdx.x; i < 512; i += 256) {
        const int lane = i >> 3, j = i & 7;
        const int n = g * 16 + (lane & 15);
        const int k = ks * 32 + (lane >> 4) * 8 + j;
        const float v = (k < K) ? src[(size_t)k * 256 + n] : 0.f;
        dst[((size_t)(g * KS + ks) * 64 + lane) * 8 + j] = __float2bfloat16(v);
    }
}

// ---------------------------------------------------------------------------
// Per-node projections: HS[n]=h[n]@Wsrc, HDp[n]=h[n]@Wdst (fp32 out).
__global__ __launch_bounds__(256, 4) void hproj(
    const __hip_bfloat16* __restrict__ Xb,
    const __hip_bfloat16* __restrict__ Wsrc, const __hip_bfloat16* __restrict__ Wdst,
    float* __restrict__ HS, float* __restrict__ HDp)
{
    __shared__ unsigned short sXp[32][XPP];
    const int tid  = threadIdx.x;
    const int lane = tid & 63;
    const int wave = tid >> 6;
    const int col  = lane & 15;
    const int quad = lane >> 4;
    const int r0   = blockIdx.x * 32;

    for (int i = tid; i < 32 * 32; i += 256) {
        const int row = i >> 5, c = i & 31;
        *reinterpret_cast<uint4*>(&sXp[row][c * 8]) =
            *reinterpret_cast<const uint4*>(&Xb[(size_t)(r0 + row) * HD + c * 8]);
    }
    __syncthreads();

    f32x4 acc[2][4];
    #pragma unroll
    for (int p = 0; p < 2; ++p) {
        const __hip_bfloat16* Ws = (p == 0) ? Wsrc : Wdst;
        float* outp = (p == 0) ? HS : HDp;
        #pragma unroll
        for (int nt = 0; nt < 4; ++nt) {
            acc[0][nt] = { 0.f, 0.f, 0.f, 0.f };
            acc[1][nt] = { 0.f, 0.f, 0.f, 0.f };
        }
        mfma_gemm(&sXp[0][0], XPP, Ws + (size_t)(wave * 4) * 8 * 512, 8, lane, acc);
        #pragma unroll
        for (int mt = 0; mt < 2; ++mt)
            #pragma unroll
            for (int nt = 0; nt < 4; ++nt)
                #pragma unroll
                for (int r = 0; r < 4; ++r)
                    outp[(size_t)(r0 + mt * 16 + quad * 4 + r) * HD +
                         wave * 64 + nt * 16 + col] = acc[mt][nt][r];
    }
}

// ---------------------------------------------------------------------------
// Edge MFMA kernel: 32 edges/block, dst-sorted order (elist).
// GEMM1 = gather-add of per-node projections + ONE tail MFMA K-step.
__global__ __launch_bounds__(256, 4) void edge_mfma(
    const float* __restrict__ coords,
    const float* __restrict__ hs, const float* __restrict__ hd,
    const __hip_bfloat16* __restrict__ efb,
    const int* __restrict__ src, const int* __restrict__ dst,
    const int* __restrict__ elist,
    const __hip_bfloat16* __restrict__ W1t, const float* __restrict__ b1,
    const __hip_bfloat16* __restrict__ W2s, const float* __restrict__ b2,
    const __hip_bfloat16* __restrict__ Wc1s, const float* __restrict__ bc1,
    const float* __restrict__ wc2v, const float* __restrict__ bc2,
    float* __restrict__ aggr, float* __restrict__ xsum)
{
    __shared__ unsigned short sX[32][XP];     // fp32 gather view / bf16 stages
    __shared__ unsigned short sT[32][40];     // tail [ef(16)|rbf(15)|0]
    __shared__ float sXrel[32][3];
    __shared__ int   sDst[32];
    __shared__ int   sSrc[32];
    __shared__ int   sE[32];
    __shared__ float sRedW[4][32];
    __shared__ float sPv[32];

    const int tid  = threadIdx.x;
    const int lane = tid & 63;
    const int wave = tid >> 6;
    const int col  = lane & 15;
    const int quad = lane >> 4;
    const int e0   = blockIdx.x * 32;

    // ---- edge meta: permuted id, endpoints, x_rel, RBF (into tail) ----
    if (tid < 32) {
        const int e = elist[e0 + tid];
        const int s = src[e], d = dst[e];
        sE[tid] = e; sSrc[tid] = s; sDst[tid] = d;
        float d2 = 0.f;
        #pragma unroll
        for (int c = 0; c < 3; ++c) {
            const float xr = coords[s * 3 + c] - coords[d * 3 + c];
            sXrel[tid][c] = xr;
            d2 += xr * xr;
        }
        float sig = 1.0f;
        #pragma unroll
        for (int si = 0; si < NSIG; ++si) {
            sT[tid][16 + si] = f2bu(__expf(-d2 / sig));
            sig *= 1.5f;
        }
        sT[tid][31] = 0;
    }
    __syncthreads();

    // ---- gather-add projections: sXf[row][c] = Hs[src][c] + Hd[dst][c] ----
    float* sXf = reinterpret_cast<float*>(&sX[0][0]);   // pitch FPH floats
    for (int i = tid; i < 32 * 64; i += 256) {
        const int row = i >> 6, c4 = i & 63;
        const float4 a = *reinterpret_cast<const float4*>(
            &hs[(size_t)sSrc[row] * HD + c4 * 4]);
        const float4 b = *reinterpret_cast<const float4*>(
            &hd[(size_t)sDst[row] * HD + c4 * 4]);
        float4 sum;
        sum.x = a.x + b.x; sum.y = a.y + b.y;
        sum.z = a.z + b.z; sum.w = a.w + b.w;
        *reinterpret_cast<float4*>(&sXf[row * FPH + c4 * 4]) = sum;
    }
    // ---- gather edge features (bf16, permuted rows) into tail ----
    if (tid < 64) {
        const int row = tid >> 1, hh = tid & 1;
        *reinterpret_cast<uint4*>(&sT[row][hh * 8]) =
            *reinterpret_cast<const uint4*>(&efb[(size_t)sE[row] * EFD + hh * 8]);
    }
    __syncthreads();

    f32x4 acc[2][4];
    f32x4 macc[2][4];   // message accumulators, survive the coords GEMM

    // ---- GEMM1': acc = b1 + (Hs+Hd) frag + [ef|rbf] @ W1tail (1 K-step) ----
    #pragma unroll
    for (int nt = 0; nt < 4; ++nt) {
        const float bv = b1[wave * 64 + nt * 16 + col];
        acc[0][nt] = { bv, bv, bv, bv };
        acc[1][nt] = { bv, bv, bv, bv };
    }
    #pragma unroll
    for (int mt = 0; mt < 2; ++mt)
        #pragma unroll
        for (int nt = 0; nt < 4; ++nt)
            #pragma unroll
            for (int r = 0; r < 4; ++r)
                acc[mt][nt][r] +=
                    sXf[(mt * 16 + quad * 4 + r) * FPH + wave * 64 + nt * 16 + col];
    {
        const bf16x8 aT0 = *reinterpret_cast<const bf16x8*>(&sT[col][quad * 8]);
        const bf16x8 aT1 = *reinterpret_cast<const bf16x8*>(&sT[16 + col][quad * 8]);
        #pragma unroll
        for (int nt = 0; nt < 4; ++nt) {
            const bf16x8 bT = *reinterpret_cast<const bf16x8*>(
                W1t + (size_t)(wave * 4 + nt) * 512 + lane * 8);
            acc[0][nt] = __builtin_amdgcn_mfma_f32_16x16x32_bf16(aT0, bT, acc[0][nt], 0, 0, 0);
            acc[1][nt] = __builtin_amdgcn_mfma_f32_16x16x32_bf16(aT1, bT, acc[1][nt], 0, 0, 0);
        }
    }
    __syncthreads();
    #pragma unroll
    for (int mt = 0; mt < 2; ++mt)
        #pragma unroll
        for (int nt = 0; nt < 4; ++nt)
            #pragma unroll
            for (int r = 0; r < 4; ++r)
                sX[mt * 16 + quad * 4 + r][wave * 64 + nt * 16 + col] =
                    f2bu(lrelu(acc[mt][nt][r]));
    __syncthreads();

    // ---- GEMM2: hidden @ W2 -> msg (kept fp32 in macc) ----
    #pragma unroll
    for (int nt = 0; nt < 4; ++nt) {
        const float bv = b2[wave * 64 + nt * 16 + col];
        macc[0][nt] = { bv, bv, bv, bv };
        macc[1][nt] = { bv, bv, bv, bv };
    }
    mfma_gemm(&sX[0][0], XP, W2s + (size_t)(wave * 4) * 8 * 512, 8, lane, macc);
    __syncthreads();
    #pragma unroll
    for (int mt = 0; mt < 2; ++mt)
        #pragma unroll
        for (int nt = 0; nt < 4; ++nt)
            #pragma unroll
            for (int r = 0; r < 4; ++r)
                sX[mt * 16 + quad * 4 + r][wave * 64 + nt * 16 + col] =
                    f2bu(macc[mt][nt][r]);
    __syncthreads();

    // ---- GEMM3: msg @ Wc1 -> lrelu -> dot wc2 (per-edge scalar p) ----
    #pragma unroll
    for (int nt = 0; nt < 4; ++nt) {
        const float bv = bc1[wave * 64 + nt * 16 + col];
        acc[0][nt] = { bv, bv, bv, bv };
        acc[1][nt] = { bv, bv, bv, bv };
    }
    mfma_gemm(&sX[0][0], XP, Wc1s + (size_t)(wave * 4) * 8 * 512, 8, lane, acc);
    float w2l[4];
    #pragma unroll
    for (int nt = 0; nt < 4; ++nt) w2l[nt] = wc2v[wave * 64 + nt * 16 + col];
    #pragma unroll
    for (int mt = 0; mt < 2; ++mt) {
        float pr[4] = { 0.f, 0.f, 0.f, 0.f };
        #pragma unroll
        for (int nt = 0; nt < 4; ++nt)
            #pragma unroll
            for (int r = 0; r < 4; ++r)
                pr[r] += lrelu(acc[mt][nt][r]) * w2l[nt];
        #pragma unroll
        for (int r = 0; r < 4; ++r) {
            #pragma unroll
            for (int off = 1; off < 16; off <<= 1) pr[r] += __shfl_xor(pr[r], off);
        }
        if (col == 0)
            #pragma unroll
            for (int r = 0; r < 4; ++r)
                sRedW[wave][mt * 16 + quad * 4 + r] = pr[r];
    }
    __syncthreads();

    // ---- dump fp32 messages into LDS (reuse sX), gather p per edge ----
    float* sF = reinterpret_cast<float*>(&sX[0][0]);   // [32][FP] floats
    #pragma unroll
    for (int mt = 0; mt < 2; ++mt)
        #pragma unroll
        for (int nt = 0; nt < 4; ++nt)
            #pragma unroll
            for (int r = 0; r < 4; ++r)
                sF[(mt * 16 + quad * 4 + r) * FP + wave * 64 + nt * 16 + col] =
                    macc[mt][nt][r];
    if (tid < 32)
        sPv[tid] = sRedW[0][tid] + sRedW[1][tid] + sRedW[2][tid] + sRedW[3][tid]
                 + bc2[0];
    __syncthreads();

    // ---- segmented flush: one atomic per (distinct dst x column) ----
    {
        const int c = tid;               // 256 threads = 256 columns
        float av = 0.f;
        int dprev = sDst[0];
        for (int row = 0; row < 32; ++row) {
            const int d = sDst[row];     // uniform across block -> no divergence
            if (d != dprev) {
                atomicAdd(&aggr[(size_t)dprev * HD + c], av);
                av = 0.f; dprev = d;
            }
            av += sF[row * FP + c];
        }
        atomicAdd(&aggr[(size_t)dprev * HD + c], av);
    }
    if (tid < 3) {
        const int c = tid;
        float av = 0.f;
        int dprev = sDst[0];
        for (int row = 0; row < 32; ++row) {
            const int d = sDst[row];
            if (d != dprev) {
                atomicAdd(&xsum[(size_t)dprev * 3 + c], av);
                av = 0.f; dprev = d;
            }
            av += sXrel[row][c] * sPv[row];
        }
        atomicAdd(&xsum[(size_t)dprev * 3 + c], av);
    }
}

// ---------------------------------------------------------------------------
// Node MFMA kernel: 32 nodes/block (unchanged).
__global__ __launch_bounds__(256, 4) void node_mfma(
    const float* __restrict__ aggr, const float* __restrict__ cnt,
    const __hip_bfloat16* __restrict__ cross, const float* __restrict__ orig,
    const float* __restrict__ hfeat,
    const __hip_bfloat16* __restrict__ WN1s, const float* __restrict__ b1,
    const __hip_bfloat16* __restrict__ WN2s, const float* __restrict__ b2,
    float* __restrict__ out)
{
    __shared__ unsigned short sXn[32][XPN];
    __shared__ float sInv[32];

    const int tid  = threadIdx.x;
    const int lane = tid & 63;
    const int wave = tid >> 6;
    const int col  = lane & 15;
    const int quad = lane >> 4;
    const int r0   = blockIdx.x * 32;

    if (tid < 32) sInv[tid] = 1.f / fmaxf(cnt[r0 + tid], 1.f);
    __syncthreads();

    for (int i = tid; i < 32 * 64; i += 256) {
        const int row = i >> 6, c4 = i & 63;
        const float inv = sInv[row];
        const float4 v = *reinterpret_cast<const float4*>(
            &aggr[(size_t)(r0 + row) * HD + c4 * 4]);
        ushort4 u = { f2bu(v.x * inv), f2bu(v.y * inv), f2bu(v.z * inv), f2bu(v.w * inv) };
        *reinterpret_cast<ushort4*>(&sXn[row][c4 * 4]) = u;
    }
    for (int i = tid; i < 32 * 64; i += 256) {
        const int row = i >> 6, c4 = i & 63;
        const ushort4 u = *reinterpret_cast<const ushort4*>(
            &cross[(size_t)(r0 + row) * HD + c4 * 4]);
        *reinterpret_cast<ushort4*>(&sXn[row][256 + c4 * 4]) = u;
    }
    for (int i = tid; i < 32 * 16; i += 256) {
        const int row = i >> 4, c4 = i & 15;
        const float4 v = *reinterpret_cast<const float4*>(
            &orig[(size_t)(r0 + row) * ORIGD + c4 * 4]);
        ushort4 u = { f2bu(v.x), f2bu(v.y), f2bu(v.z), f2bu(v.w) };
        *reinterpret_cast<ushort4*>(&sXn[row][512 + c4 * 4]) = u;
    }
    __syncthreads();

    f32x4 acc[2][4];

    #pragma unroll
    for (int nt = 0; nt < 4; ++nt) {
        const float bv = b1[wave * 64 + nt * 16 + col];
        acc[0][nt] = { bv, bv, bv, bv };
        acc[1][nt] = { bv, bv, bv, bv };
    }
    mfma_gemm(&sXn[0][0], XPN, WN1s + (size_t)(wave * 4) * 18 * 512, 18, lane, acc);
    __syncthreads();
    #pragma unroll
    for (int mt = 0; mt < 2; ++mt)
        #pragma unroll
        for (int nt = 0; nt < 4; ++nt)
            #pragma unroll
            for (int r = 0; r < 4; ++r)
                sXn[mt * 16 + quad * 4 + r][wave * 64 + nt * 16 + col] =
                    f2bu(lrelu(acc[mt][nt][r]));
    __syncthreads();

    #pragma unroll
    for (int nt = 0; nt < 4; ++nt) {
        const float bv = b2[wave * 64 + nt * 16 + col];
        acc[0][nt] = { bv, bv, bv, bv };
        acc[1][nt] = { bv, bv, bv, bv };
    }
    mfma_gemm(&sXn[0][0], XPN, WN2s + (size_t)(wave * 4) * 8 * 512, 8, lane, acc);
    #pragma unroll
    for (int mt = 0; mt < 2; ++mt)
        #pragma unroll
        for (int nt = 0; nt < 4; ++nt)
            #pragma unroll
            for (int r = 0; r < 4; ++r) {
                const int g = r0 + mt * 16 + quad * 4 + r;
                const int n = wave * 64 + nt * 16 + col;
                out[(size_t)g * HD + n] =
                    0.5f * acc[mt][nt][r] + 0.5f * hfeat[(size_t)g * HD + n];
            }
}

// ---------------------------------------------------------------------------
// Fused Q/K/V projection: stage X once, run 3 GEMMs from the same LDS tile.
// K/V written directly in fragment-blob order (r19, proven).
__global__ __launch_bounds__(256, 4) void qkv_proj(
    const __hip_bfloat16* __restrict__ Xb,
    const __hip_bfloat16* __restrict__ Wq, const __hip_bfloat16* __restrict__ Wk,
    const __hip_bfloat16* __restrict__ Wv,
    __hip_bfloat16* __restrict__ Q, __hip_bfloat16* __restrict__ Kz,
    __hip_bfloat16* __restrict__ Vz)
{
    __shared__ unsigned short sXp[32][XPP];
    const int tid  = threadIdx.x;
    const int lane = tid & 63;
    const int wave = tid >> 6;
    const int col  = lane & 15;
    const int quad = lane >> 4;
    const int r0   = blockIdx.x * 32;

    for (int i = tid; i < 32 * 32; i += 256) {
        const int row = i >> 5, c = i & 31;
        *reinterpret_cast<uint4*>(&sXp[row][c * 8]) =
            *reinterpret_cast<const uint4*>(&Xb[(size_t)(r0 + row) * HD + c * 8]);
    }
    __syncthreads();

    f32x4 acc[2][4];
    #pragma unroll
    for (int p = 0; p < 3; ++p) {
        const __hip_bfloat16* Ws = (p == 0) ? Wq : (p == 1) ? Wk : Wv;
        #pragma unroll
        for (int nt = 0; nt < 4; ++nt) {
            acc[0][nt] = { 0.f, 0.f, 0.f, 0.f };
            acc[1][nt] = { 0.f, 0.f, 0.f, 0.f };
        }
        mfma_gemm(&sXp[0][0], XPP, Ws + (size_t)(wave * 4) * 8 * 512, 8, lane, acc);
        #pragma unroll
        for (int mt = 0; mt < 2; ++mt)
            #pragma unroll
            for (int nt = 0; nt < 4; ++nt)
                #pragma unroll
                for (int r = 0; r < 4; ++r) {
                    float v = acc[mt][nt][r];
                    const int row = r0 + mt * 16 + quad * 4 + r;
                    const int c   = wave * 64 + nt * 16 + col;
                    if (p == 0) {
                        Q[(size_t)row * HD + c] = __float2bfloat16(lrelu(v));
                    } else if (p == 1) {
                        const int kt = row >> 4, rr = row & 15;
                        const int s  = c >> 5, cc8 = (c >> 3) & 3, j = c & 7;
                        Kz[(size_t)(kt * 8 + s) * 512 + (cc8 * 16 + rr) * 8 + j] =
                            __float2bfloat16(lrelu(v));
                    } else {
                        const int jt = row >> 5, rowin = row & 31;
                        const int dt = c >> 4, cc = c & 15;
                        Vz[((size_t)(jt * 16 + dt) * 64 + (rowin >> 3) * 16 + cc) * 8
                           + (rowin & 7)] = __float2bfloat16(v);
                    }
                }
    }
}

// ---------------------------------------------------------------------------
// Attention helpers (r14 structure, proven).
__device__ __forceinline__ void load_mask(
    const float* __restrict__ maskG, int transposed, int R0, int j0,
    int wave, int quad, int col, float mv[2][4])
{
    if (!transposed) {
        #pragma unroll
        for (int t = 0; t < 2; ++t)
            #pragma unroll
            for (int r = 0; r < 4; ++r)
                mv[t][r] = maskG[(size_t)(R0 + wave * 16 + quad * 4 + r) * N_REC
                                 + j0 + col + 16 * t];
    } else {
        #pragma unroll
        for (int t = 0; t < 2; ++t)
            #pragma unroll
            for (int r = 0; r < 4; ++r)
                mv[t][r] = maskG[(size_t)(j0 + col + 16 * t) * N_REC
                                 + R0 + wave * 16 + quad * 4 + r];
    }
}

__device__ __forceinline__ void attn_tile(
    const unsigned short* sK, const unsigned short* sV,
    unsigned short (*sPw)[40], const bf16x8 qf[8], const float mv[2][4],
    int lane, int col, int quad, f32x4 o[16], float m[4], float l[4])
{
    // ---- S = Q K^T ----
    f32x4 sacc[2];
    sacc[0][0]=0.f; sacc[0][1]=0.f; sacc[0][2]=0.f; sacc[0][3]=0.f;
    sacc[1][0]=0.f; sacc[1][1]=0.f; sacc[1][2]=0.f; sacc[1][3]=0.f;
    #pragma unroll
    for (int t = 0; t < 2; ++t) {
        #pragma unroll
        for (int s = 0; s < 8; ++s) {
            bf16x8 kf = *reinterpret_cast<const bf16x8*>(
                &sK[(t * 8 + s) * 512 + lane * 8]);
            sacc[t] = __builtin_amdgcn_mfma_f32_16x16x32_bf16(qf[s], kf, sacc[t], 0, 0, 0);
        }
    }

    // ---- masked scores ----
    float a[2][4];
    #pragma unroll
    for (int t = 0; t < 2; ++t)
        #pragma unroll
        for (int r = 0; r < 4; ++r)
            a[t][r] = mv[t][r] * sacc[t][r] - 1000.f * (1.f - mv[t][r]);

    // ---- defer-max: rescale only when local max grows past m+8 ----
    float lm[4];
    #pragma unroll
    for (int r = 0; r < 4; ++r) lm[r] = fmaxf(a[0][r], a[1][r]);
    float w = lm[0] - m[0];
    #pragma unroll
    for (int r = 1; r < 4; ++r) w = fmaxf(w, lm[r] - m[r]);
    if (!__all(w <= 8.f)) {
        #pragma unroll
        for (int r = 0; r < 4; ++r) {
            float mx = lm[r];
            #pragma unroll
            for (int off = 1; off < 16; off <<= 1)
                mx = fmaxf(mx, __shfl_xor(mx, off));
            const float mn = fmaxf(m[r], mx);
            const float c  = __expf(m[r] - mn);
            m[r] = mn;
            l[r] *= c;
            #pragma unroll
            for (int dt = 0; dt < 16; ++dt) o[dt][r] *= c;
        }
    }

    // ---- P = exp(a - m), per-lane l partials ----
    #pragma unroll
    for (int r = 0; r < 4; ++r) {
        const float p0 = __expf(a[0][r] - m[r]);
        const float p1 = __expf(a[1][r] - m[r]);
        sPw[quad * 4 + r][col]      = f2bu(p0);
        sPw[quad * 4 + r][col + 16] = f2bu(p1);
        l[r] += p0 + p1;
    }

    // ---- O += P V ----
    bf16x8 pf = *reinterpret_cast<const bf16x8*>(&sPw[col][quad * 8]);
    #pragma unroll
    for (int dt = 0; dt < 16; ++dt) {
        bf16x8 vf = *reinterpret_cast<const bf16x8*>(&sV[dt * 512 + lane * 8]);
        o[dt] = __builtin_amdgcn_mfma_f32_16x16x32_bf16(pf, vf, o[dt], 0, 0, 0);
    }
}

// ---------------------------------------------------------------------------
// MFMA flash attention partial (r14 structure, proven).
__global__ __launch_bounds__(512) void attn_mfma(
    const __hip_bfloat16* __restrict__ Qb, const __hip_bfloat16* __restrict__ Kz,
    const __hip_bfloat16* __restrict__ Vz, const float* __restrict__ maskG,
    float* __restrict__ PO, float* __restrict__ PM, float* __restrict__ PL,
    int M, int chunkKeys, int transposed)
{
    __shared__ unsigned short sKb[2][8192];   // 2 x 16 KB
    __shared__ unsigned short sVb[2][8192];   // 2 x 16 KB
    __shared__ unsigned short sP[8][16][40];  // 10 KB

    const int tid  = threadIdx.x;
    const int lane = tid & 63;
    const int wave = tid >> 6;
    const int col  = lane & 15;
    const int quad = lane >> 4;
    const int R0   = blockIdx.x * 128;
    const int split = blockIdx.y;
    const int jbase = split * chunkKeys;

    bf16x8 qf[8];
    {
        const __hip_bfloat16* qp =
            Qb + (size_t)(R0 + wave * 16 + col) * HD + quad * 8;
        #pragma unroll
        for (int s = 0; s < 8; ++s)
            qf[s] = *reinterpret_cast<const bf16x8*>(qp + 32 * s);
    }

    f32x4 o[16];
    #pragma unroll
    for (int dt = 0; dt < 16; ++dt) { o[dt][0]=0.f; o[dt][1]=0.f; o[dt][2]=0.f; o[dt][3]=0.f; }
    float m[4], l[4];
    #pragma unroll
    for (int r = 0; r < 4; ++r) { m[r] = -INFINITY; l[r] = 0.f; }

    float mvA[2][4], mvB[2][4];

    // ---- prologue: tile 0 -> buf0 + mvA ----
    stage_tile(Kz + (size_t)jbase * 256, &sKb[0][0], wave, lane);
    stage_tile(Vz + (size_t)jbase * 256, &sVb[0][0], wave, lane);
    load_mask(maskG, transposed, R0, jbase, wave, quad, col, mvA);

    for (int jt = 0; jt < chunkKeys; jt += 64) {
        // ===== phase A: compute tile jt (buf0, mvA); stage jt+32 =====
        asm volatile("s_waitcnt vmcnt(0)" ::: "memory");
        __builtin_amdgcn_s_barrier();
        __builtin_amdgcn_sched_barrier(0);
        stage_tile(Kz + (size_t)(jbase + jt + 32) * 256, &sKb[1][0], wave, lane);
        stage_tile(Vz + (size_t)(jbase + jt + 32) * 256, &sVb[1][0], wave, lane);
        load_mask(maskG, transposed, R0, jbase + jt + 32, wave, quad, col, mvB);
        __builtin_amdgcn_sched_barrier(0);
        attn_tile(&sKb[0][0], &sVb[0][0], sP[wave], qf, mvA,
                  lane, col, quad, o, m, l);

        // ===== phase B: compute tile jt+32 (buf1, mvB); stage jt+64 =====
        asm volatile("s_waitcnt vmcnt(0)" ::: "memory");
        __builtin_amdgcn_s_barrier();
        __builtin_amdgcn_sched_barrier(0);
        if (jt + 64 < chunkKeys) {
            stage_tile(Kz + (size_t)(jbase + jt + 64) * 256, &sKb[0][0], wave, lane);
            stage_tile(Vz + (size_t)(jbase + jt + 64) * 256, &sVb[0][0], wave, lane);
            load_mask(maskG, transposed, R0, jbase + jt + 64, wave, quad, col, mvA);
        }
        __builtin_amdgcn_sched_barrier(0);
        attn_tile(&sKb[1][0], &sVb[1][0], sP[wave], qf, mvB,
                  lane, col, quad, o, m, l);
    }

    // ---- final l reduction (per-lane partials -> 16-lane row sums) ----
    #pragma unroll
    for (int r = 0; r < 4; ++r) {
        #pragma unroll
        for (int off = 1; off < 16; off <<= 1)
            l[r] += __shfl_xor(l[r], off);
    }

    #pragma unroll
    for (int dt = 0; dt < 16; ++dt)
        #pragma unroll
        for (int r = 0; r < 4; ++r) {
            const int row = R0 + wave * 16 + quad * 4 + r;
            PO[((size_t)split * M + row) * HD + dt * 16 + col] = o[dt][r];
        }
    if (col == 0) {
        #pragma unroll
        for (int r = 0; r < 4; ++r) {
            const int row = R0 + wave * 16 + quad * 4 + r;
            PM[(size_t)split * M + row] = m[r];
            PL[(size_t)split * M + row] = l[r];
        }
    }
}

// ---------------------------------------------------------------------------
__global__ void attn_combine(
    const float* __restrict__ PO, const float* __restrict__ PM,
    const float* __restrict__ PL, __hip_bfloat16* __restrict__ Out,
    int M, int nchunks)
{
    const int idx = blockIdx.x * 256 + threadIdx.x;
    const int row = idx >> 8;
    float mmax = -INFINITY;
    for (int c = 0; c < nchunks; ++c) mmax = fmaxf(mmax, PM[(size_t)c * M + row]);
    float denom = 0.f, acc = 0.f;
    for (int c = 0; c < nchunks; ++c) {
        const float w = __expf(PM[(size_t)c * M + row] - mmax);
        denom += PL[(size_t)c * M + row] * w;
        acc   += PO[(size_t)c * M * HD + idx] * w;
    }
    Out[idx] = __float2bfloat16(acc / denom);
}

// ---------------------------------------------------------------------------
__global__ void coords_fin(
    const float* __restrict__ coords, const float* __restrict__ origc,
    const float* __restrict__ xsum, const float* __restrict__ cnt,
    float* __restrict__ out, int n)
{
    const int i = blockIdx.x * 256 + threadIdx.x;
    if (i >= n * 3) return;
    const int node = i / 3;
    const float inv = 1.f / fmaxf(cnt[node], 1.f);
    out[i] = 0.25f * origc[i] + 0.75f * coords[i] + xsum[i] * inv;
}

// ---------------------------------------------------------------------------
extern "C" void kernel_launch(void* const* d_in, const int* in_sizes, int n_in,
                              void* d_out, int out_size, void* d_ws, size_t ws_size,
                              hipStream_t stream)
{
    const float* coords_lig = (const float*)d_in[0];
    const float* h_lig      = (const float*)d_in[1];
    const float* orig_lig   = (const float*)d_in[2];
    const float* origc_lig  = (const float*)d_in[3];
    const float* coords_rec = (const float*)d_in[4];
    const float* h_rec      = (const float*)d_in[5];
    const float* orig_rec   = (const float*)d_in[6];
    const float* origc_rec  = (const float*)d_in[7];
    const float* mask       = (const float*)d_in[8];
    const float* lig_ef     = (const float*)d_in[9];
    const float* rec_ef     = (const float*)d_in[10];
    const int* lig_src = (const int*)d_in[11];
    const int* lig_dst = (const int*)d_in[12];
    const int* rec_src = (const int*)d_in[13];
    const int* rec_dst = (const int*)d_in[14];
    const float* le_w1 = (const float*)d_in[15];
    const float* le_b1 = (const float*)d_in[16];
    const float* le_w2 = (const float*)d_in[17];
    const float* le_b2 = (const float*)d_in[18];
    const float* re_w1 = (const float*)d_in[19];
    const float* re_b1 = (const float*)d_in[20];
    const float* re_w2 = (const float*)d_in[21];
    const float* re_b2 = (const float*)d_in[22];
    const float* aql_w = (const float*)d_in[23];
    const float* akl_w = (const float*)d_in[24];
    const float* avl_w = (const float*)d_in[25];
    const float* aqr_w = (const float*)d_in[26];
    const float* akr_w = (const float*)d_in[27];
    const float* avr_w = (const float*)d_in[28];
    const float* nl_w1 = (const float*)d_in[29];
    const float* nl_b1 = (const float*)d_in[30];
    const float* nl_w2 = (const float*)d_in[31];
    const float* nl_b2 = (const float*)d_in[32];
    const float* nr_w1 = (const float*)d_in[33];
    const float* nr_b1 = (const float*)d_in[34];
    const float* nr_w2 = (const float*)d_in[35];
    const float* nr_b2 = (const float*)d_in[36];
    const float* cl_w1 = (const float*)d_in[37];
    const float* cl_b1 = (const float*)d_in[38];
    const float* cl_w2 = (const float*)d_in[39];
    const float* cl_b2 = (const float*)d_in[40];
    const float* cr_w1 = (const float*)d_in[41];
    const float* cr_b1 = (const float*)d_in[42];
    const float* cr_w2 = (const float*)d_in[43];
    const float* cr_b2 = (const float*)d_in[44];

    float* out = (float*)d_out;
    float* wsf = (float*)d_ws;

    // ---- fp32 accumulator + CSR + projection zone ----
    const size_t AGGRL = 0;
    const size_t AGGRR = AGGRL + (size_t)N_LIG * HD;
    const size_t CNTL  = AGGRR + (size_t)N_REC * HD;
    const size_t CNTR  = CNTL + N_LIG;
    const size_t XSUML = CNTR + N_REC;
    const size_t XSUMR = XSUML + (size_t)N_LIG * 3;
    const size_t HISTL = XSUMR + (size_t)N_REC * 3;
    const size_t CURL  = HISTL + N_LIG;
    const size_t HISTR = CURL + N_LIG;
    const size_t CURR  = HISTR + N_REC;
    const size_t ZEND  = CURR + N_REC;          // zeroed through here
    const size_t ELISTL = ZEND;                 // not zeroed
    const size_t ELISTR = ELISTL + E_LIG_N;
    const size_t HS_L   = ELISTR + E_REC_N;     // per-node projections (fp32)
    const size_t HD_L   = HS_L + (size_t)N_LIG * HD;
    const size_t HS_R   = HD_L + (size_t)N_LIG * HD;
    const size_t HD_R   = HS_R + (size_t)N_REC * HD;
    const size_t FEND   = HD_R + (size_t)N_REC * HD;

    // ---- bf16 zone ----
    __hip_bfloat16* wsb = (__hip_bfloat16*)(wsf + FEND);
    const size_t QL  = 0;
    const size_t KL  = QL + (size_t)N_LIG * HD;   // unused (kept for layout)
    const size_t VL  = KL + (size_t)N_LIG * HD;   // unused
    const size_t QR  = VL + (size_t)N_LIG * HD;
    const size_t KR  = QR + (size_t)N_REC * HD;   // unused
    const size_t VR  = KR + (size_t)N_REC * HD;   // unused
    const size_t CRL = VR + (size_t)N_REC * HD;
    const size_t CRR = CRL + (size_t)N_LIG * HD;
    const size_t KZL = CRR + (size_t)N_REC * HD;          // K swizzled lig
    const size_t VZL = KZL + (size_t)N_LIG * HD;          // V swizzled lig
    const size_t KZR = VZL + (size_t)N_LIG * HD;          // K swizzled rec
    const size_t VZR = KZR + (size_t)N_REC * HD;          // V swizzled rec
    const size_t KW256 = (size_t)16 * 8 * 512;
    const size_t KTAIL = (size_t)16 * 512;
    const size_t NW1SZ = (size_t)16 * 18 * 512;
    const size_t SW_ESL = VZR + (size_t)N_REC * HD;       // W1 src slice (lig)
    const size_t SW_EDL = SW_ESL + KW256;                 // W1 dst slice (lig)
    const size_t SW_ETL = SW_EDL + KW256;                 // W1 tail (lig)
    const size_t SW_EL2 = SW_ETL + KTAIL;
    const size_t SW_EC1 = SW_EL2 + KW256;
    const size_t SW_NL1 = SW_EC1 + KW256;
    const size_t SW_NL2 = SW_NL1 + NW1SZ;
    const size_t SW_ESR = SW_NL2 + KW256;                 // W1 src slice (rec)
    const size_t SW_EDR = SW_ESR + KW256;
    const size_t SW_ETR = SW_EDR + KW256;
    const size_t SW_ER2 = SW_ETR + KTAIL;
    const size_t SW_EC1R = SW_ER2 + KW256;
    const size_t SW_NR1 = SW_EC1R + KW256;
    const size_t SW_NR2 = SW_NR1 + NW1SZ;
    const size_t SW_PQL = SW_NR2 + KW256;
    const size_t SW_PKL = SW_PQL + KW256;
    const size_t SW_PVL = SW_PKL + KW256;
    const size_t SW_PQR = SW_PVL + KW256;
    const size_t SW_PKR = SW_PQR + KW256;
    const size_t SW_PVR = SW_PKR + KW256;
    // pre-converted bf16 operand blobs
    const size_t HB_L  = SW_PVR + KW256;
    const size_t HB_R  = HB_L + (size_t)N_LIG * HD;
    const size_t EFB_L = HB_R + (size_t)N_REC * HD;
    const size_t EFB_R = EFB_L + (size_t)E_LIG_N * EFD;
    const size_t BF_END = EFB_R + (size_t)E_REC_N * EFD;

    // ---- split-K partial zone (fp32), dynamic splits ----
    float* wsp = (float*)(wsb + ((BF_END + 1) & ~(size_t)1));
    const size_t baseBytes = (size_t)((char*)wsp - (char*)d_ws);
    int SL = 16, SR = 4;
    {
        const size_t poElems16 = (size_t)16 * N_LIG * HD;
        const size_t need16 = baseBytes +
            (poElems16 + 2 * (size_t)16 * N_LIG) * sizeof(float);
        if (ws_size < need16) { SL = 8; SR = 2; }
    }
    const size_t PO_ = 0;
    const size_t PM_ = PO_ + (size_t)SL * N_LIG * HD;
    const size_t PL_ = PM_ + (size_t)SL * N_LIG;

    const size_t O_XL = 0;
    const size_t O_HL = O_XL + (size_t)N_LIG * 3;
    const size_t O_XR = O_HL + (size_t)N_LIG * HD;
    const size_t O_HR = O_XR + (size_t)N_REC * 3;

    // 1) zero atomic accumulators + CSR hist/cursors
    zero_kernel<<<((int)ZEND + 255) / 256, 256, 0, stream>>>(wsf, (int)ZEND);

    // 1a) fp32 -> bf16 operand blobs (h and edge features)
    f2b_kernel<<<(N_LIG * HD / 8 + 255) / 256, 256, 0, stream>>>(
        h_lig, wsb + HB_L, N_LIG * HD / 8);
    f2b_kernel<<<(N_REC * HD / 8 + 255) / 256, 256, 0, stream>>>(
        h_rec, wsb + HB_R, N_REC * HD / 8);
    f2b_kernel<<<(E_LIG_N * EFD / 8 + 255) / 256, 256, 0, stream>>>(
        lig_ef, wsb + EFB_L, E_LIG_N * EFD / 8);
    f2b_kernel<<<(E_REC_N * EFD / 8 + 255) / 256, 256, 0, stream>>>(
        rec_ef, wsb + EFB_R, E_REC_N * EFD / 8);

    // 1b) CSR build: dst-sorted edge permutations (also produces fp32 counts)
    hist_kernel<<<E_LIG_N / 256, 256, 0, stream>>>(lig_dst, (int*)(wsf + HISTL), E_LIG_N);
    hist_kernel<<<E_REC_N / 256, 256, 0, stream>>>(rec_dst, (int*)(wsf + HISTR), E_REC_N);
    scan_kernel<<<1, 256, 0, stream>>>((int*)(wsf + HISTL), (int*)(wsf + CURL),
                                       wsf + CNTL, N_LIG);
    scan_kernel<<<1, 256, 0, stream>>>((int*)(wsf + HISTR), (int*)(wsf + CURR),
                                       wsf + CNTR, N_REC);
    scatter_kernel<<<E_LIG_N / 256, 256, 0, stream>>>(
        lig_dst, (int*)(wsf + CURL), (int*)(wsf + ELISTL), E_LIG_N);
    scatter_kernel<<<E_REC_N / 256, 256, 0, stream>>>(
        rec_dst, (int*)(wsf + CURR), (int*)(wsf + ELISTR), E_REC_N);

    // 2) weight swizzles (W1 split into src/dst/tail slices)
    wt_swz<<<16 * 8,  256, 0, stream>>>(le_w1,             wsb + SW_ESL, 256, 8);
    wt_swz<<<16 * 8,  256, 0, stream>>>(le_w1 + 256 * 256, wsb + SW_EDL, 256, 8);
    wt_swz<<<16 * 1,  256, 0, stream>>>(le_w1 + 512 * 256, wsb + SW_ETL, 31, 1);
    wt_swz<<<16 * 8,  256, 0, stream>>>(le_w2, wsb + SW_EL2, 256, 8);
    wt_swz<<<16 * 8,  256, 0, stream>>>(cl_w1, wsb + SW_EC1, 256, 8);
    wt_swz<<<16 * 18, 256, 0, stream>>>(nl_w1, wsb + SW_NL1, 576, 18);
    wt_swz<<<16 * 8,  256, 0, stream>>>(nl_w2, wsb + SW_NL2, 256, 8);
    wt_swz<<<16 * 8,  256, 0, stream>>>(re_w1,             wsb + SW_ESR, 256, 8);
    wt_swz<<<16 * 8,  256, 0, stream>>>(re_w1 + 256 * 256, wsb + SW_EDR, 256, 8);
    wt_swz<<<16 * 1,  256, 0, stream>>>(re_w1 + 512 * 256, wsb + SW_ETR, 31, 1);
    wt_swz<<<16 * 8,  256, 0, stream>>>(re_w2, wsb + SW_ER2, 256, 8);
    wt_swz<<<16 * 8,  256, 0, stream>>>(cr_w1, wsb + SW_EC1R, 256, 8);
    wt_swz<<<16 * 18, 256, 0, stream>>>(nr_w1, wsb + SW_NR1, 576, 18);
    wt_swz<<<16 * 8,  256, 0, stream>>>(nr_w2, wsb + SW_NR2, 256, 8);
    wt_swz<<<16 * 8,  256, 0, stream>>>(aql_w, wsb + SW_PQL, 256, 8);
    wt_swz<<<16 * 8,  256, 0, stream>>>(akl_w, wsb + SW_PKL, 256, 8);
    wt_swz<<<16 * 8,  256, 0, stream>>>(avl_w, wsb + SW_PVL, 256, 8);
    wt_swz<<<16 * 8,  256, 0, stream>>>(aqr_w, wsb + SW_PQR, 256, 8);
    wt_swz<<<16 * 8,  256, 0, stream>>>(akr_w, wsb + SW_PKR, 256, 8);
    wt_swz<<<16 * 8,  256, 0, stream>>>(avr_w, wsb + SW_PVR, 256, 8);

    // 2b) per-node W1 projections (fp32)
    hproj<<<N_LIG / 32, 256, 0, stream>>>(
        wsb + HB_L, wsb + SW_ESL, wsb + SW_EDL, wsf + HS_L, wsf + HD_L);
    hproj<<<N_REC / 32, 256, 0, stream>>>(
        wsb + HB_R, wsb + SW_ESR, wsb + SW_EDR, wsf + HS_R, wsf + HD_R);

    // 3) edge MFMA kernels (32 edges/block, dst-sorted, segmented atomics)
    edge_mfma<<<E_LIG_N / 32, 256, 0, stream>>>(
        coords_lig, wsf + HS_L, wsf + HD_L, wsb + EFB_L, lig_src, lig_dst,
        (const int*)(wsf + ELISTL),
        wsb + SW_ETL, le_b1, wsb + SW_EL2, le_b2, wsb + SW_EC1, cl_b1, cl_w2, cl_b2,
        wsf + AGGRL, wsf + XSUML);
    edge_mfma<<<E_REC_N / 32, 256, 0, stream>>>(
        coords_rec, wsf + HS_R, wsf + HD_R, wsb + EFB_R, rec_src, rec_dst,
        (const int*)(wsf + ELISTR),
        wsb + SW_ETR, re_b1, wsb + SW_ER2, re_b2, wsb + SW_EC1R, cr_b1, cr_w2, cr_b2,
        wsf + AGGRR, wsf + XSUMR);

    // 4) fused q/k/v projections (K/V written directly in fragment-blob order)
    qkv_proj<<<N_LIG / 32, 256, 0, stream>>>(
        wsb + HB_L, wsb + SW_PQL, wsb + SW_PKL, wsb + SW_PVL,
        wsb + QL, wsb + KZL, wsb + VZL);
    qkv_proj<<<N_REC / 32, 256, 0, stream>>>(
        wsb + HB_R, wsb + SW_PQR, wsb + SW_PKR, wsb + SW_PVR,
        wsb + QR, wsb + KZR, wsb + VZR);

    // 5) MFMA flash attention, split-K + combine
    {
        dim3 gl(N_LIG / 128, SL);
        attn_mfma<<<gl, 512, 0, stream>>>(wsb + QL, wsb + KZR, wsb + VZR, mask,
                                          wsp + PO_, wsp + PM_, wsp + PL_,
                                          N_LIG, N_REC / SL, 0);
        attn_combine<<<N_LIG, 256, 0, stream>>>(
            wsp + PO_, wsp + PM_, wsp + PL_, wsb + CRL, N_LIG, SL);

        dim3 gr(N_REC / 128, SR);
        attn_mfma<<<gr, 512, 0, stream>>>(wsb + QR, wsb + KZL, wsb + VZL, mask,
                                          wsp + PO_, wsp + PM_, wsp + PL_,
                                          N_REC, N_LIG / SR, 1);
        attn_combine<<<N_REC, 256, 0, stream>>>(
            wsp + PO_, wsp + PM_, wsp + PL_, wsb + CRR, N_REC, SR);
    }

    // 6) coordinate outputs
    coords_fin<<<(N_LIG * 3 + 255) / 256, 256, 0, stream>>>(
        coords_lig, origc_lig, wsf + XSUML, wsf + CNTL, out + O_XL, N_LIG);
    coords_fin<<<(N_REC * 3 + 255) / 256, 256, 0, stream>>>(
        coords_rec, origc_rec, wsf + XSUMR, wsf + CNTR, out + O_XR, N_REC);

    // 7) node MFMA kernels
    node_mfma<<<N_LIG / 32, 256, 0, stream>>>(
        wsf + AGGRL, wsf + CNTL, wsb + CRL, orig_lig, h_lig,
        wsb + SW_NL1, nl_b1, wsb + SW_NL2, nl_b2, out + O_HL);
    node_mfma<<<N_REC / 32, 256, 0, stream>>>(
        wsf + AGGRR, wsf + CNTR, wsb + CRR, orig_rec, h_rec,
        wsb + SW_NR1, nr_b1, wsb + SW_NR2, nr_b2, out + O_HR);

    (void)in_sizes; (void)n_in; (void)out_size;
}

// Round 13
// 1341.254 us; speedup vs baseline: 1.0011x; 1.0011x over previous
//
#include <hip/hip_runtime.h>
#include <hip/hip_bf16.h>

// ---------------------------------------------------------------------------
// IEGMN layer, MI355X round-21: round-20's factored edge GEMM1 kept, but
// HS/HD per-node projection buffers now ALIAS the split-K partial zone
// (consumed before attention writes PO; same-stream ordering guarantees
// safety). This restores SL=16/SR=4 attention splits that r20's static
// allocation accidentally demoted to 8/2 (the source of its regression).
// ---------------------------------------------------------------------------

#define N_LIG   4096
#define N_REC   16384
#define E_LIG_N 65536
#define E_REC_N 262144
#define HD      256
#define ORIGD   64
#define EFD     16
#define NSIG    15
#define EIN     543      // 2*HD + EFD + NSIG
#define XP      552      // edge sX pitch (bf16 elems), 544 used
#define XPN     584      // node sX pitch, 576 used
#define XPP     264      // proj sX pitch, 256 used
#define FP      264      // fp32 msg-dump pitch inside sX (floats)
#define FPH     276      // fp32 gather-sum pitch inside sX (floats) = XP/2

typedef __bf16 bf16x8 __attribute__((ext_vector_type(8)));
typedef float  f32x4  __attribute__((ext_vector_type(4)));

__device__ __forceinline__ float lrelu(float x) { return x > 0.f ? x : 0.01f * x; }
__device__ __forceinline__ unsigned short f2bu(float f) {
    __hip_bfloat16 h = __float2bfloat16(f);
    return *reinterpret_cast<unsigned short*>(&h);
}

// Direct global->LDS async copy, 16B per lane.
__device__ __forceinline__ void glds16(const void* g, void* l) {
    __builtin_amdgcn_global_load_lds(
        (const __attribute__((address_space(1))) void*)g,
        (__attribute__((address_space(3))) void*)l,
        16, 0, 0);
}

// Stage 16KB (one 32-key K or V tile) into LDS with 512 threads: 2 glds/thr.
__device__ __forceinline__ void stage_tile(
    const __hip_bfloat16* g, unsigned short* l, int wave, int lane)
{
    #pragma unroll
    for (int i = 0; i < 2; ++i) {
        const __hip_bfloat16* gp = g + (size_t)(i * 512 + wave * 64 + lane) * 8;
        unsigned short* lp = l + (i * 512 + wave * 64) * 8;  // wave-uniform base
        glds16(gp, lp);
    }
}

// ---------------------------------------------------------------------------
// Shared 32xKx256 GEMM core. Even/odd depth-2 pipeline (r19, proven).
__device__ __forceinline__ void mfma_gemm(
    const unsigned short* sA, int pitch,
    const __hip_bfloat16* Wswz, int KS, int lane, f32x4 acc[2][4])
{
    const int col = lane & 15, quad = lane >> 4;
    const unsigned short* a0p = sA + (size_t)col * pitch + quad * 8;
    const unsigned short* a1p = sA + (size_t)(16 + col) * pitch + quad * 8;
    const __hip_bfloat16* wp = Wswz + lane * 8;

    bf16x8 bE[4], bO[4], aE0, aE1, aO0, aO1;
    #pragma unroll
    for (int nt = 0; nt < 4; ++nt) {
        bE[nt] = *reinterpret_cast<const bf16x8*>(wp + (size_t)nt * KS * 512);
        bO[nt] = *reinterpret_cast<const bf16x8*>(wp + ((size_t)nt * KS + 1) * 512);
    }
    aE0 = *reinterpret_cast<const bf16x8*>(a0p);
    aE1 = *reinterpret_cast<const bf16x8*>(a1p);
    aO0 = *reinterpret_cast<const bf16x8*>(a0p + 32);
    aO1 = *reinterpret_cast<const bf16x8*>(a1p + 32);

    int ks = 0;
    for (; ks + 2 <= KS; ks += 2) {
        #pragma unroll
        for (int nt = 0; nt < 4; ++nt) {
            acc[0][nt] = __builtin_amdgcn_mfma_f32_16x16x32_bf16(aE0, bE[nt], acc[0][nt], 0, 0, 0);
            acc[1][nt] = __builtin_amdgcn_mfma_f32_16x16x32_bf16(aE1, bE[nt], acc[1][nt], 0, 0, 0);
        }
        if (ks + 2 < KS) {
            #pragma unroll
            for (int nt = 0; nt < 4; ++nt)
                bE[nt] = *reinterpret_cast<const bf16x8*>(
                    wp + ((size_t)nt * KS + ks + 2) * 512);
            aE0 = *reinterpret_cast<const bf16x8*>(a0p + (ks + 2) * 32);
            aE1 = *reinterpret_cast<const bf16x8*>(a1p + (ks + 2) * 32);
        }
        #pragma unroll
        for (int nt = 0; nt < 4; ++nt) {
            acc[0][nt] = __builtin_amdgcn_mfma_f32_16x16x32_bf16(aO0, bO[nt], acc[0][nt], 0, 0, 0);
            acc[1][nt] = __builtin_amdgcn_mfma_f32_16x16x32_bf16(aO1, bO[nt], acc[1][nt], 0, 0, 0);
        }
        if (ks + 3 < KS) {
            #pragma unroll
            for (int nt = 0; nt < 4; ++nt)
                bO[nt] = *reinterpret_cast<const bf16x8*>(
                    wp + ((size_t)nt * KS + ks + 3) * 512);
            aO0 = *reinterpret_cast<const bf16x8*>(a0p + (ks + 3) * 32);
            aO1 = *reinterpret_cast<const bf16x8*>(a1p + (ks + 3) * 32);
        }
    }
    if (ks < KS) {   // odd-KS tail (even slot)
        #pragma unroll
        for (int nt = 0; nt < 4; ++nt) {
            acc[0][nt] = __builtin_amdgcn_mfma_f32_16x16x32_bf16(aE0, bE[nt], acc[0][nt], 0, 0, 0);
            acc[1][nt] = __builtin_amdgcn_mfma_f32_16x16x32_bf16(aE1, bE[nt], acc[1][nt], 0, 0, 0);
        }
    }
}

// ---------------------------------------------------------------------------
__global__ void zero_kernel(float* __restrict__ p, int n) {
    int i = blockIdx.x * 256 + threadIdx.x;
    if (i < n) p[i] = 0.f;
}

// ---------------------------------------------------------------------------
// fp32 -> bf16 blob, 8 elems/thread (vectorized).
__global__ void f2b_kernel(const float* __restrict__ src,
                           __hip_bfloat16* __restrict__ dst, int n8) {
    const int i = blockIdx.x * 256 + threadIdx.x;
    if (i >= n8) return;
    const float4 a = *reinterpret_cast<const float4*>(src + (size_t)i * 8);
    const float4 b = *reinterpret_cast<const float4*>(src + (size_t)i * 8 + 4);
    ushort4 u0 = { f2bu(a.x), f2bu(a.y), f2bu(a.z), f2bu(a.w) };
    ushort4 u1 = { f2bu(b.x), f2bu(b.y), f2bu(b.z), f2bu(b.w) };
    unsigned short* d = (unsigned short*)dst + (size_t)i * 8;
    *reinterpret_cast<ushort4*>(d)     = u0;
    *reinterpret_cast<ushort4*>(d + 4) = u1;
}

// ---------------------------------------------------------------------------
// CSR build: histogram -> scan -> scatter (dst-sorted edge permutation).
__global__ void hist_kernel(const int* __restrict__ dst, int* __restrict__ hist, int n) {
    int i = blockIdx.x * 256 + threadIdx.x;
    if (i < n) atomicAdd(&hist[dst[i]], 1);
}

__global__ __launch_bounds__(256) void scan_kernel(
    const int* __restrict__ hist, int* __restrict__ cur,
    float* __restrict__ cntf, int n)
{
    __shared__ int part[256];
    const int tid = threadIdx.x;
    const int per = n >> 8;            // n is 4096 or 16384
    const int base = tid * per;
    int s = 0;
    for (int i = 0; i < per; ++i) s += hist[base + i];
    part[tid] = s;
    __syncthreads();
    #pragma unroll
    for (int off = 1; off < 256; off <<= 1) {
        int v = (tid >= off) ? part[tid - off] : 0;
        __syncthreads();
        part[tid] += v;
        __syncthreads();
    }
    int run = part[tid] - s;           // exclusive prefix of this chunk
    for (int i = 0; i < per; ++i) {
        const int h = hist[base + i];
        cur[base + i]  = run;
        cntf[base + i] = (float)h;
        run += h;
    }
}

__global__ void scatter_kernel(const int* __restrict__ dst, int* __restrict__ cur,
                               int* __restrict__ elist, int n) {
    int i = blockIdx.x * 256 + threadIdx.x;
    if (i < n) { int p = atomicAdd(&cur[dst[i]], 1); elist[p] = i; }
}

// ---------------------------------------------------------------------------
__global__ void wt_swz(const float* __restrict__ src,
                       __hip_bfloat16* __restrict__ dst, int K, int KS) {
    const int g  = blockIdx.x / KS;
    const int ks = blockIdx.x % KS;
    for (int i = threadIdx.x; i < 512; i += 256) {
        const int lane = i >> 3, j = i & 7;
        const int n = g * 16 + (lane & 15);
        const int k = ks * 32 + (lane >> 4) * 8 + j;
        const float v = (k < K) ? src[(size_t)k * 256 + n] : 0.f;
        dst[((size_t)(g * KS + ks) * 64 + lane) * 8 + j] = __float2bfloat16(v);
    }
}

// ---------------------------------------------------------------------------
// Per-node projections: HS[n]=h[n]@Wsrc, HDp[n]=h[n]@Wdst (fp32 out).
__global__ __launch_bounds__(256, 4) void hproj(
    const __hip_bfloat16* __restrict__ Xb,
    const __hip_bfloat16* __restrict__ Wsrc, const __hip_bfloat16* __restrict__ Wdst,
    float* __restrict__ HS, float* __restrict__ HDp)
{
    __shared__ unsigned short sXp[32][XPP];
    const int tid  = threadIdx.x;
    const int lane = tid & 63;
    const int wave = tid >> 6;
    const int col  = lane & 15;
    const int quad = lane >> 4;
    const int r0   = blockIdx.x * 32;

    for (int i = tid; i < 32 * 32; i += 256) {
        const int row = i >> 5, c = i & 31;
        *reinterpret_cast<uint4*>(&sXp[row][c * 8]) =
            *reinterpret_cast<const uint4*>(&Xb[(size_t)(r0 + row) * HD + c * 8]);
    }
    __syncthreads();

    f32x4 acc[2][4];
    #pragma unroll
    for (int p = 0; p < 2; ++p) {
        const __hip_bfloat16* Ws = (p == 0) ? Wsrc : Wdst;
        float* outp = (p == 0) ? HS : HDp;
        #pragma unroll
        for (int nt = 0; nt < 4; ++nt) {
            acc[0][nt] = { 0.f, 0.f, 0.f, 0.f };
            acc[1][nt] = { 0.f, 0.f, 0.f, 0.f };
        }
        mfma_gemm(&sXp[0][0], XPP, Ws + (size_t)(wave * 4) * 8 * 512, 8, lane, acc);
        #pragma unroll
        for (int mt = 0; mt < 2; ++mt)
            #pragma unroll
            for (int nt = 0; nt < 4; ++nt)
                #pragma unroll
                for (int r = 0; r < 4; ++r)
                    outp[(size_t)(r0 + mt * 16 + quad * 4 + r) * HD +
                         wave * 64 + nt * 16 + col] = acc[mt][nt][r];
    }
}

// ---------------------------------------------------------------------------
// Edge MFMA kernel: 32 edges/block, dst-sorted order (elist).
// GEMM1 = gather-add of per-node projections + ONE tail MFMA K-step.
__global__ __launch_bounds__(256, 4) void edge_mfma(
    const float* __restrict__ coords,
    const float* __restrict__ hs, const float* __restrict__ hd,
    const __hip_bfloat16* __restrict__ efb,
    const int* __restrict__ src, const int* __restrict__ dst,
    const int* __restrict__ elist,
    const __hip_bfloat16* __restrict__ W1t, const float* __restrict__ b1,
    const __hip_bfloat16* __restrict__ W2s, const float* __restrict__ b2,
    const __hip_bfloat16* __restrict__ Wc1s, const float* __restrict__ bc1,
    const float* __restrict__ wc2v, const float* __restrict__ bc2,
    float* __restrict__ aggr, float* __restrict__ xsum)
{
    __shared__ unsigned short sX[32][XP];     // fp32 gather view / bf16 stages
    __shared__ unsigned short sT[32][40];     // tail [ef(16)|rbf(15)|0]
    __shared__ float sXrel[32][3];
    __shared__ int   sDst[32];
    __shared__ int   sSrc[32];
    __shared__ int   sE[32];
    __shared__ float sRedW[4][32];
    __shared__ float sPv[32];

    const int tid  = threadIdx.x;
    const int lane = tid & 63;
    const int wave = tid >> 6;
    const int col  = lane & 15;
    const int quad = lane >> 4;
    const int e0   = blockIdx.x * 32;

    // ---- edge meta: permuted id, endpoints, x_rel, RBF (into tail) ----
    if (tid < 32) {
        const int e = elist[e0 + tid];
        const int s = src[e], d = dst[e];
        sE[tid] = e; sSrc[tid] = s; sDst[tid] = d;
        float d2 = 0.f;
        #pragma unroll
        for (int c = 0; c < 3; ++c) {
            const float xr = coords[s * 3 + c] - coords[d * 3 + c];
            sXrel[tid][c] = xr;
            d2 += xr * xr;
        }
        float sig = 1.0f;
        #pragma unroll
        for (int si = 0; si < NSIG; ++si) {
            sT[tid][16 + si] = f2bu(__expf(-d2 / sig));
            sig *= 1.5f;
        }
        sT[tid][31] = 0;
    }
    __syncthreads();

    // ---- gather-add projections: sXf[row][c] = Hs[src][c] + Hd[dst][c] ----
    float* sXf = reinterpret_cast<float*>(&sX[0][0]);   // pitch FPH floats
    for (int i = tid; i < 32 * 64; i += 256) {
        const int row = i >> 6, c4 = i & 63;
        const float4 a = *reinterpret_cast<const float4*>(
            &hs[(size_t)sSrc[row] * HD + c4 * 4]);
        const float4 b = *reinterpret_cast<const float4*>(
            &hd[(size_t)sDst[row] * HD + c4 * 4]);
        float4 sum;
        sum.x = a.x + b.x; sum.y = a.y + b.y;
        sum.z = a.z + b.z; sum.w = a.w + b.w;
        *reinterpret_cast<float4*>(&sXf[row * FPH + c4 * 4]) = sum;
    }
    // ---- gather edge features (bf16, permuted rows) into tail ----
    if (tid < 64) {
        const int row = tid >> 1, hh = tid & 1;
        *reinterpret_cast<uint4*>(&sT[row][hh * 8]) =
            *reinterpret_cast<const uint4*>(&efb[(size_t)sE[row] * EFD + hh * 8]);
    }
    __syncthreads();

    f32x4 acc[2][4];
    f32x4 macc[2][4];   // message accumulators, survive the coords GEMM

    // ---- GEMM1': acc = b1 + (Hs+Hd) frag + [ef|rbf] @ W1tail (1 K-step) ----
    #pragma unroll
    for (int nt = 0; nt < 4; ++nt) {
        const float bv = b1[wave * 64 + nt * 16 + col];
        acc[0][nt] = { bv, bv, bv, bv };
        acc[1][nt] = { bv, bv, bv, bv };
    }
    #pragma unroll
    for (int mt = 0; mt < 2; ++mt)
        #pragma unroll
        for (int nt = 0; nt < 4; ++nt)
            #pragma unroll
            for (int r = 0; r < 4; ++r)
                acc[mt][nt][r] +=
                    sXf[(mt * 16 + quad * 4 + r) * FPH + wave * 64 + nt * 16 + col];
    {
        const bf16x8 aT0 = *reinterpret_cast<const bf16x8*>(&sT[col][quad * 8]);
        const bf16x8 aT1 = *reinterpret_cast<const bf16x8*>(&sT[16 + col][quad * 8]);
        #pragma unroll
        for (int nt = 0; nt < 4; ++nt) {
            const bf16x8 bT = *reinterpret_cast<const bf16x8*>(
                W1t + (size_t)(wave * 4 + nt) * 512 + lane * 8);
            acc[0][nt] = __builtin_amdgcn_mfma_f32_16x16x32_bf16(aT0, bT, acc[0][nt], 0, 0, 0);
            acc[1][nt] = __builtin_amdgcn_mfma_f32_16x16x32_bf16(aT1, bT, acc[1][nt], 0, 0, 0);
        }
    }
    __syncthreads();
    #pragma unroll
    for (int mt = 0; mt < 2; ++mt)
        #pragma unroll
        for (int nt = 0; nt < 4; ++nt)
            #pragma unroll
            for (int r = 0; r < 4; ++r)
                sX[mt * 16 + quad * 4 + r][wave * 64 + nt * 16 + col] =
                    f2bu(lrelu(acc[mt][nt][r]));
    __syncthreads();

    // ---- GEMM2: hidden @ W2 -> msg (kept fp32 in macc) ----
    #pragma unroll
    for (int nt = 0; nt < 4; ++nt) {
        const float bv = b2[wave * 64 + nt * 16 + col];
        macc[0][nt] = { bv, bv, bv, bv };
        macc[1][nt] = { bv, bv, bv, bv };
    }
    mfma_gemm(&sX[0][0], XP, W2s + (size_t)(wave * 4) * 8 * 512, 8, lane, macc);
    __syncthreads();
    #pragma unroll
    for (int mt = 0; mt < 2; ++mt)
        #pragma unroll
        for (int nt = 0; nt < 4; ++nt)
            #pragma unroll
            for (int r = 0; r < 4; ++r)
                sX[mt * 16 + quad * 4 + r][wave * 64 + nt * 16 + col] =
                    f2bu(macc[mt][nt][r]);
    __syncthreads();

    // ---- GEMM3: msg @ Wc1 -> lrelu -> dot wc2 (per-edge scalar p) ----
    #pragma unroll
    for (int nt = 0; nt < 4; ++nt) {
        const float bv = bc1[wave * 64 + nt * 16 + col];
        acc[0][nt] = { bv, bv, bv, bv };
        acc[1][nt] = { bv, bv, bv, bv };
    }
    mfma_gemm(&sX[0][0], XP, Wc1s + (size_t)(wave * 4) * 8 * 512, 8, lane, acc);
    float w2l[4];
    #pragma unroll
    for (int nt = 0; nt < 4; ++nt) w2l[nt] = wc2v[wave * 64 + nt * 16 + col];
    #pragma unroll
    for (int mt = 0; mt < 2; ++mt) {
        float pr[4] = { 0.f, 0.f, 0.f, 0.f };
        #pragma unroll
        for (int nt = 0; nt < 4; ++nt)
            #pragma unroll
            for (int r = 0; r < 4; ++r)
                pr[r] += lrelu(acc[mt][nt][r]) * w2l[nt];
        #pragma unroll
        for (int r = 0; r < 4; ++r) {
            #pragma unroll
            for (int off = 1; off < 16; off <<= 1) pr[r] += __shfl_xor(pr[r], off);
        }
        if (col == 0)
            #pragma unroll
            for (int r = 0; r < 4; ++r)
                sRedW[wave][mt * 16 + quad * 4 + r] = pr[r];
    }
    __syncthreads();

    // ---- dump fp32 messages into LDS (reuse sX), gather p per edge ----
    float* sF = reinterpret_cast<float*>(&sX[0][0]);   // [32][FP] floats
    #pragma unroll
    for (int mt = 0; mt < 2; ++mt)
        #pragma unroll
        for (int nt = 0; nt < 4; ++nt)
            #pragma unroll
            for (int r = 0; r < 4; ++r)
                sF[(mt * 16 + quad * 4 + r) * FP + wave * 64 + nt * 16 + col] =
                    macc[mt][nt][r];
    if (tid < 32)
        sPv[tid] = sRedW[0][tid] + sRedW[1][tid] + sRedW[2][tid] + sRedW[3][tid]
                 + bc2[0];
    __syncthreads();

    // ---- segmented flush: one atomic per (distinct dst x column) ----
    {
        const int c = tid;               // 256 threads = 256 columns
        float av = 0.f;
        int dprev = sDst[0];
        for (int row = 0; row < 32; ++row) {
            const int d = sDst[row];     // uniform across block -> no divergence
            if (d != dprev) {
                atomicAdd(&aggr[(size_t)dprev * HD + c], av);
                av = 0.f; dprev = d;
            }
            av += sF[row * FP + c];
        }
        atomicAdd(&aggr[(size_t)dprev * HD + c], av);
    }
    if (tid < 3) {
        const int c = tid;
        float av = 0.f;
        int dprev = sDst[0];
        for (int row = 0; row < 32; ++row) {
            const int d = sDst[row];
            if (d != dprev) {
                atomicAdd(&xsum[(size_t)dprev * 3 + c], av);
                av = 0.f; dprev = d;
            }
            av += sXrel[row][c] * sPv[row];
        }
        atomicAdd(&xsum[(size_t)dprev * 3 + c], av);
    }
}

// ---------------------------------------------------------------------------
// Node MFMA kernel: 32 nodes/block (unchanged).
__global__ __launch_bounds__(256, 4) void node_mfma(
    const float* __restrict__ aggr, const float* __restrict__ cnt,
    const __hip_bfloat16* __restrict__ cross, const float* __restrict__ orig,
    const float* __restrict__ hfeat,
    const __hip_bfloat16* __restrict__ WN1s, const float* __restrict__ b1,
    const __hip_bfloat16* __restrict__ WN2s, const float* __restrict__ b2,
    float* __restrict__ out)
{
    __shared__ unsigned short sXn[32][XPN];
    __shared__ float sInv[32];

    const int tid  = threadIdx.x;
    const int lane = tid & 63;
    const int wave = tid >> 6;
    const int col  = lane & 15;
    const int quad = lane >> 4;
    const int r0   = blockIdx.x * 32;

    if (tid < 32) sInv[tid] = 1.f / fmaxf(cnt[r0 + tid], 1.f);
    __syncthreads();

    for (int i = tid; i < 32 * 64; i += 256) {
        const int row = i >> 6, c4 = i & 63;
        const float inv = sInv[row];
        const float4 v = *reinterpret_cast<const float4*>(
            &aggr[(size_t)(r0 + row) * HD + c4 * 4]);
        ushort4 u = { f2bu(v.x * inv), f2bu(v.y * inv), f2bu(v.z * inv), f2bu(v.w * inv) };
        *reinterpret_cast<ushort4*>(&sXn[row][c4 * 4]) = u;
    }
    for (int i = tid; i < 32 * 64; i += 256) {
        const int row = i >> 6, c4 = i & 63;
        const ushort4 u = *reinterpret_cast<const ushort4*>(
            &cross[(size_t)(r0 + row) * HD + c4 * 4]);
        *reinterpret_cast<ushort4*>(&sXn[row][256 + c4 * 4]) = u;
    }
    for (int i = tid; i < 32 * 16; i += 256) {
        const int row = i >> 4, c4 = i & 15;
        const float4 v = *reinterpret_cast<const float4*>(
            &orig[(size_t)(r0 + row) * ORIGD + c4 * 4]);
        ushort4 u = { f2bu(v.x), f2bu(v.y), f2bu(v.z), f2bu(v.w) };
        *reinterpret_cast<ushort4*>(&sXn[row][512 + c4 * 4]) = u;
    }
    __syncthreads();

    f32x4 acc[2][4];

    #pragma unroll
    for (int nt = 0; nt < 4; ++nt) {
        const float bv = b1[wave * 64 + nt * 16 + col];
        acc[0][nt] = { bv, bv, bv, bv };
        acc[1][nt] = { bv, bv, bv, bv };
    }
    mfma_gemm(&sXn[0][0], XPN, WN1s + (size_t)(wave * 4) * 18 * 512, 18, lane, acc);
    __syncthreads();
    #pragma unroll
    for (int mt = 0; mt < 2; ++mt)
        #pragma unroll
        for (int nt = 0; nt < 4; ++nt)
            #pragma unroll
            for (int r = 0; r < 4; ++r)
                sXn[mt * 16 + quad * 4 + r][wave * 64 + nt * 16 + col] =
                    f2bu(lrelu(acc[mt][nt][r]));
    __syncthreads();

    #pragma unroll
    for (int nt = 0; nt < 4; ++nt) {
        const float bv = b2[wave * 64 + nt * 16 + col];
        acc[0][nt] = { bv, bv, bv, bv };
        acc[1][nt] = { bv, bv, bv, bv };
    }
    mfma_gemm(&sXn[0][0], XPN, WN2s + (size_t)(wave * 4) * 8 * 512, 8, lane, acc);
    #pragma unroll
    for (int mt = 0; mt < 2; ++mt)
        #pragma unroll
        for (int nt = 0; nt < 4; ++nt)
            #pragma unroll
            for (int r = 0; r < 4; ++r) {
                const int g = r0 + mt * 16 + quad * 4 + r;
                const int n = wave * 64 + nt * 16 + col;
                out[(size_t)g * HD + n] =
                    0.5f * acc[mt][nt][r] + 0.5f * hfeat[(size_t)g * HD + n];
            }
}

// ---------------------------------------------------------------------------
// Fused Q/K/V projection: stage X once, run 3 GEMMs from the same LDS tile.
// K/V written directly in fragment-blob order (r19, proven).
__global__ __launch_bounds__(256, 4) void qkv_proj(
    const __hip_bfloat16* __restrict__ Xb,
    const __hip_bfloat16* __restrict__ Wq, const __hip_bfloat16* __restrict__ Wk,
    const __hip_bfloat16* __restrict__ Wv,
    __hip_bfloat16* __restrict__ Q, __hip_bfloat16* __restrict__ Kz,
    __hip_bfloat16* __restrict__ Vz)
{
    __shared__ unsigned short sXp[32][XPP];
    const int tid  = threadIdx.x;
    const int lane = tid & 63;
    const int wave = tid >> 6;
    const int col  = lane & 15;
    const int quad = lane >> 4;
    const int r0   = blockIdx.x * 32;

    for (int i = tid; i < 32 * 32; i += 256) {
        const int row = i >> 5, c = i & 31;
        *reinterpret_cast<uint4*>(&sXp[row][c * 8]) =
            *reinterpret_cast<const uint4*>(&Xb[(size_t)(r0 + row) * HD + c * 8]);
    }
    __syncthreads();

    f32x4 acc[2][4];
    #pragma unroll
    for (int p = 0; p < 3; ++p) {
        const __hip_bfloat16* Ws = (p == 0) ? Wq : (p == 1) ? Wk : Wv;
        #pragma unroll
        for (int nt = 0; nt < 4; ++nt) {
            acc[0][nt] = { 0.f, 0.f, 0.f, 0.f };
            acc[1][nt] = { 0.f, 0.f, 0.f, 0.f };
        }
        mfma_gemm(&sXp[0][0], XPP, Ws + (size_t)(wave * 4) * 8 * 512, 8, lane, acc);
        #pragma unroll
        for (int mt = 0; mt < 2; ++mt)
            #pragma unroll
            for (int nt = 0; nt < 4; ++nt)
                #pragma unroll
                for (int r = 0; r < 4; ++r) {
                    float v = acc[mt][nt][r];
                    const int row = r0 + mt * 16 + quad * 4 + r;
                    const int c   = wave * 64 + nt * 16 + col;
                    if (p == 0) {
                        Q[(size_t)row * HD + c] = __float2bfloat16(lrelu(v));
                    } else if (p == 1) {
                        const int kt = row >> 4, rr = row & 15;
                        const int s  = c >> 5, cc8 = (c >> 3) & 3, j = c & 7;
                        Kz[(size_t)(kt * 8 + s) * 512 + (cc8 * 16 + rr) * 8 + j] =
                            __float2bfloat16(lrelu(v));
                    } else {
                        const int jt = row >> 5, rowin = row & 31;
                        const int dt = c >> 4, cc = c & 15;
                        Vz[((size_t)(jt * 16 + dt) * 64 + (rowin >> 3) * 16 + cc) * 8
                           + (rowin & 7)] = __float2bfloat16(v);
                    }
                }
    }
}

// ---------------------------------------------------------------------------
// Attention helpers (r14 structure, proven).
__device__ __forceinline__ void load_mask(
    const float* __restrict__ maskG, int transposed, int R0, int j0,
    int wave, int quad, int col, float mv[2][4])
{
    if (!transposed) {
        #pragma unroll
        for (int t = 0; t < 2; ++t)
            #pragma unroll
            for (int r = 0; r < 4; ++r)
                mv[t][r] = maskG[(size_t)(R0 + wave * 16 + quad * 4 + r) * N_REC
                                 + j0 + col + 16 * t];
    } else {
        #pragma unroll
        for (int t = 0; t < 2; ++t)
            #pragma unroll
            for (int r = 0; r < 4; ++r)
                mv[t][r] = maskG[(size_t)(j0 + col + 16 * t) * N_REC
                                 + R0 + wave * 16 + quad * 4 + r];
    }
}

__device__ __forceinline__ void attn_tile(
    const unsigned short* sK, const unsigned short* sV,
    unsigned short (*sPw)[40], const bf16x8 qf[8], const float mv[2][4],
    int lane, int col, int quad, f32x4 o[16], float m[4], float l[4])
{
    // ---- S = Q K^T ----
    f32x4 sacc[2];
    sacc[0][0]=0.f; sacc[0][1]=0.f; sacc[0][2]=0.f; sacc[0][3]=0.f;
    sacc[1][0]=0.f; sacc[1][1]=0.f; sacc[1][2]=0.f; sacc[1][3]=0.f;
    #pragma unroll
    for (int t = 0; t < 2; ++t) {
        #pragma unroll
        for (int s = 0; s < 8; ++s) {
            bf16x8 kf = *reinterpret_cast<const bf16x8*>(
                &sK[(t * 8 + s) * 512 + lane * 8]);
            sacc[t] = __builtin_amdgcn_mfma_f32_16x16x32_bf16(qf[s], kf, sacc[t], 0, 0, 0);
        }
    }

    // ---- masked scores ----
    float a[2][4];
    #pragma unroll
    for (int t = 0; t < 2; ++t)
        #pragma unroll
        for (int r = 0; r < 4; ++r)
            a[t][r] = mv[t][r] * sacc[t][r] - 1000.f * (1.f - mv[t][r]);

    // ---- defer-max: rescale only when local max grows past m+8 ----
    float lm[4];
    #pragma unroll
    for (int r = 0; r < 4; ++r) lm[r] = fmaxf(a[0][r], a[1][r]);
    float w = lm[0] - m[0];
    #pragma unroll
    for (int r = 1; r < 4; ++r) w = fmaxf(w, lm[r] - m[r]);
    if (!__all(w <= 8.f)) {
        #pragma unroll
        for (int r = 0; r < 4; ++r) {
            float mx = lm[r];
            #pragma unroll
            for (int off = 1; off < 16; off <<= 1)
                mx = fmaxf(mx, __shfl_xor(mx, off));
            const float mn = fmaxf(m[r], mx);
            const float c  = __expf(m[r] - mn);
            m[r] = mn;
            l[r] *= c;
            #pragma unroll
            for (int dt = 0; dt < 16; ++dt) o[dt][r] *= c;
        }
    }

    // ---- P = exp(a - m), per-lane l partials ----
    #pragma unroll
    for (int r = 0; r < 4; ++r) {
        const float p0 = __expf(a[0][r] - m[r]);
        const float p1 = __expf(a[1][r] - m[r]);
        sPw[quad * 4 + r][col]      = f2bu(p0);
        sPw[quad * 4 + r][col + 16] = f2bu(p1);
        l[r] += p0 + p1;
    }

    // ---- O += P V ----
    bf16x8 pf = *reinterpret_cast<const bf16x8*>(&sPw[col][quad * 8]);
    #pragma unroll
    for (int dt = 0; dt < 16; ++dt) {
        bf16x8 vf = *reinterpret_cast<const bf16x8*>(&sV[dt * 512 + lane * 8]);
        o[dt] = __builtin_amdgcn_mfma_f32_16x16x32_bf16(pf, vf, o[dt], 0, 0, 0);
    }
}

// ---------------------------------------------------------------------------
// MFMA flash attention partial (r14 structure, proven).
__global__ __launch_bounds__(512) void attn_mfma(
    const __hip_bfloat16* __restrict__ Qb, const __hip_bfloat16* __restrict__ Kz,
    const __hip_bfloat16* __restrict__ Vz, const float* __restrict__ maskG,
    float* __restrict__ PO, float* __restrict__ PM, float* __restrict__ PL,
    int M, int chunkKeys, int transposed)
{
    __shared__ unsigned short sKb[2][8192];   // 2 x 16 KB
    __shared__ unsigned short sVb[2][8192];   // 2 x 16 KB
    __shared__ unsigned short sP[8][16][40];  // 10 KB

    const int tid  = threadIdx.x;
    const int lane = tid & 63;
    const int wave = tid >> 6;
    const int col  = lane & 15;
    const int quad = lane >> 4;
    const int R0   = blockIdx.x * 128;
    const int split = blockIdx.y;
    const int jbase = split * chunkKeys;

    bf16x8 qf[8];
    {
        const __hip_bfloat16* qp =
            Qb + (size_t)(R0 + wave * 16 + col) * HD + quad * 8;
        #pragma unroll
        for (int s = 0; s < 8; ++s)
            qf[s] = *reinterpret_cast<const bf16x8*>(qp + 32 * s);
    }

    f32x4 o[16];
    #pragma unroll
    for (int dt = 0; dt < 16; ++dt) { o[dt][0]=0.f; o[dt][1]=0.f; o[dt][2]=0.f; o[dt][3]=0.f; }
    float m[4], l[4];
    #pragma unroll
    for (int r = 0; r < 4; ++r) { m[r] = -INFINITY; l[r] = 0.f; }

    float mvA[2][4], mvB[2][4];

    // ---- prologue: tile 0 -> buf0 + mvA ----
    stage_tile(Kz + (size_t)jbase * 256, &sKb[0][0], wave, lane);
    stage_tile(Vz + (size_t)jbase * 256, &sVb[0][0], wave, lane);
    load_mask(maskG, transposed, R0, jbase, wave, quad, col, mvA);

    for (int jt = 0; jt < chunkKeys; jt += 64) {
        // ===== phase A: compute tile jt (buf0, mvA); stage jt+32 =====
        asm volatile("s_waitcnt vmcnt(0)" ::: "memory");
        __builtin_amdgcn_s_barrier();
        __builtin_amdgcn_sched_barrier(0);
        stage_tile(Kz + (size_t)(jbase + jt + 32) * 256, &sKb[1][0], wave, lane);
        stage_tile(Vz + (size_t)(jbase + jt + 32) * 256, &sVb[1][0], wave, lane);
        load_mask(maskG, transposed, R0, jbase + jt + 32, wave, quad, col, mvB);
        __builtin_amdgcn_sched_barrier(0);
        attn_tile(&sKb[0][0], &sVb[0][0], sP[wave], qf, mvA,
                  lane, col, quad, o, m, l);

        // ===== phase B: compute tile jt+32 (buf1, mvB); stage jt+64 =====
        asm volatile("s_waitcnt vmcnt(0)" ::: "memory");
        __builtin_amdgcn_s_barrier();
        __builtin_amdgcn_sched_barrier(0);
        if (jt + 64 < chunkKeys) {
            stage_tile(Kz + (size_t)(jbase + jt + 64) * 256, &sKb[0][0], wave, lane);
            stage_tile(Vz + (size_t)(jbase + jt + 64) * 256, &sVb[0][0], wave, lane);
            load_mask(maskG, transposed, R0, jbase + jt + 64, wave, quad, col, mvA);
        }
        __builtin_amdgcn_sched_barrier(0);
        attn_tile(&sKb[1][0], &sVb[1][0], sP[wave], qf, mvB,
                  lane, col, quad, o, m, l);
    }

    // ---- final l reduction (per-lane partials -> 16-lane row sums) ----
    #pragma unroll
    for (int r = 0; r < 4; ++r) {
        #pragma unroll
        for (int off = 1; off < 16; off <<= 1)
            l[r] += __shfl_xor(l[r], off);
    }

    #pragma unroll
    for (int dt = 0; dt < 16; ++dt)
        #pragma unroll
        for (int r = 0; r < 4; ++r) {
            const int row = R0 + wave * 16 + quad * 4 + r;
            PO[((size_t)split * M + row) * HD + dt * 16 + col] = o[dt][r];
        }
    if (col == 0) {
        #pragma unroll
        for (int r = 0; r < 4; ++r) {
            const int row = R0 + wave * 16 + quad * 4 + r;
            PM[(size_t)split * M + row] = m[r];
            PL[(size_t)split * M + row] = l[r];
        }
    }
}

// ---------------------------------------------------------------------------
__global__ void attn_combine(
    const float* __restrict__ PO, const float* __restrict__ PM,
    const float* __restrict__ PL, __hip_bfloat16* __restrict__ Out,
    int M, int nchunks)
{
    const int idx = blockIdx.x * 256 + threadIdx.x;
    const int row = idx >> 8;
    float mmax = -INFINITY;
    for (int c = 0; c < nchunks; ++c) mmax = fmaxf(mmax, PM[(size_t)c * M + row]);
    float denom = 0.f, acc = 0.f;
    for (int c = 0; c < nchunks; ++c) {
        const float w = __expf(PM[(size_t)c * M + row] - mmax);
        denom += PL[(size_t)c * M + row] * w;
        acc   += PO[(size_t)c * M * HD + idx] * w;
    }
    Out[idx] = __float2bfloat16(acc / denom);
}

// ---------------------------------------------------------------------------
__global__ void coords_fin(
    const float* __restrict__ coords, const float* __restrict__ origc,
    const float* __restrict__ xsum, const float* __restrict__ cnt,
    float* __restrict__ out, int n)
{
    const int i = blockIdx.x * 256 + threadIdx.x;
    if (i >= n * 3) return;
    const int node = i / 3;
    const float inv = 1.f / fmaxf(cnt[node], 1.f);
    out[i] = 0.25f * origc[i] + 0.75f * coords[i] + xsum[i] * inv;
}

// ---------------------------------------------------------------------------
extern "C" void kernel_launch(void* const* d_in, const int* in_sizes, int n_in,
                              void* d_out, int out_size, void* d_ws, size_t ws_size,
                              hipStream_t stream)
{
    const float* coords_lig = (const float*)d_in[0];
    const float* h_lig      = (const float*)d_in[1];
    const float* orig_lig   = (const float*)d_in[2];
    const float* origc_lig  = (const float*)d_in[3];
    const float* coords_rec = (const float*)d_in[4];
    const float* h_rec      = (const float*)d_in[5];
    const float* orig_rec   = (const float*)d_in[6];
    const float* origc_rec  = (const float*)d_in[7];
    const float* mask       = (const float*)d_in[8];
    const float* lig_ef     = (const float*)d_in[9];
    const float* rec_ef     = (const float*)d_in[10];
    const int* lig_src = (const int*)d_in[11];
    const int* lig_dst = (const int*)d_in[12];
    const int* rec_src = (const int*)d_in[13];
    const int* rec_dst = (const int*)d_in[14];
    const float* le_w1 = (const float*)d_in[15];
    const float* le_b1 = (const float*)d_in[16];
    const float* le_w2 = (const float*)d_in[17];
    const float* le_b2 = (const float*)d_in[18];
    const float* re_w1 = (const float*)d_in[19];
    const float* re_b1 = (const float*)d_in[20];
    const float* re_w2 = (const float*)d_in[21];
    const float* re_b2 = (const float*)d_in[22];
    const float* aql_w = (const float*)d_in[23];
    const float* akl_w = (const float*)d_in[24];
    const float* avl_w = (const float*)d_in[25];
    const float* aqr_w = (const float*)d_in[26];
    const float* akr_w = (const float*)d_in[27];
    const float* avr_w = (const float*)d_in[28];
    const float* nl_w1 = (const float*)d_in[29];
    const float* nl_b1 = (const float*)d_in[30];
    const float* nl_w2 = (const float*)d_in[31];
    const float* nl_b2 = (const float*)d_in[32];
    const float* nr_w1 = (const float*)d_in[33];
    const float* nr_b1 = (const float*)d_in[34];
    const float* nr_w2 = (const float*)d_in[35];
    const float* nr_b2 = (const float*)d_in[36];
    const float* cl_w1 = (const float*)d_in[37];
    const float* cl_b1 = (const float*)d_in[38];
    const float* cl_w2 = (const float*)d_in[39];
    const float* cl_b2 = (const float*)d_in[40];
    const float* cr_w1 = (const float*)d_in[41];
    const float* cr_b1 = (const float*)d_in[42];
    const float* cr_w2 = (const float*)d_in[43];
    const float* cr_b2 = (const float*)d_in[44];

    float* out = (float*)d_out;
    float* wsf = (float*)d_ws;

    // ---- fp32 accumulator + CSR zone (same footprint as r19) ----
    const size_t AGGRL = 0;
    const size_t AGGRR = AGGRL + (size_t)N_LIG * HD;
    const size_t CNTL  = AGGRR + (size_t)N_REC * HD;
    const size_t CNTR  = CNTL + N_LIG;
    const size_t XSUML = CNTR + N_REC;
    const size_t XSUMR = XSUML + (size_t)N_LIG * 3;
    const size_t HISTL = XSUMR + (size_t)N_REC * 3;
    const size_t CURL  = HISTL + N_LIG;
    const size_t HISTR = CURL + N_LIG;
    const size_t CURR  = HISTR + N_REC;
    const size_t ZEND  = CURR + N_REC;          // zeroed through here
    const size_t ELISTL = ZEND;                 // not zeroed
    const size_t ELISTR = ELISTL + E_LIG_N;
    const size_t FEND   = ELISTR + E_REC_N;

    // ---- bf16 zone ----
    __hip_bfloat16* wsb = (__hip_bfloat16*)(wsf + FEND);
    const size_t QL  = 0;
    const size_t KL  = QL + (size_t)N_LIG * HD;   // unused (kept for layout)
    const size_t VL  = KL + (size_t)N_LIG * HD;   // unused
    const size_t QR  = VL + (size_t)N_LIG * HD;
    const size_t KR  = QR + (size_t)N_REC * HD;   // unused
    const size_t VR  = KR + (size_t)N_REC * HD;   // unused
    const size_t CRL = VR + (size_t)N_REC * HD;
    const size_t CRR = CRL + (size_t)N_LIG * HD;
    const size_t KZL = CRR + (size_t)N_REC * HD;          // K swizzled lig
    const size_t VZL = KZL + (size_t)N_LIG * HD;          // V swizzled lig
    const size_t KZR = VZL + (size_t)N_LIG * HD;          // K swizzled rec
    const size_t VZR = KZR + (size_t)N_REC * HD;          // V swizzled rec
    const size_t KW256 = (size_t)16 * 8 * 512;
    const size_t KTAIL = (size_t)16 * 512;
    const size_t NW1SZ = (size_t)16 * 18 * 512;
    const size_t SW_ESL = VZR + (size_t)N_REC * HD;       // W1 src slice (lig)
    const size_t SW_EDL = SW_ESL + KW256;                 // W1 dst slice (lig)
    const size_t SW_ETL = SW_EDL + KW256;                 // W1 tail (lig)
    const size_t SW_EL2 = SW_ETL + KTAIL;
    const size_t SW_EC1 = SW_EL2 + KW256;
    const size_t SW_NL1 = SW_EC1 + KW256;
    const size_t SW_NL2 = SW_NL1 + NW1SZ;
    const size_t SW_ESR = SW_NL2 + KW256;                 // W1 src slice (rec)
    const size_t SW_EDR = SW_ESR + KW256;
    const size_t SW_ETR = SW_EDR + KW256;
    const size_t SW_ER2 = SW_ETR + KTAIL;
    const size_t SW_EC1R = SW_ER2 + KW256;
    const size_t SW_NR1 = SW_EC1R + KW256;
    const size_t SW_NR2 = SW_NR1 + NW1SZ;
    const size_t SW_PQL = SW_NR2 + KW256;
    const size_t SW_PKL = SW_PQL + KW256;
    const size_t SW_PVL = SW_PKL + KW256;
    const size_t SW_PQR = SW_PVL + KW256;
    const size_t SW_PKR = SW_PQR + KW256;
    const size_t SW_PVR = SW_PKR + KW256;
    // pre-converted bf16 operand blobs
    const size_t HB_L  = SW_PVR + KW256;
    const size_t HB_R  = HB_L + (size_t)N_LIG * HD;
    const size_t EFB_L = HB_R + (size_t)N_REC * HD;
    const size_t EFB_R = EFB_L + (size_t)E_LIG_N * EFD;
    const size_t BF_END = EFB_R + (size_t)E_REC_N * EFD;

    // ---- split-K partial zone (fp32), dynamic splits ----
    float* wsp = (float*)(wsb + ((BF_END + 1) & ~(size_t)1));
    const size_t baseBytes = (size_t)((char*)wsp - (char*)d_ws);
    int SL = 16, SR = 4;
    {
        const size_t poElems16 = (size_t)16 * N_LIG * HD;
        const size_t need16 = baseBytes +
            (poElems16 + 2 * (size_t)16 * N_LIG) * sizeof(float);
        if (ws_size < need16) { SL = 8; SR = 2; }
    }
    const size_t PO_ = 0;
    const size_t PM_ = PO_ + (size_t)SL * N_LIG * HD;
    const size_t PL_ = PM_ + (size_t)SL * N_LIG;

    // ---- HS/HD per-node projections ALIAS the split-K zone (consumed by
    //      hproj->edge_mfma strictly before attn_mfma writes PO; same-stream
    //      ordering makes this safe). 10.5M floats < PO zone (16.8M). ----
    const size_t HS_L = 0;
    const size_t HD_L = HS_L + (size_t)N_LIG * HD;
    const size_t HS_R = HD_L + (size_t)N_LIG * HD;
    const size_t HD_R = HS_R + (size_t)N_REC * HD;

    const size_t O_XL = 0;
    const size_t O_HL = O_XL + (size_t)N_LIG * 3;
    const size_t O_XR = O_HL + (size_t)N_LIG * HD;
    const size_t O_HR = O_XR + (size_t)N_REC * 3;

    // 1) zero atomic accumulators + CSR hist/cursors
    zero_kernel<<<((int)ZEND + 255) / 256, 256, 0, stream>>>(wsf, (int)ZEND);

    // 1a) fp32 -> bf16 operand blobs (h and edge features)
    f2b_kernel<<<(N_LIG * HD / 8 + 255) / 256, 256, 0, stream>>>(
        h_lig, wsb + HB_L, N_LIG * HD / 8);
    f2b_kernel<<<(N_REC * HD / 8 + 255) / 256, 256, 0, stream>>>(
        h_rec, wsb + HB_R, N_REC * HD / 8);
    f2b_kernel<<<(E_LIG_N * EFD / 8 + 255) / 256, 256, 0, stream>>>(
        lig_ef, wsb + EFB_L, E_LIG_N * EFD / 8);
    f2b_kernel<<<(E_REC_N * EFD / 8 + 255) / 256, 256, 0, stream>>>(
        rec_ef, wsb + EFB_R, E_REC_N * EFD / 8);

    // 1b) CSR build: dst-sorted edge permutations (also produces fp32 counts)
    hist_kernel<<<E_LIG_N / 256, 256, 0, stream>>>(lig_dst, (int*)(wsf + HISTL), E_LIG_N);
    hist_kernel<<<E_REC_N / 256, 256, 0, stream>>>(rec_dst, (int*)(wsf + HISTR), E_REC_N);
    scan_kernel<<<1, 256, 0, stream>>>((int*)(wsf + HISTL), (int*)(wsf + CURL),
                                       wsf + CNTL, N_LIG);
    scan_kernel<<<1, 256, 0, stream>>>((int*)(wsf + HISTR), (int*)(wsf + CURR),
                                       wsf + CNTR, N_REC);
    scatter_kernel<<<E_LIG_N / 256, 256, 0, stream>>>(
        lig_dst, (int*)(wsf + CURL), (int*)(wsf + ELISTL), E_LIG_N);
    scatter_kernel<<<E_REC_N / 256, 256, 0, stream>>>(
        rec_dst, (int*)(wsf + CURR), (int*)(wsf + ELISTR), E_REC_N);

    // 2) weight swizzles (W1 split into src/dst/tail slices)
    wt_swz<<<16 * 8,  256, 0, stream>>>(le_w1,             wsb + SW_ESL, 256, 8);
    wt_swz<<<16 * 8,  256, 0, stream>>>(le_w1 + 256 * 256, wsb + SW_EDL, 256, 8);
    wt_swz<<<16 * 1,  256, 0, stream>>>(le_w1 + 512 * 256, wsb + SW_ETL, 31, 1);
    wt_swz<<<16 * 8,  256, 0, stream>>>(le_w2, wsb + SW_EL2, 256, 8);
    wt_swz<<<16 * 8,  256, 0, stream>>>(cl_w1, wsb + SW_EC1, 256, 8);
    wt_swz<<<16 * 18, 256, 0, stream>>>(nl_w1, wsb + SW_NL1, 576, 18);
    wt_swz<<<16 * 8,  256, 0, stream>>>(nl_w2, wsb + SW_NL2, 256, 8);
    wt_swz<<<16 * 8,  256, 0, stream>>>(re_w1,             wsb + SW_ESR, 256, 8);
    wt_swz<<<16 * 8,  256, 0, stream>>>(re_w1 + 256 * 256, wsb + SW_EDR, 256, 8);
    wt_swz<<<16 * 1,  256, 0, stream>>>(re_w1 + 512 * 256, wsb + SW_ETR, 31, 1);
    wt_swz<<<16 * 8,  256, 0, stream>>>(re_w2, wsb + SW_ER2, 256, 8);
    wt_swz<<<16 * 8,  256, 0, stream>>>(cr_w1, wsb + SW_EC1R, 256, 8);
    wt_swz<<<16 * 18, 256, 0, stream>>>(nr_w1, wsb + SW_NR1, 576, 18);
    wt_swz<<<16 * 8,  256, 0, stream>>>(nr_w2, wsb + SW_NR2, 256, 8);
    wt_swz<<<16 * 8,  256, 0, stream>>>(aql_w, wsb + SW_PQL, 256, 8);
    wt_swz<<<16 * 8,  256, 0, stream>>>(akl_w, wsb + SW_PKL, 256, 8);
    wt_swz<<<16 * 8,  256, 0, stream>>>(avl_w, wsb + SW_PVL, 256, 8);
    wt_swz<<<16 * 8,  256, 0, stream>>>(aqr_w, wsb + SW_PQR, 256, 8);
    wt_swz<<<16 * 8,  256, 0, stream>>>(akr_w, wsb + SW_PKR, 256, 8);
    wt_swz<<<16 * 8,  256, 0, stream>>>(avr_w, wsb + SW_PVR, 256, 8);

    // 2b) per-node W1 projections (fp32, in the aliased zone)
    hproj<<<N_LIG / 32, 256, 0, stream>>>(
        wsb + HB_L, wsb + SW_ESL, wsb + SW_EDL, wsp + HS_L, wsp + HD_L);
    hproj<<<N_REC / 32, 256, 0, stream>>>(
        wsb + HB_R, wsb + SW_ESR, wsb + SW_EDR, wsp + HS_R, wsp + HD_R);

    // 3) edge MFMA kernels (32 edges/block, dst-sorted, segmented atomics)
    edge_mfma<<<E_LIG_N / 32, 256, 0, stream>>>(
        coords_lig, wsp + HS_L, wsp + HD_L, wsb + EFB_L, lig_src, lig_dst,
        (const int*)(wsf + ELISTL),
        wsb + SW_ETL, le_b1, wsb + SW_EL2, le_b2, wsb + SW_EC1, cl_b1, cl_w2, cl_b2,
        wsf + AGGRL, wsf + XSUML);
    edge_mfma<<<E_REC_N / 32, 256, 0, stream>>>(
        coords_rec, wsp + HS_R, wsp + HD_R, wsb + EFB_R, rec_src, rec_dst,
        (const int*)(wsf + ELISTR),
        wsb + SW_ETR, re_b1, wsb + SW_ER2, re_b2, wsb + SW_EC1R, cr_b1, cr_w2, cr_b2,
        wsf + AGGRR, wsf + XSUMR);

    // 4) fused q/k/v projections (K/V written directly in fragment-blob order)
    qkv_proj<<<N_LIG / 32, 256, 0, stream>>>(
        wsb + HB_L, wsb + SW_PQL, wsb + SW_PKL, wsb + SW_PVL,
        wsb + QL, wsb + KZL, wsb + VZL);
    qkv_proj<<<N_REC / 32, 256, 0, stream>>>(
        wsb + HB_R, wsb + SW_PQR, wsb + SW_PKR, wsb + SW_PVR,
        wsb + QR, wsb + KZR, wsb + VZR);

    // 5) MFMA flash attention, split-K + combine (PO overwrites HS/HD zone
    //    only after edge_mfma has consumed it - same-stream ordering)
    {
        dim3 gl(N_LIG / 128, SL);
        attn_mfma<<<gl, 512, 0, stream>>>(wsb + QL, wsb + KZR, wsb + VZR, mask,
                                          wsp + PO_, wsp + PM_, wsp + PL_,
                                          N_LIG, N_REC / SL, 0);
        attn_combine<<<N_LIG, 256, 0, stream>>>(
            wsp + PO_, wsp + PM_, wsp + PL_, wsb + CRL, N_LIG, SL);

        dim3 gr(N_REC / 128, SR);
        attn_mfma<<<gr, 512, 0, stream>>>(wsb + QR, wsb + KZL, wsb + VZL, mask,
                                          wsp + PO_, wsp + PM_, wsp + PL_,
                                          N_REC, N_LIG / SR, 1);
        attn_combine<<<N_REC, 256, 0, stream>>>(
            wsp + PO_, wsp + PM_, wsp + PL_, wsb + CRR, N_REC, SR);
    }

    // 6) coordinate outputs
    coords_fin<<<(N_LIG * 3 + 255) / 256, 256, 0, stream>>>(
        coords_lig, origc_lig, wsf + XSUML, wsf + CNTL, out + O_XL, N_LIG);
    coords_fin<<<(N_REC * 3 + 255) / 256, 256, 0, stream>>>(
        coords_rec, origc_rec, wsf + XSUMR, wsf + CNTR, out + O_XR, N_REC);

    // 7) node MFMA kernels
    node_mfma<<<N_LIG / 32, 256, 0, stream>>>(
        wsf + AGGRL, wsf + CNTL, wsb + CRL, orig_lig, h_lig,
        wsb + SW_NL1, nl_b1, wsb + SW_NL2, nl_b2, out + O_HL);
    node_mfma<<<N_REC / 32, 256, 0, stream>>>(
        wsf + AGGRR, wsf + CNTR, wsb + CRR, orig_rec, h_rec,
        wsb + SW_NR1, nr_b1, wsb + SW_NR2, nr_b2, out + O_HR);

    (void)in_sizes; (void)n_in; (void)out_size;
}

// Round 14
// 1294.434 us; speedup vs baseline: 1.0373x; 1.0362x over previous
//
#include <hip/hip_runtime.h>
#include <hip/hip_bf16.h>

// ---------------------------------------------------------------------------
// IEGMN layer, MI355X round-22: exact revert to round-19 (session best,
// 1303.3 us measured). r20/r21's W1 factorization improved edge_mfma locally
// but regressed the total (~+38 us: hproj dispatches + 42MB fp32 HS/HD
// round-trip + L2 pollution); reverted per post-mortem.
//  * mfma_gemm: even/odd depth-2 prefetch (2x load-ahead, no reg rotation)
//  * edge_mfma: 32 edges/block, dst-sorted CSR order, segmented atomics
//  * qkv_proj: fused Q/K/V, K/V stored directly in fragment-blob order
//  * attn_mfma: 8 waves x 16 q-rows, glds LDS double-buffer, defer-max
// ---------------------------------------------------------------------------

#define N_LIG   4096
#define N_REC   16384
#define E_LIG_N 65536
#define E_REC_N 262144
#define HD      256
#define ORIGD   64
#define EFD     16
#define NSIG    15
#define EIN     543      // 2*HD + EFD + NSIG
#define XP      552      // edge sX pitch (bf16 elems), 544 used
#define XPN     584      // node sX pitch, 576 used
#define XPP     264      // proj sX pitch, 256 used
#define FP      264      // fp32 reuse pitch inside sX (floats)

typedef __bf16 bf16x8 __attribute__((ext_vector_type(8)));
typedef float  f32x4  __attribute__((ext_vector_type(4)));

__device__ __forceinline__ float lrelu(float x) { return x > 0.f ? x : 0.01f * x; }
__device__ __forceinline__ unsigned short f2bu(float f) {
    __hip_bfloat16 h = __float2bfloat16(f);
    return *reinterpret_cast<unsigned short*>(&h);
}

// Direct global->LDS async copy, 16B per lane.
__device__ __forceinline__ void glds16(const void* g, void* l) {
    __builtin_amdgcn_global_load_lds(
        (const __attribute__((address_space(1))) void*)g,
        (__attribute__((address_space(3))) void*)l,
        16, 0, 0);
}

// Stage 16KB (one 32-key K or V tile) into LDS with 512 threads: 2 glds/thr.
__device__ __forceinline__ void stage_tile(
    const __hip_bfloat16* g, unsigned short* l, int wave, int lane)
{
    #pragma unroll
    for (int i = 0; i < 2; ++i) {
        const __hip_bfloat16* gp = g + (size_t)(i * 512 + wave * 64 + lane) * 8;
        unsigned short* lp = l + (i * 512 + wave * 64) * 8;  // wave-uniform base
        glds16(gp, lp);
    }
}

// ---------------------------------------------------------------------------
// Shared 32xKx256 GEMM core. Even/odd depth-2 pipeline: weights/A-fragments
// for step ks are loaded two K-steps before use; no register rotation.
__device__ __forceinline__ void mfma_gemm(
    const unsigned short* sA, int pitch,
    const __hip_bfloat16* Wswz, int KS, int lane, f32x4 acc[2][4])
{
    const int col = lane & 15, quad = lane >> 4;
    const unsigned short* a0p = sA + (size_t)col * pitch + quad * 8;
    const unsigned short* a1p = sA + (size_t)(16 + col) * pitch + quad * 8;
    const __hip_bfloat16* wp = Wswz + lane * 8;

    bf16x8 bE[4], bO[4], aE0, aE1, aO0, aO1;
    #pragma unroll
    for (int nt = 0; nt < 4; ++nt) {
        bE[nt] = *reinterpret_cast<const bf16x8*>(wp + (size_t)nt * KS * 512);
        bO[nt] = *reinterpret_cast<const bf16x8*>(wp + ((size_t)nt * KS + 1) * 512);
    }
    aE0 = *reinterpret_cast<const bf16x8*>(a0p);
    aE1 = *reinterpret_cast<const bf16x8*>(a1p);
    aO0 = *reinterpret_cast<const bf16x8*>(a0p + 32);
    aO1 = *reinterpret_cast<const bf16x8*>(a1p + 32);

    int ks = 0;
    for (; ks + 2 <= KS; ks += 2) {
        // ---- even step: compute ks, prefetch ks+2 ----
        #pragma unroll
        for (int nt = 0; nt < 4; ++nt) {
            acc[0][nt] = __builtin_amdgcn_mfma_f32_16x16x32_bf16(aE0, bE[nt], acc[0][nt], 0, 0, 0);
            acc[1][nt] = __builtin_amdgcn_mfma_f32_16x16x32_bf16(aE1, bE[nt], acc[1][nt], 0, 0, 0);
        }
        if (ks + 2 < KS) {
            #pragma unroll
            for (int nt = 0; nt < 4; ++nt)
                bE[nt] = *reinterpret_cast<const bf16x8*>(
                    wp + ((size_t)nt * KS + ks + 2) * 512);
            aE0 = *reinterpret_cast<const bf16x8*>(a0p + (ks + 2) * 32);
            aE1 = *reinterpret_cast<const bf16x8*>(a1p + (ks + 2) * 32);
        }
        // ---- odd step: compute ks+1, prefetch ks+3 ----
        #pragma unroll
        for (int nt = 0; nt < 4; ++nt) {
            acc[0][nt] = __builtin_amdgcn_mfma_f32_16x16x32_bf16(aO0, bO[nt], acc[0][nt], 0, 0, 0);
            acc[1][nt] = __builtin_amdgcn_mfma_f32_16x16x32_bf16(aO1, bO[nt], acc[1][nt], 0, 0, 0);
        }
        if (ks + 3 < KS) {
            #pragma unroll
            for (int nt = 0; nt < 4; ++nt)
                bO[nt] = *reinterpret_cast<const bf16x8*>(
                    wp + ((size_t)nt * KS + ks + 3) * 512);
            aO0 = *reinterpret_cast<const bf16x8*>(a0p + (ks + 3) * 32);
            aO1 = *reinterpret_cast<const bf16x8*>(a1p + (ks + 3) * 32);
        }
    }
    if (ks < KS) {   // odd-KS tail (even slot)
        #pragma unroll
        for (int nt = 0; nt < 4; ++nt) {
            acc[0][nt] = __builtin_amdgcn_mfma_f32_16x16x32_bf16(aE0, bE[nt], acc[0][nt], 0, 0, 0);
            acc[1][nt] = __builtin_amdgcn_mfma_f32_16x16x32_bf16(aE1, bE[nt], acc[1][nt], 0, 0, 0);
        }
    }
}

// ---------------------------------------------------------------------------
__global__ void zero_kernel(float* __restrict__ p, int n) {
    int i = blockIdx.x * 256 + threadIdx.x;
    if (i < n) p[i] = 0.f;
}

// ---------------------------------------------------------------------------
// fp32 -> bf16 blob, 8 elems/thread (vectorized).
__global__ void f2b_kernel(const float* __restrict__ src,
                           __hip_bfloat16* __restrict__ dst, int n8) {
    const int i = blockIdx.x * 256 + threadIdx.x;
    if (i >= n8) return;
    const float4 a = *reinterpret_cast<const float4*>(src + (size_t)i * 8);
    const float4 b = *reinterpret_cast<const float4*>(src + (size_t)i * 8 + 4);
    ushort4 u0 = { f2bu(a.x), f2bu(a.y), f2bu(a.z), f2bu(a.w) };
    ushort4 u1 = { f2bu(b.x), f2bu(b.y), f2bu(b.z), f2bu(b.w) };
    unsigned short* d = (unsigned short*)dst + (size_t)i * 8;
    *reinterpret_cast<ushort4*>(d)     = u0;
    *reinterpret_cast<ushort4*>(d + 4) = u1;
}

// ---------------------------------------------------------------------------
// CSR build: histogram -> scan -> scatter (dst-sorted edge permutation).
__global__ void hist_kernel(const int* __restrict__ dst, int* __restrict__ hist, int n) {
    int i = blockIdx.x * 256 + threadIdx.x;
    if (i < n) atomicAdd(&hist[dst[i]], 1);
}

__global__ __launch_bounds__(256) void scan_kernel(
    const int* __restrict__ hist, int* __restrict__ cur,
    float* __restrict__ cntf, int n)
{
    __shared__ int part[256];
    const int tid = threadIdx.x;
    const int per = n >> 8;            // n is 4096 or 16384
    const int base = tid * per;
    int s = 0;
    for (int i = 0; i < per; ++i) s += hist[base + i];
    part[tid] = s;
    __syncthreads();
    #pragma unroll
    for (int off = 1; off < 256; off <<= 1) {
        int v = (tid >= off) ? part[tid - off] : 0;
        __syncthreads();
        part[tid] += v;
        __syncthreads();
    }
    int run = part[tid] - s;           // exclusive prefix of this chunk
    for (int i = 0; i < per; ++i) {
        const int h = hist[base + i];
        cur[base + i]  = run;
        cntf[base + i] = (float)h;
        run += h;
    }
}

__global__ void scatter_kernel(const int* __restrict__ dst, int* __restrict__ cur,
                               int* __restrict__ elist, int n) {
    int i = blockIdx.x * 256 + threadIdx.x;
    if (i < n) { int p = atomicAdd(&cur[dst[i]], 1); elist[p] = i; }
}

// ---------------------------------------------------------------------------
__global__ void wt_swz(const float* __restrict__ src,
                       __hip_bfloat16* __restrict__ dst, int K, int KS) {
    const int g  = blockIdx.x / KS;
    const int ks = blockIdx.x % KS;
    for (int i = threadIdx.x; i < 512; i += 256) {
        const int lane = i >> 3, j = i & 7;
        const int n = g * 16 + (lane & 15);
        const int k = ks * 32 + (lane >> 4) * 8 + j;
        const float v = (k < K) ? src[(size_t)k * 256 + n] : 0.f;
        dst[((size_t)(g * KS + ks) * 64 + lane) * 8 + j] = __float2bfloat16(v);
    }
}

// ---------------------------------------------------------------------------
// Edge MFMA kernel: 32 edges/block, edges taken in dst-sorted order (elist).
// (r15 structure; measured 227 us rec / MfmaUtil 27%.)
__global__ __launch_bounds__(256, 4) void edge_mfma(
    const float* __restrict__ coords, const __hip_bfloat16* __restrict__ hb,
    const __hip_bfloat16* __restrict__ efb,
    const int* __restrict__ src, const int* __restrict__ dst,
    const int* __restrict__ elist,
    const __hip_bfloat16* __restrict__ W1s, const float* __restrict__ b1,
    const __hip_bfloat16* __restrict__ W2s, const float* __restrict__ b2,
    const __hip_bfloat16* __restrict__ Wc1s, const float* __restrict__ bc1,
    const float* __restrict__ wc2v, const float* __restrict__ bc2,
    float* __restrict__ aggr, float* __restrict__ xsum)
{
    __shared__ unsigned short sX[32][XP];     // also reused as fp32 [32][FP]
    __shared__ float sXrel[32][3];
    __shared__ int   sDst[32];
    __shared__ int   sSrc[32];
    __shared__ int   sE[32];
    __shared__ float sRedW[4][32];
    __shared__ float sPv[32];

    const int tid  = threadIdx.x;
    const int lane = tid & 63;
    const int wave = tid >> 6;
    const int col  = lane & 15;
    const int quad = lane >> 4;
    const int e0   = blockIdx.x * 32;

    // ---- edge meta: permuted id, endpoints, x_rel, RBF ----
    if (tid < 32) {
        const int e = elist[e0 + tid];
        const int s = src[e], d = dst[e];
        sE[tid] = e; sSrc[tid] = s; sDst[tid] = d;
        float d2 = 0.f;
        #pragma unroll
        for (int c = 0; c < 3; ++c) {
            const float xr = coords[s * 3 + c] - coords[d * 3 + c];
            sXrel[tid][c] = xr;
            d2 += xr * xr;
        }
        float sig = 1.0f;
        #pragma unroll
        for (int si = 0; si < NSIG; ++si) {
            sX[tid][528 + si] = f2bu(__expf(-d2 / sig));
            sig *= 1.5f;
        }
        sX[tid][543] = 0;
    }
    __syncthreads();

    // ---- gather h[src], h[dst] (bf16, uint4 copies) ----
    for (int i = tid; i < 32 * 64; i += 256) {
        const int row = i >> 6, c = i & 63;
        const int node = (c < 32) ? sSrc[row] : sDst[row];
        const int chunk = c & 31;
        *reinterpret_cast<uint4*>(&sX[row][(c < 32 ? 0 : 256) + chunk * 8]) =
            *reinterpret_cast<const uint4*>(&hb[(size_t)node * HD + chunk * 8]);
    }
    // ---- gather edge features (bf16, permuted rows) ----
    if (tid < 64) {
        const int row = tid >> 1, hh = tid & 1;
        *reinterpret_cast<uint4*>(&sX[row][512 + hh * 8]) =
            *reinterpret_cast<const uint4*>(&efb[(size_t)sE[row] * EFD + hh * 8]);
    }
    __syncthreads();

    f32x4 acc[2][4];
    f32x4 macc[2][4];   // message accumulators, survive the coords GEMM

    // ---- GEMM1: [32 x 544] @ W1 -> hidden, lrelu ----
    #pragma unroll
    for (int nt = 0; nt < 4; ++nt) {
        const float bv = b1[wave * 64 + nt * 16 + col];
        acc[0][nt] = { bv, bv, bv, bv };
        acc[1][nt] = { bv, bv, bv, bv };
    }
    mfma_gemm(&sX[0][0], XP, W1s + (size_t)(wave * 4) * 17 * 512, 17, lane, acc);
    __syncthreads();
    #pragma unroll
    for (int mt = 0; mt < 2; ++mt)
        #pragma unroll
        for (int nt = 0; nt < 4; ++nt)
            #pragma unroll
            for (int r = 0; r < 4; ++r)
                sX[mt * 16 + quad * 4 + r][wave * 64 + nt * 16 + col] =
                    f2bu(lrelu(acc[mt][nt][r]));
    __syncthreads();

    // ---- GEMM2: hidden @ W2 -> msg (kept fp32 in macc) ----
    #pragma unroll
    for (int nt = 0; nt < 4; ++nt) {
        const float bv = b2[wave * 64 + nt * 16 + col];
        macc[0][nt] = { bv, bv, bv, bv };
        macc[1][nt] = { bv, bv, bv, bv };
    }
    mfma_gemm(&sX[0][0], XP, W2s + (size_t)(wave * 4) * 8 * 512, 8, lane, macc);
    __syncthreads();
    #pragma unroll
    for (int mt = 0; mt < 2; ++mt)
        #pragma unroll
        for (int nt = 0; nt < 4; ++nt)
            #pragma unroll
            for (int r = 0; r < 4; ++r)
                sX[mt * 16 + quad * 4 + r][wave * 64 + nt * 16 + col] =
                    f2bu(macc[mt][nt][r]);
    __syncthreads();

    // ---- GEMM3: msg @ Wc1 -> lrelu -> dot wc2 (per-edge scalar p) ----
    #pragma unroll
    for (int nt = 0; nt < 4; ++nt) {
        const float bv = bc1[wave * 64 + nt * 16 + col];
        acc[0][nt] = { bv, bv, bv, bv };
        acc[1][nt] = { bv, bv, bv, bv };
    }
    mfma_gemm(&sX[0][0], XP, Wc1s + (size_t)(wave * 4) * 8 * 512, 8, lane, acc);
    float w2l[4];
    #pragma unroll
    for (int nt = 0; nt < 4; ++nt) w2l[nt] = wc2v[wave * 64 + nt * 16 + col];
    #pragma unroll
    for (int mt = 0; mt < 2; ++mt) {
        float pr[4] = { 0.f, 0.f, 0.f, 0.f };
        #pragma unroll
        for (int nt = 0; nt < 4; ++nt)
            #pragma unroll
            for (int r = 0; r < 4; ++r)
                pr[r] += lrelu(acc[mt][nt][r]) * w2l[nt];
        #pragma unroll
        for (int r = 0; r < 4; ++r) {
            #pragma unroll
            for (int off = 1; off < 16; off <<= 1) pr[r] += __shfl_xor(pr[r], off);
        }
        if (col == 0)
            #pragma unroll
            for (int r = 0; r < 4; ++r)
                sRedW[wave][mt * 16 + quad * 4 + r] = pr[r];
    }
    __syncthreads();

    // ---- dump fp32 messages into LDS (reuse sX), gather p per edge ----
    float* sF = reinterpret_cast<float*>(&sX[0][0]);   // [32][FP] floats
    #pragma unroll
    for (int mt = 0; mt < 2; ++mt)
        #pragma unroll
        for (int nt = 0; nt < 4; ++nt)
            #pragma unroll
            for (int r = 0; r < 4; ++r)
                sF[(mt * 16 + quad * 4 + r) * FP + wave * 64 + nt * 16 + col] =
                    macc[mt][nt][r];
    if (tid < 32)
        sPv[tid] = sRedW[0][tid] + sRedW[1][tid] + sRedW[2][tid] + sRedW[3][tid]
                 + bc2[0];
    __syncthreads();

    // ---- segmented flush: one atomic per (distinct dst x column) ----
    {
        const int c = tid;               // 256 threads = 256 columns
        float av = 0.f;
        int dprev = sDst[0];
        for (int row = 0; row < 32; ++row) {
            const int d = sDst[row];     // uniform across block -> no divergence
            if (d != dprev) {
                atomicAdd(&aggr[(size_t)dprev * HD + c], av);
                av = 0.f; dprev = d;
            }
            av += sF[row * FP + c];
        }
        atomicAdd(&aggr[(size_t)dprev * HD + c], av);
    }
    if (tid < 3) {
        const int c = tid;
        float av = 0.f;
        int dprev = sDst[0];
        for (int row = 0; row < 32; ++row) {
            const int d = sDst[row];
            if (d != dprev) {
                atomicAdd(&xsum[(size_t)dprev * 3 + c], av);
                av = 0.f; dprev = d;
            }
            av += sXrel[row][c] * sPv[row];
        }
        atomicAdd(&xsum[(size_t)dprev * 3 + c], av);
    }
}

// ---------------------------------------------------------------------------
// Node MFMA kernel: 32 nodes/block (unchanged).
__global__ __launch_bounds__(256, 4) void node_mfma(
    const float* __restrict__ aggr, const float* __restrict__ cnt,
    const __hip_bfloat16* __restrict__ cross, const float* __restrict__ orig,
    const float* __restrict__ hfeat,
    const __hip_bfloat16* __restrict__ WN1s, const float* __restrict__ b1,
    const __hip_bfloat16* __restrict__ WN2s, const float* __restrict__ b2,
    float* __restrict__ out)
{
    __shared__ unsigned short sXn[32][XPN];
    __shared__ float sInv[32];

    const int tid  = threadIdx.x;
    const int lane = tid & 63;
    const int wave = tid >> 6;
    const int col  = lane & 15;
    const int quad = lane >> 4;
    const int r0   = blockIdx.x * 32;

    if (tid < 32) sInv[tid] = 1.f / fmaxf(cnt[r0 + tid], 1.f);
    __syncthreads();

    for (int i = tid; i < 32 * 64; i += 256) {
        const int row = i >> 6, c4 = i & 63;
        const float inv = sInv[row];
        const float4 v = *reinterpret_cast<const float4*>(
            &aggr[(size_t)(r0 + row) * HD + c4 * 4]);
        ushort4 u = { f2bu(v.x * inv), f2bu(v.y * inv), f2bu(v.z * inv), f2bu(v.w * inv) };
        *reinterpret_cast<ushort4*>(&sXn[row][c4 * 4]) = u;
    }
    for (int i = tid; i < 32 * 64; i += 256) {
        const int row = i >> 6, c4 = i & 63;
        const ushort4 u = *reinterpret_cast<const ushort4*>(
            &cross[(size_t)(r0 + row) * HD + c4 * 4]);
        *reinterpret_cast<ushort4*>(&sXn[row][256 + c4 * 4]) = u;
    }
    for (int i = tid; i < 32 * 16; i += 256) {
        const int row = i >> 4, c4 = i & 15;
        const float4 v = *reinterpret_cast<const float4*>(
            &orig[(size_t)(r0 + row) * ORIGD + c4 * 4]);
        ushort4 u = { f2bu(v.x), f2bu(v.y), f2bu(v.z), f2bu(v.w) };
        *reinterpret_cast<ushort4*>(&sXn[row][512 + c4 * 4]) = u;
    }
    __syncthreads();

    f32x4 acc[2][4];

    #pragma unroll
    for (int nt = 0; nt < 4; ++nt) {
        const float bv = b1[wave * 64 + nt * 16 + col];
        acc[0][nt] = { bv, bv, bv, bv };
        acc[1][nt] = { bv, bv, bv, bv };
    }
    mfma_gemm(&sXn[0][0], XPN, WN1s + (size_t)(wave * 4) * 18 * 512, 18, lane, acc);
    __syncthreads();
    #pragma unroll
    for (int mt = 0; mt < 2; ++mt)
        #pragma unroll
        for (int nt = 0; nt < 4; ++nt)
            #pragma unroll
            for (int r = 0; r < 4; ++r)
                sXn[mt * 16 + quad * 4 + r][wave * 64 + nt * 16 + col] =
                    f2bu(lrelu(acc[mt][nt][r]));
    __syncthreads();

    #pragma unroll
    for (int nt = 0; nt < 4; ++nt) {
        const float bv = b2[wave * 64 + nt * 16 + col];
        acc[0][nt] = { bv, bv, bv, bv };
        acc[1][nt] = { bv, bv, bv, bv };
    }
    mfma_gemm(&sXn[0][0], XPN, WN2s + (size_t)(wave * 4) * 8 * 512, 8, lane, acc);
    #pragma unroll
    for (int mt = 0; mt < 2; ++mt)
        #pragma unroll
        for (int nt = 0; nt < 4; ++nt)
            #pragma unroll
            for (int r = 0; r < 4; ++r) {
                const int g = r0 + mt * 16 + quad * 4 + r;
                const int n = wave * 64 + nt * 16 + col;
                out[(size_t)g * HD + n] =
                    0.5f * acc[mt][nt][r] + 0.5f * hfeat[(size_t)g * HD + n];
            }
}

// ---------------------------------------------------------------------------
// Fused Q/K/V projection: stage X once, run 3 GEMMs from the same LDS tile.
// K and V are written DIRECTLY in the attention fragment-blob layouts
// (what kswz/vswz used to produce), eliminating those copy kernels.
__global__ __launch_bounds__(256, 4) void qkv_proj(
    const __hip_bfloat16* __restrict__ Xb,
    const __hip_bfloat16* __restrict__ Wq, const __hip_bfloat16* __restrict__ Wk,
    const __hip_bfloat16* __restrict__ Wv,
    __hip_bfloat16* __restrict__ Q, __hip_bfloat16* __restrict__ Kz,
    __hip_bfloat16* __restrict__ Vz)
{
    __shared__ unsigned short sXp[32][XPP];
    const int tid  = threadIdx.x;
    const int lane = tid & 63;
    const int wave = tid >> 6;
    const int col  = lane & 15;
    const int quad = lane >> 4;
    const int r0   = blockIdx.x * 32;

    for (int i = tid; i < 32 * 32; i += 256) {
        const int row = i >> 5, c = i & 31;
        *reinterpret_cast<uint4*>(&sXp[row][c * 8]) =
            *reinterpret_cast<const uint4*>(&Xb[(size_t)(r0 + row) * HD + c * 8]);
    }
    __syncthreads();

    f32x4 acc[2][4];
    #pragma unroll
    for (int p = 0; p < 3; ++p) {
        const __hip_bfloat16* Ws = (p == 0) ? Wq : (p == 1) ? Wk : Wv;
        #pragma unroll
        for (int nt = 0; nt < 4; ++nt) {
            acc[0][nt] = { 0.f, 0.f, 0.f, 0.f };
            acc[1][nt] = { 0.f, 0.f, 0.f, 0.f };
        }
        mfma_gemm(&sXp[0][0], XPP, Ws + (size_t)(wave * 4) * 8 * 512, 8, lane, acc);
        #pragma unroll
        for (int mt = 0; mt < 2; ++mt)
            #pragma unroll
            for (int nt = 0; nt < 4; ++nt)
                #pragma unroll
                for (int r = 0; r < 4; ++r) {
                    float v = acc[mt][nt][r];
                    const int row = r0 + mt * 16 + quad * 4 + r;
                    const int c   = wave * 64 + nt * 16 + col;
                    if (p == 0) {
                        Q[(size_t)row * HD + c] = __float2bfloat16(lrelu(v));
                    } else if (p == 1) {
                        // K blob: ((kt*8+s)*512 + (cc8*16+rr)*8 + j)
                        const int kt = row >> 4, rr = row & 15;
                        const int s  = c >> 5, cc8 = (c >> 3) & 3, j = c & 7;
                        Kz[(size_t)(kt * 8 + s) * 512 + (cc8 * 16 + rr) * 8 + j] =
                            __float2bfloat16(lrelu(v));
                    } else {
                        // V blob: (((jt*16+dt)*64 + (rowin>>3)*16 + cc)*8 + (rowin&7))
                        const int jt = row >> 5, rowin = row & 31;
                        const int dt = c >> 4, cc = c & 15;
                        Vz[((size_t)(jt * 16 + dt) * 64 + (rowin >> 3) * 16 + cc) * 8
                           + (rowin & 7)] = __float2bfloat16(v);
                    }
                }
    }
}

// ---------------------------------------------------------------------------
// Attention helpers.
__device__ __forceinline__ void load_mask(
    const float* __restrict__ maskG, int transposed, int R0, int j0,
    int wave, int quad, int col, float mv[2][4])
{
    if (!transposed) {
        #pragma unroll
        for (int t = 0; t < 2; ++t)
            #pragma unroll
            for (int r = 0; r < 4; ++r)
                mv[t][r] = maskG[(size_t)(R0 + wave * 16 + quad * 4 + r) * N_REC
                                 + j0 + col + 16 * t];
    } else {
        #pragma unroll
        for (int t = 0; t < 2; ++t)
            #pragma unroll
            for (int r = 0; r < 4; ++r)
                mv[t][r] = maskG[(size_t)(j0 + col + 16 * t) * N_REC
                                 + R0 + wave * 16 + quad * 4 + r];
    }
}

// One 32-key tile with defer-max online softmax (THR=8); l kept as per-lane
// partials (reduced once at kernel end).
__device__ __forceinline__ void attn_tile(
    const unsigned short* sK, const unsigned short* sV,
    unsigned short (*sPw)[40], const bf16x8 qf[8], const float mv[2][4],
    int lane, int col, int quad, f32x4 o[16], float m[4], float l[4])
{
    // ---- S = Q K^T ----
    f32x4 sacc[2];
    sacc[0][0]=0.f; sacc[0][1]=0.f; sacc[0][2]=0.f; sacc[0][3]=0.f;
    sacc[1][0]=0.f; sacc[1][1]=0.f; sacc[1][2]=0.f; sacc[1][3]=0.f;
    #pragma unroll
    for (int t = 0; t < 2; ++t) {
        #pragma unroll
        for (int s = 0; s < 8; ++s) {
            bf16x8 kf = *reinterpret_cast<const bf16x8*>(
                &sK[(t * 8 + s) * 512 + lane * 8]);
            sacc[t] = __builtin_amdgcn_mfma_f32_16x16x32_bf16(qf[s], kf, sacc[t], 0, 0, 0);
        }
    }

    // ---- masked scores ----
    float a[2][4];
    #pragma unroll
    for (int t = 0; t < 2; ++t)
        #pragma unroll
        for (int r = 0; r < 4; ++r)
            a[t][r] = mv[t][r] * sacc[t][r] - 1000.f * (1.f - mv[t][r]);

    // ---- defer-max: rescale only when local max grows past m+8 ----
    float lm[4];
    #pragma unroll
    for (int r = 0; r < 4; ++r) lm[r] = fmaxf(a[0][r], a[1][r]);
    float w = lm[0] - m[0];
    #pragma unroll
    for (int r = 1; r < 4; ++r) w = fmaxf(w, lm[r] - m[r]);
    if (!__all(w <= 8.f)) {
        #pragma unroll
        for (int r = 0; r < 4; ++r) {
            float mx = lm[r];
            #pragma unroll
            for (int off = 1; off < 16; off <<= 1)
                mx = fmaxf(mx, __shfl_xor(mx, off));
            const float mn = fmaxf(m[r], mx);
            const float c  = __expf(m[r] - mn);
            m[r] = mn;
            l[r] *= c;
            #pragma unroll
            for (int dt = 0; dt < 16; ++dt) o[dt][r] *= c;
        }
    }

    // ---- P = exp(a - m), per-lane l partials ----
    #pragma unroll
    for (int r = 0; r < 4; ++r) {
        const float p0 = __expf(a[0][r] - m[r]);
        const float p1 = __expf(a[1][r] - m[r]);
        sPw[quad * 4 + r][col]      = f2bu(p0);
        sPw[quad * 4 + r][col + 16] = f2bu(p1);
        l[r] += p0 + p1;
    }

    // ---- O += P V ----
    bf16x8 pf = *reinterpret_cast<const bf16x8*>(&sPw[col][quad * 8]);
    #pragma unroll
    for (int dt = 0; dt < 16; ++dt) {
        bf16x8 vf = *reinterpret_cast<const bf16x8*>(&sV[dt * 512 + lane * 8]);
        o[dt] = __builtin_amdgcn_mfma_f32_16x16x32_bf16(pf, vf, o[dt], 0, 0, 0);
    }
}

// ---------------------------------------------------------------------------
// MFMA flash attention partial. 128 q-rows/block (8 waves x 16), 32-key
// tiles. K/V double-buffered in LDS via global_load_lds; masks prefetched
// one tile ahead into alternating reg sets. (r14 structure, proven.)
__global__ __launch_bounds__(512) void attn_mfma(
    const __hip_bfloat16* __restrict__ Qb, const __hip_bfloat16* __restrict__ Kz,
    const __hip_bfloat16* __restrict__ Vz, const float* __restrict__ maskG,
    float* __restrict__ PO, float* __restrict__ PM, float* __restrict__ PL,
    int M, int chunkKeys, int transposed)
{
    __shared__ unsigned short sKb[2][8192];   // 2 x 16 KB
    __shared__ unsigned short sVb[2][8192];   // 2 x 16 KB
    __shared__ unsigned short sP[8][16][40];  // 10 KB

    const int tid  = threadIdx.x;
    const int lane = tid & 63;
    const int wave = tid >> 6;
    const int col  = lane & 15;
    const int quad = lane >> 4;
    const int R0   = blockIdx.x * 128;
    const int split = blockIdx.y;
    const int jbase = split * chunkKeys;

    bf16x8 qf[8];
    {
        const __hip_bfloat16* qp =
            Qb + (size_t)(R0 + wave * 16 + col) * HD + quad * 8;
        #pragma unroll
        for (int s = 0; s < 8; ++s)
            qf[s] = *reinterpret_cast<const bf16x8*>(qp + 32 * s);
    }

    f32x4 o[16];
    #pragma unroll
    for (int dt = 0; dt < 16; ++dt) { o[dt][0]=0.f; o[dt][1]=0.f; o[dt][2]=0.f; o[dt][3]=0.f; }
    float m[4], l[4];
    #pragma unroll
    for (int r = 0; r < 4; ++r) { m[r] = -INFINITY; l[r] = 0.f; }

    float mvA[2][4], mvB[2][4];

    // ---- prologue: tile 0 -> buf0 + mvA ----
    stage_tile(Kz + (size_t)jbase * 256, &sKb[0][0], wave, lane);
    stage_tile(Vz + (size_t)jbase * 256, &sVb[0][0], wave, lane);
    load_mask(maskG, transposed, R0, jbase, wave, quad, col, mvA);

    for (int jt = 0; jt < chunkKeys; jt += 64) {
        // ===== phase A: compute tile jt (buf0, mvA); stage jt+32 =====
        asm volatile("s_waitcnt vmcnt(0)" ::: "memory");
        __builtin_amdgcn_s_barrier();
        __builtin_amdgcn_sched_barrier(0);
        stage_tile(Kz + (size_t)(jbase + jt + 32) * 256, &sKb[1][0], wave, lane);
        stage_tile(Vz + (size_t)(jbase + jt + 32) * 256, &sVb[1][0], wave, lane);
        load_mask(maskG, transposed, R0, jbase + jt + 32, wave, quad, col, mvB);
        __builtin_amdgcn_sched_barrier(0);
        attn_tile(&sKb[0][0], &sVb[0][0], sP[wave], qf, mvA,
                  lane, col, quad, o, m, l);

        // ===== phase B: compute tile jt+32 (buf1, mvB); stage jt+64 =====
        asm volatile("s_waitcnt vmcnt(0)" ::: "memory");
        __builtin_amdgcn_s_barrier();
        __builtin_amdgcn_sched_barrier(0);
        if (jt + 64 < chunkKeys) {
            stage_tile(Kz + (size_t)(jbase + jt + 64) * 256, &sKb[0][0], wave, lane);
            stage_tile(Vz + (size_t)(jbase + jt + 64) * 256, &sVb[0][0], wave, lane);
            load_mask(maskG, transposed, R0, jbase + jt + 64, wave, quad, col, mvA);
        }
        __builtin_amdgcn_sched_barrier(0);
        attn_tile(&sKb[1][0], &sVb[1][0], sP[wave], qf, mvB,
                  lane, col, quad, o, m, l);
    }

    // ---- final l reduction (per-lane partials -> 16-lane row sums) ----
    #pragma unroll
    for (int r = 0; r < 4; ++r) {
        #pragma unroll
        for (int off = 1; off < 16; off <<= 1)
            l[r] += __shfl_xor(l[r], off);
    }

    #pragma unroll
    for (int dt = 0; dt < 16; ++dt)
        #pragma unroll
        for (int r = 0; r < 4; ++r) {
            const int row = R0 + wave * 16 + quad * 4 + r;
            PO[((size_t)split * M + row) * HD + dt * 16 + col] = o[dt][r];
        }
    if (col == 0) {
        #pragma unroll
        for (int r = 0; r < 4; ++r) {
            const int row = R0 + wave * 16 + quad * 4 + r;
            PM[(size_t)split * M + row] = m[r];
            PL[(size_t)split * M + row] = l[r];
        }
    }
}

// ---------------------------------------------------------------------------
__global__ void attn_combine(
    const float* __restrict__ PO, const float* __restrict__ PM,
    const float* __restrict__ PL, __hip_bfloat16* __restrict__ Out,
    int M, int nchunks)
{
    const int idx = blockIdx.x * 256 + threadIdx.x;
    const int row = idx >> 8;
    float mmax = -INFINITY;
    for (int c = 0; c < nchunks; ++c) mmax = fmaxf(mmax, PM[(size_t)c * M + row]);
    float denom = 0.f, acc = 0.f;
    for (int c = 0; c < nchunks; ++c) {
        const float w = __expf(PM[(size_t)c * M + row] - mmax);
        denom += PL[(size_t)c * M + row] * w;
        acc   += PO[(size_t)c * M * HD + idx] * w;
    }
    Out[idx] = __float2bfloat16(acc / denom);
}

// ---------------------------------------------------------------------------
__global__ void coords_fin(
    const float* __restrict__ coords, const float* __restrict__ origc,
    const float* __restrict__ xsum, const float* __restrict__ cnt,
    float* __restrict__ out, int n)
{
    const int i = blockIdx.x * 256 + threadIdx.x;
    if (i >= n * 3) return;
    const int node = i / 3;
    const float inv = 1.f / fmaxf(cnt[node], 1.f);
    out[i] = 0.25f * origc[i] + 0.75f * coords[i] + xsum[i] * inv;
}

// ---------------------------------------------------------------------------
extern "C" void kernel_launch(void* const* d_in, const int* in_sizes, int n_in,
                              void* d_out, int out_size, void* d_ws, size_t ws_size,
                              hipStream_t stream)
{
    const float* coords_lig = (const float*)d_in[0];
    const float* h_lig      = (const float*)d_in[1];
    const float* orig_lig   = (const float*)d_in[2];
    const float* origc_lig  = (const float*)d_in[3];
    const float* coords_rec = (const float*)d_in[4];
    const float* h_rec      = (const float*)d_in[5];
    const float* orig_rec   = (const float*)d_in[6];
    const float* origc_rec  = (const float*)d_in[7];
    const float* mask       = (const float*)d_in[8];
    const float* lig_ef     = (const float*)d_in[9];
    const float* rec_ef     = (const float*)d_in[10];
    const int* lig_src = (const int*)d_in[11];
    const int* lig_dst = (const int*)d_in[12];
    const int* rec_src = (const int*)d_in[13];
    const int* rec_dst = (const int*)d_in[14];
    const float* le_w1 = (const float*)d_in[15];
    const float* le_b1 = (const float*)d_in[16];
    const float* le_w2 = (const float*)d_in[17];
    const float* le_b2 = (const float*)d_in[18];
    const float* re_w1 = (const float*)d_in[19];
    const float* re_b1 = (const float*)d_in[20];
    const float* re_w2 = (const float*)d_in[21];
    const float* re_b2 = (const float*)d_in[22];
    const float* aql_w = (const float*)d_in[23];
    const float* akl_w = (const float*)d_in[24];
    const float* avl_w = (const float*)d_in[25];
    const float* aqr_w = (const float*)d_in[26];
    const float* akr_w = (const float*)d_in[27];
    const float* avr_w = (const float*)d_in[28];
    const float* nl_w1 = (const float*)d_in[29];
    const float* nl_b1 = (const float*)d_in[30];
    const float* nl_w2 = (const float*)d_in[31];
    const float* nl_b2 = (const float*)d_in[32];
    const float* nr_w1 = (const float*)d_in[33];
    const float* nr_b1 = (const float*)d_in[34];
    const float* nr_w2 = (const float*)d_in[35];
    const float* nr_b2 = (const float*)d_in[36];
    const float* cl_w1 = (const float*)d_in[37];
    const float* cl_b1 = (const float*)d_in[38];
    const float* cl_w2 = (const float*)d_in[39];
    const float* cl_b2 = (const float*)d_in[40];
    const float* cr_w1 = (const float*)d_in[41];
    const float* cr_b1 = (const float*)d_in[42];
    const float* cr_w2 = (const float*)d_in[43];
    const float* cr_b2 = (const float*)d_in[44];

    float* out = (float*)d_out;
    float* wsf = (float*)d_ws;

    // ---- fp32 accumulator + CSR zone ----
    const size_t AGGRL = 0;
    const size_t AGGRR = AGGRL + (size_t)N_LIG * HD;
    const size_t CNTL  = AGGRR + (size_t)N_REC * HD;
    const size_t CNTR  = CNTL + N_LIG;
    const size_t XSUML = CNTR + N_REC;
    const size_t XSUMR = XSUML + (size_t)N_LIG * 3;
    const size_t HISTL = XSUMR + (size_t)N_REC * 3;
    const size_t CURL  = HISTL + N_LIG;
    const size_t HISTR = CURL + N_LIG;
    const size_t CURR  = HISTR + N_REC;
    const size_t ZEND  = CURR + N_REC;          // zeroed through here
    const size_t ELISTL = ZEND;                 // not zeroed
    const size_t ELISTR = ELISTL + E_LIG_N;
    const size_t FEND   = ELISTR + E_REC_N;

    // ---- bf16 zone ----
    __hip_bfloat16* wsb = (__hip_bfloat16*)(wsf + FEND);
    const size_t QL  = 0;
    const size_t KL  = QL + (size_t)N_LIG * HD;   // unused (kept for layout)
    const size_t VL  = KL + (size_t)N_LIG * HD;   // unused
    const size_t QR  = VL + (size_t)N_LIG * HD;
    const size_t KR  = QR + (size_t)N_REC * HD;   // unused
    const size_t VR  = KR + (size_t)N_REC * HD;   // unused
    const size_t CRL = VR + (size_t)N_REC * HD;
    const size_t CRR = CRL + (size_t)N_LIG * HD;
    const size_t KZL = CRR + (size_t)N_REC * HD;          // K swizzled lig
    const size_t VZL = KZL + (size_t)N_LIG * HD;          // V swizzled lig
    const size_t KZR = VZL + (size_t)N_LIG * HD;          // K swizzled rec
    const size_t VZR = KZR + (size_t)N_REC * HD;          // V swizzled rec
    const size_t EW1SZ = (size_t)16 * 17 * 512;
    const size_t KW256 = (size_t)16 * 8 * 512;
    const size_t NW1SZ = (size_t)16 * 18 * 512;
    const size_t SW_EL1 = VZR + (size_t)N_REC * HD;
    const size_t SW_EL2 = SW_EL1 + EW1SZ;
    const size_t SW_EC1 = SW_EL2 + KW256;
    const size_t SW_NL1 = SW_EC1 + KW256;
    const size_t SW_NL2 = SW_NL1 + NW1SZ;
    const size_t SW_ER1 = SW_NL2 + KW256;
    const size_t SW_ER2 = SW_ER1 + EW1SZ;
    const size_t SW_EC1R = SW_ER2 + KW256;
    const size_t SW_NR1 = SW_EC1R + KW256;
    const size_t SW_NR2 = SW_NR1 + NW1SZ;
    const size_t SW_PQL = SW_NR2 + KW256;
    const size_t SW_PKL = SW_PQL + KW256;
    const size_t SW_PVL = SW_PKL + KW256;
    const size_t SW_PQR = SW_PVL + KW256;
    const size_t SW_PKR = SW_PQR + KW256;
    const size_t SW_PVR = SW_PKR + KW256;
    // pre-converted bf16 operand blobs
    const size_t HB_L  = SW_PVR + KW256;
    const size_t HB_R  = HB_L + (size_t)N_LIG * HD;
    const size_t EFB_L = HB_R + (size_t)N_REC * HD;
    const size_t EFB_R = EFB_L + (size_t)E_LIG_N * EFD;
    const size_t BF_END = EFB_R + (size_t)E_REC_N * EFD;

    // ---- split-K partial zone (fp32), dynamic splits ----
    float* wsp = (float*)(wsb + ((BF_END + 1) & ~(size_t)1));
    const size_t baseBytes = (size_t)((char*)wsp - (char*)d_ws);
    int SL = 16, SR = 4;
    {
        const size_t poElems16 = (size_t)16 * N_LIG * HD;
        const size_t need16 = baseBytes +
            (poElems16 + 2 * (size_t)16 * N_LIG) * sizeof(float);
        if (ws_size < need16) { SL = 8; SR = 2; }
    }
    const size_t PO_ = 0;
    const size_t PM_ = PO_ + (size_t)SL * N_LIG * HD;
    const size_t PL_ = PM_ + (size_t)SL * N_LIG;

    const size_t O_XL = 0;
    const size_t O_HL = O_XL + (size_t)N_LIG * 3;
    const size_t O_XR = O_HL + (size_t)N_LIG * HD;
    const size_t O_HR = O_XR + (size_t)N_REC * 3;

    // 1) zero atomic accumulators + CSR hist/cursors
    zero_kernel<<<((int)ZEND + 255) / 256, 256, 0, stream>>>(wsf, (int)ZEND);

    // 1a) fp32 -> bf16 operand blobs (h and edge features)
    f2b_kernel<<<(N_LIG * HD / 8 + 255) / 256, 256, 0, stream>>>(
        h_lig, wsb + HB_L, N_LIG * HD / 8);
    f2b_kernel<<<(N_REC * HD / 8 + 255) / 256, 256, 0, stream>>>(
        h_rec, wsb + HB_R, N_REC * HD / 8);
    f2b_kernel<<<(E_LIG_N * EFD / 8 + 255) / 256, 256, 0, stream>>>(
        lig_ef, wsb + EFB_L, E_LIG_N * EFD / 8);
    f2b_kernel<<<(E_REC_N * EFD / 8 + 255) / 256, 256, 0, stream>>>(
        rec_ef, wsb + EFB_R, E_REC_N * EFD / 8);

    // 1b) CSR build: dst-sorted edge permutations (also produces fp32 counts)
    hist_kernel<<<E_LIG_N / 256, 256, 0, stream>>>(lig_dst, (int*)(wsf + HISTL), E_LIG_N);
    hist_kernel<<<E_REC_N / 256, 256, 0, stream>>>(rec_dst, (int*)(wsf + HISTR), E_REC_N);
    scan_kernel<<<1, 256, 0, stream>>>((int*)(wsf + HISTL), (int*)(wsf + CURL),
                                       wsf + CNTL, N_LIG);
    scan_kernel<<<1, 256, 0, stream>>>((int*)(wsf + HISTR), (int*)(wsf + CURR),
                                       wsf + CNTR, N_REC);
    scatter_kernel<<<E_LIG_N / 256, 256, 0, stream>>>(
        lig_dst, (int*)(wsf + CURL), (int*)(wsf + ELISTL), E_LIG_N);
    scatter_kernel<<<E_REC_N / 256, 256, 0, stream>>>(
        rec_dst, (int*)(wsf + CURR), (int*)(wsf + ELISTR), E_REC_N);

    // 2) weight swizzles
    wt_swz<<<16 * 17, 256, 0, stream>>>(le_w1, wsb + SW_EL1, EIN, 17);
    wt_swz<<<16 * 8,  256, 0, stream>>>(le_w2, wsb + SW_EL2, 256, 8);
    wt_swz<<<16 * 8,  256, 0, stream>>>(cl_w1, wsb + SW_EC1, 256, 8);
    wt_swz<<<16 * 18, 256, 0, stream>>>(nl_w1, wsb + SW_NL1, 576, 18);
    wt_swz<<<16 * 8,  256, 0, stream>>>(nl_w2, wsb + SW_NL2, 256, 8);
    wt_swz<<<16 * 17, 256, 0, stream>>>(re_w1, wsb + SW_ER1, EIN, 17);
    wt_swz<<<16 * 8,  256, 0, stream>>>(re_w2, wsb + SW_ER2, 256, 8);
    wt_swz<<<16 * 8,  256, 0, stream>>>(cr_w1, wsb + SW_EC1R, 256, 8);
    wt_swz<<<16 * 18, 256, 0, stream>>>(nr_w1, wsb + SW_NR1, 576, 18);
    wt_swz<<<16 * 8,  256, 0, stream>>>(nr_w2, wsb + SW_NR2, 256, 8);
    wt_swz<<<16 * 8,  256, 0, stream>>>(aql_w, wsb + SW_PQL, 256, 8);
    wt_swz<<<16 * 8,  256, 0, stream>>>(akl_w, wsb + SW_PKL, 256, 8);
    wt_swz<<<16 * 8,  256, 0, stream>>>(avl_w, wsb + SW_PVL, 256, 8);
    wt_swz<<<16 * 8,  256, 0, stream>>>(aqr_w, wsb + SW_PQR, 256, 8);
    wt_swz<<<16 * 8,  256, 0, stream>>>(akr_w, wsb + SW_PKR, 256, 8);
    wt_swz<<<16 * 8,  256, 0, stream>>>(avr_w, wsb + SW_PVR, 256, 8);

    // 3) edge MFMA kernels (32 edges/block, dst-sorted, segmented atomics)
    edge_mfma<<<E_LIG_N / 32, 256, 0, stream>>>(
        coords_lig, wsb + HB_L, wsb + EFB_L, lig_src, lig_dst,
        (const int*)(wsf + ELISTL),
        wsb + SW_EL1, le_b1, wsb + SW_EL2, le_b2, wsb + SW_EC1, cl_b1, cl_w2, cl_b2,
        wsf + AGGRL, wsf + XSUML);
    edge_mfma<<<E_REC_N / 32, 256, 0, stream>>>(
        coords_rec, wsb + HB_R, wsb + EFB_R, rec_src, rec_dst,
        (const int*)(wsf + ELISTR),
        wsb + SW_ER1, re_b1, wsb + SW_ER2, re_b2, wsb + SW_EC1R, cr_b1, cr_w2, cr_b2,
        wsf + AGGRR, wsf + XSUMR);

    // 4) fused q/k/v projections (K/V written directly in fragment-blob order)
    qkv_proj<<<N_LIG / 32, 256, 0, stream>>>(
        wsb + HB_L, wsb + SW_PQL, wsb + SW_PKL, wsb + SW_PVL,
        wsb + QL, wsb + KZL, wsb + VZL);
    qkv_proj<<<N_REC / 32, 256, 0, stream>>>(
        wsb + HB_R, wsb + SW_PQR, wsb + SW_PKR, wsb + SW_PVR,
        wsb + QR, wsb + KZR, wsb + VZR);

    // 5) MFMA flash attention, split-K + combine
    {
        dim3 gl(N_LIG / 128, SL);
        attn_mfma<<<gl, 512, 0, stream>>>(wsb + QL, wsb + KZR, wsb + VZR, mask,
                                          wsp + PO_, wsp + PM_, wsp + PL_,
                                          N_LIG, N_REC / SL, 0);
        attn_combine<<<N_LIG, 256, 0, stream>>>(
            wsp + PO_, wsp + PM_, wsp + PL_, wsb + CRL, N_LIG, SL);

        dim3 gr(N_REC / 128, SR);
        attn_mfma<<<gr, 512, 0, stream>>>(wsb + QR, wsb + KZL, wsb + VZL, mask,
                                          wsp + PO_, wsp + PM_, wsp + PL_,
                                          N_REC, N_LIG / SR, 1);
        attn_combine<<<N_REC, 256, 0, stream>>>(
            wsp + PO_, wsp + PM_, wsp + PL_, wsb + CRR, N_REC, SR);
    }

    // 6) coordinate outputs
    coords_fin<<<(N_LIG * 3 + 255) / 256, 256, 0, stream>>>(
        coords_lig, origc_lig, wsf + XSUML, wsf + CNTL, out + O_XL, N_LIG);
    coords_fin<<<(N_REC * 3 + 255) / 256, 256, 0, stream>>>(
        coords_rec, origc_rec, wsf + XSUMR, wsf + CNTR, out + O_XR, N_REC);

    // 7) node MFMA kernels
    node_mfma<<<N_LIG / 32, 256, 0, stream>>>(
        wsf + AGGRL, wsf + CNTL, wsb + CRL, orig_lig, h_lig,
        wsb + SW_NL1, nl_b1, wsb + SW_NL2, nl_b2, out + O_HL);
    node_mfma<<<N_REC / 32, 256, 0, stream>>>(
        wsf + AGGRR, wsf + CNTR, wsb + CRR, orig_rec, h_rec,
        wsb + SW_NR1, nr_b1, wsb + SW_NR2, nr_b2, out + O_HR);

    (void)in_sizes; (void)n_in; (void)out_size;
}

// Round 15
// 1291.274 us; speedup vs baseline: 1.0399x; 1.0024x over previous
//
#include <hip/hip_runtime.h>
#include <hip/hip_bf16.h>

// ---------------------------------------------------------------------------
// IEGMN layer, MI355X round-23: r22 (session best, 1294 us) + mask-sparsity
// flags. A scan kernel builds a 32x32-granular "any-zero" flag grid over the
// fp32 mask ONCE; attention tiles check 4 block-uniform flags and skip all
// mask loads + mask FMAs when the tile is all-ones (exact: 1*s-1000*0 = s).
// Arbitrary masks still take the exact original inline path. For this
// workload's all-ones mask this removes 536 MB of HBM mask traffic (268 MB
// of which was transposed scalar loads) at the cost of one 268 MB scan.
//  * mfma_gemm: even/odd depth-2 prefetch (r19, proven)
//  * edge_mfma: 32 edges/block, dst-sorted CSR order, segmented atomics
//  * qkv_proj: fused Q/K/V, K/V stored directly in fragment-blob order
//  * attn_mfma: 8 waves x 16 q-rows, glds LDS double-buffer, defer-max
// ---------------------------------------------------------------------------

#define N_LIG   4096
#define N_REC   16384
#define E_LIG_N 65536
#define E_REC_N 262144
#define HD      256
#define ORIGD   64
#define EFD     16
#define NSIG    15
#define EIN     543      // 2*HD + EFD + NSIG
#define XP      552      // edge sX pitch (bf16 elems), 544 used
#define XPN     584      // node sX pitch, 576 used
#define XPP     264      // proj sX pitch, 256 used
#define FP      264      // fp32 reuse pitch inside sX (floats)
#define FCOLS   (N_REC / 32)   // 512 flag columns (rec 32-groups)

typedef __bf16 bf16x8 __attribute__((ext_vector_type(8)));
typedef float  f32x4  __attribute__((ext_vector_type(4)));

__device__ __forceinline__ float lrelu(float x) { return x > 0.f ? x : 0.01f * x; }
__device__ __forceinline__ unsigned short f2bu(float f) {
    __hip_bfloat16 h = __float2bfloat16(f);
    return *reinterpret_cast<unsigned short*>(&h);
}

// Direct global->LDS async copy, 16B per lane.
__device__ __forceinline__ void glds16(const void* g, void* l) {
    __builtin_amdgcn_global_load_lds(
        (const __attribute__((address_space(1))) void*)g,
        (__attribute__((address_space(3))) void*)l,
        16, 0, 0);
}

// Stage 16KB (one 32-key K or V tile) into LDS with 512 threads: 2 glds/thr.
__device__ __forceinline__ void stage_tile(
    const __hip_bfloat16* g, unsigned short* l, int wave, int lane)
{
    #pragma unroll
    for (int i = 0; i < 2; ++i) {
        const __hip_bfloat16* gp = g + (size_t)(i * 512 + wave * 64 + lane) * 8;
        unsigned short* lp = l + (i * 512 + wave * 64) * 8;  // wave-uniform base
        glds16(gp, lp);
    }
}

// ---------------------------------------------------------------------------
// Shared 32xKx256 GEMM core. Even/odd depth-2 pipeline: weights/A-fragments
// for step ks are loaded two K-steps before use; no register rotation.
__device__ __forceinline__ void mfma_gemm(
    const unsigned short* sA, int pitch,
    const __hip_bfloat16* Wswz, int KS, int lane, f32x4 acc[2][4])
{
    const int col = lane & 15, quad = lane >> 4;
    const unsigned short* a0p = sA + (size_t)col * pitch + quad * 8;
    const unsigned short* a1p = sA + (size_t)(16 + col) * pitch + quad * 8;
    const __hip_bfloat16* wp = Wswz + lane * 8;

    bf16x8 bE[4], bO[4], aE0, aE1, aO0, aO1;
    #pragma unroll
    for (int nt = 0; nt < 4; ++nt) {
        bE[nt] = *reinterpret_cast<const bf16x8*>(wp + (size_t)nt * KS * 512);
        bO[nt] = *reinterpret_cast<const bf16x8*>(wp + ((size_t)nt * KS + 1) * 512);
    }
    aE0 = *reinterpret_cast<const bf16x8*>(a0p);
    aE1 = *reinterpret_cast<const bf16x8*>(a1p);
    aO0 = *reinterpret_cast<const bf16x8*>(a0p + 32);
    aO1 = *reinterpret_cast<const bf16x8*>(a1p + 32);

    int ks = 0;
    for (; ks + 2 <= KS; ks += 2) {
        // ---- even step: compute ks, prefetch ks+2 ----
        #pragma unroll
        for (int nt = 0; nt < 4; ++nt) {
            acc[0][nt] = __builtin_amdgcn_mfma_f32_16x16x32_bf16(aE0, bE[nt], acc[0][nt], 0, 0, 0);
            acc[1][nt] = __builtin_amdgcn_mfma_f32_16x16x32_bf16(aE1, bE[nt], acc[1][nt], 0, 0, 0);
        }
        if (ks + 2 < KS) {
            #pragma unroll
            for (int nt = 0; nt < 4; ++nt)
                bE[nt] = *reinterpret_cast<const bf16x8*>(
                    wp + ((size_t)nt * KS + ks + 2) * 512);
            aE0 = *reinterpret_cast<const bf16x8*>(a0p + (ks + 2) * 32);
            aE1 = *reinterpret_cast<const bf16x8*>(a1p + (ks + 2) * 32);
        }
        // ---- odd step: compute ks+1, prefetch ks+3 ----
        #pragma unroll
        for (int nt = 0; nt < 4; ++nt) {
            acc[0][nt] = __builtin_amdgcn_mfma_f32_16x16x32_bf16(aO0, bO[nt], acc[0][nt], 0, 0, 0);
            acc[1][nt] = __builtin_amdgcn_mfma_f32_16x16x32_bf16(aO1, bO[nt], acc[1][nt], 0, 0, 0);
        }
        if (ks + 3 < KS) {
            #pragma unroll
            for (int nt = 0; nt < 4; ++nt)
                bO[nt] = *reinterpret_cast<const bf16x8*>(
                    wp + ((size_t)nt * KS + ks + 3) * 512);
            aO0 = *reinterpret_cast<const bf16x8*>(a0p + (ks + 3) * 32);
            aO1 = *reinterpret_cast<const bf16x8*>(a1p + (ks + 3) * 32);
        }
    }
    if (ks < KS) {   // odd-KS tail (even slot)
        #pragma unroll
        for (int nt = 0; nt < 4; ++nt) {
            acc[0][nt] = __builtin_amdgcn_mfma_f32_16x16x32_bf16(aE0, bE[nt], acc[0][nt], 0, 0, 0);
            acc[1][nt] = __builtin_amdgcn_mfma_f32_16x16x32_bf16(aE1, bE[nt], acc[1][nt], 0, 0, 0);
        }
    }
}

// ---------------------------------------------------------------------------
__global__ void zero_kernel(float* __restrict__ p, int n) {
    int i = blockIdx.x * 256 + threadIdx.x;
    if (i < n) p[i] = 0.f;
}

// ---------------------------------------------------------------------------
// Mask scan: set F[ligRow32][recCol32] = 1 if any element of the 32x32 mask
// tile differs from 1.0. 16 contiguous floats per thread (fits one tile).
__global__ void scanmask_kernel(const float* __restrict__ mask,
                                int* __restrict__ F)
{
    const size_t t = (size_t)blockIdx.x * 256 + threadIdx.x;
    const int r  = (int)(t >> 10);            // N_REC/16 = 1024 chunks per row
    const int c0 = ((int)t & 1023) * 16;
    const float4* p = reinterpret_cast<const float4*>(
        &mask[(size_t)r * N_REC + c0]);
    bool ok = true;
    #pragma unroll
    for (int i = 0; i < 4; ++i) {
        const float4 v = p[i];
        ok = ok && (v.x == 1.f) && (v.y == 1.f) && (v.z == 1.f) && (v.w == 1.f);
    }
    if (!ok) atomicOr(&F[(r >> 5) * FCOLS + (c0 >> 5)], 1);
}

// ---------------------------------------------------------------------------
// fp32 -> bf16 blob, 8 elems/thread (vectorized).
__global__ void f2b_kernel(const float* __restrict__ src,
                           __hip_bfloat16* __restrict__ dst, int n8) {
    const int i = blockIdx.x * 256 + threadIdx.x;
    if (i >= n8) return;
    const float4 a = *reinterpret_cast<const float4*>(src + (size_t)i * 8);
    const float4 b = *reinterpret_cast<const float4*>(src + (size_t)i * 8 + 4);
    ushort4 u0 = { f2bu(a.x), f2bu(a.y), f2bu(a.z), f2bu(a.w) };
    ushort4 u1 = { f2bu(b.x), f2bu(b.y), f2bu(b.z), f2bu(b.w) };
    unsigned short* d = (unsigned short*)dst + (size_t)i * 8;
    *reinterpret_cast<ushort4*>(d)     = u0;
    *reinterpret_cast<ushort4*>(d + 4) = u1;
}

// ---------------------------------------------------------------------------
// CSR build: histogram -> scan -> scatter (dst-sorted edge permutation).
__global__ void hist_kernel(const int* __restrict__ dst, int* __restrict__ hist, int n) {
    int i = blockIdx.x * 256 + threadIdx.x;
    if (i < n) atomicAdd(&hist[dst[i]], 1);
}

__global__ __launch_bounds__(256) void scan_kernel(
    const int* __restrict__ hist, int* __restrict__ cur,
    float* __restrict__ cntf, int n)
{
    __shared__ int part[256];
    const int tid = threadIdx.x;
    const int per = n >> 8;            // n is 4096 or 16384
    const int base = tid * per;
    int s = 0;
    for (int i = 0; i < per; ++i) s += hist[base + i];
    part[tid] = s;
    __syncthreads();
    #pragma unroll
    for (int off = 1; off < 256; off <<= 1) {
        int v = (tid >= off) ? part[tid - off] : 0;
        __syncthreads();
        part[tid] += v;
        __syncthreads();
    }
    int run = part[tid] - s;           // exclusive prefix of this chunk
    for (int i = 0; i < per; ++i) {
        const int h = hist[base + i];
        cur[base + i]  = run;
        cntf[base + i] = (float)h;
        run += h;
    }
}

__global__ void scatter_kernel(const int* __restrict__ dst, int* __restrict__ cur,
                               int* __restrict__ elist, int n) {
    int i = blockIdx.x * 256 + threadIdx.x;
    if (i < n) { int p = atomicAdd(&cur[dst[i]], 1); elist[p] = i; }
}

// ---------------------------------------------------------------------------
__global__ void wt_swz(const float* __restrict__ src,
                       __hip_bfloat16* __restrict__ dst, int K, int KS) {
    const int g  = blockIdx.x / KS;
    const int ks = blockIdx.x % KS;
    for (int i = threadIdx.x; i < 512; i += 256) {
        const int lane = i >> 3, j = i & 7;
        const int n = g * 16 + (lane & 15);
        const int k = ks * 32 + (lane >> 4) * 8 + j;
        const float v = (k < K) ? src[(size_t)k * 256 + n] : 0.f;
        dst[((size_t)(g * KS + ks) * 64 + lane) * 8 + j] = __float2bfloat16(v);
    }
}

// ---------------------------------------------------------------------------
// Edge MFMA kernel: 32 edges/block, edges taken in dst-sorted order (elist).
// (r15 structure; measured 232 us rec / MfmaUtil 27%.)
__global__ __launch_bounds__(256, 4) void edge_mfma(
    const float* __restrict__ coords, const __hip_bfloat16* __restrict__ hb,
    const __hip_bfloat16* __restrict__ efb,
    const int* __restrict__ src, const int* __restrict__ dst,
    const int* __restrict__ elist,
    const __hip_bfloat16* __restrict__ W1s, const float* __restrict__ b1,
    const __hip_bfloat16* __restrict__ W2s, const float* __restrict__ b2,
    const __hip_bfloat16* __restrict__ Wc1s, const float* __restrict__ bc1,
    const float* __restrict__ wc2v, const float* __restrict__ bc2,
    float* __restrict__ aggr, float* __restrict__ xsum)
{
    __shared__ unsigned short sX[32][XP];     // also reused as fp32 [32][FP]
    __shared__ float sXrel[32][3];
    __shared__ int   sDst[32];
    __shared__ int   sSrc[32];
    __shared__ int   sE[32];
    __shared__ float sRedW[4][32];
    __shared__ float sPv[32];

    const int tid  = threadIdx.x;
    const int lane = tid & 63;
    const int wave = tid >> 6;
    const int col  = lane & 15;
    const int quad = lane >> 4;
    const int e0   = blockIdx.x * 32;

    // ---- edge meta: permuted id, endpoints, x_rel, RBF ----
    if (tid < 32) {
        const int e = elist[e0 + tid];
        const int s = src[e], d = dst[e];
        sE[tid] = e; sSrc[tid] = s; sDst[tid] = d;
        float d2 = 0.f;
        #pragma unroll
        for (int c = 0; c < 3; ++c) {
            const float xr = coords[s * 3 + c] - coords[d * 3 + c];
            sXrel[tid][c] = xr;
            d2 += xr * xr;
        }
        float sig = 1.0f;
        #pragma unroll
        for (int si = 0; si < NSIG; ++si) {
            sX[tid][528 + si] = f2bu(__expf(-d2 / sig));
            sig *= 1.5f;
        }
        sX[tid][543] = 0;
    }
    __syncthreads();

    // ---- gather h[src], h[dst] (bf16, uint4 copies) ----
    for (int i = tid; i < 32 * 64; i += 256) {
        const int row = i >> 6, c = i & 63;
        const int node = (c < 32) ? sSrc[row] : sDst[row];
        const int chunk = c & 31;
        *reinterpret_cast<uint4*>(&sX[row][(c < 32 ? 0 : 256) + chunk * 8]) =
            *reinterpret_cast<const uint4*>(&hb[(size_t)node * HD + chunk * 8]);
    }
    // ---- gather edge features (bf16, permuted rows) ----
    if (tid < 64) {
        const int row = tid >> 1, hh = tid & 1;
        *reinterpret_cast<uint4*>(&sX[row][512 + hh * 8]) =
            *reinterpret_cast<const uint4*>(&efb[(size_t)sE[row] * EFD + hh * 8]);
    }
    __syncthreads();

    f32x4 acc[2][4];
    f32x4 macc[2][4];   // message accumulators, survive the coords GEMM

    // ---- GEMM1: [32 x 544] @ W1 -> hidden, lrelu ----
    #pragma unroll
    for (int nt = 0; nt < 4; ++nt) {
        const float bv = b1[wave * 64 + nt * 16 + col];
        acc[0][nt] = { bv, bv, bv, bv };
        acc[1][nt] = { bv, bv, bv, bv };
    }
    mfma_gemm(&sX[0][0], XP, W1s + (size_t)(wave * 4) * 17 * 512, 17, lane, acc);
    __syncthreads();
    #pragma unroll
    for (int mt = 0; mt < 2; ++mt)
        #pragma unroll
        for (int nt = 0; nt < 4; ++nt)
            #pragma unroll
            for (int r = 0; r < 4; ++r)
                sX[mt * 16 + quad * 4 + r][wave * 64 + nt * 16 + col] =
                    f2bu(lrelu(acc[mt][nt][r]));
    __syncthreads();

    // ---- GEMM2: hidden @ W2 -> msg (kept fp32 in macc) ----
    #pragma unroll
    for (int nt = 0; nt < 4; ++nt) {
        const float bv = b2[wave * 64 + nt * 16 + col];
        macc[0][nt] = { bv, bv, bv, bv };
        macc[1][nt] = { bv, bv, bv, bv };
    }
    mfma_gemm(&sX[0][0], XP, W2s + (size_t)(wave * 4) * 8 * 512, 8, lane, macc);
    __syncthreads();
    #pragma unroll
    for (int mt = 0; mt < 2; ++mt)
        #pragma unroll
        for (int nt = 0; nt < 4; ++nt)
            #pragma unroll
            for (int r = 0; r < 4; ++r)
                sX[mt * 16 + quad * 4 + r][wave * 64 + nt * 16 + col] =
                    f2bu(macc[mt][nt][r]);
    __syncthreads();

    // ---- GEMM3: msg @ Wc1 -> lrelu -> dot wc2 (per-edge scalar p) ----
    #pragma unroll
    for (int nt = 0; nt < 4; ++nt) {
        const float bv = bc1[wave * 64 + nt * 16 + col];
        acc[0][nt] = { bv, bv, bv, bv };
        acc[1][nt] = { bv, bv, bv, bv };
    }
    mfma_gemm(&sX[0][0], XP, Wc1s + (size_t)(wave * 4) * 8 * 512, 8, lane, acc);
    float w2l[4];
    #pragma unroll
    for (int nt = 0; nt < 4; ++nt) w2l[nt] = wc2v[wave * 64 + nt * 16 + col];
    #pragma unroll
    for (int mt = 0; mt < 2; ++mt) {
        float pr[4] = { 0.f, 0.f, 0.f, 0.f };
        #pragma unroll
        for (int nt = 0; nt < 4; ++nt)
            #pragma unroll
            for (int r = 0; r < 4; ++r)
                pr[r] += lrelu(acc[mt][nt][r]) * w2l[nt];
        #pragma unroll
        for (int r = 0; r < 4; ++r) {
            #pragma unroll
            for (int off = 1; off < 16; off <<= 1) pr[r] += __shfl_xor(pr[r], off);
        }
        if (col == 0)
            #pragma unroll
            for (int r = 0; r < 4; ++r)
                sRedW[wave][mt * 16 + quad * 4 + r] = pr[r];
    }
    __syncthreads();

    // ---- dump fp32 messages into LDS (reuse sX), gather p per edge ----
    float* sF = reinterpret_cast<float*>(&sX[0][0]);   // [32][FP] floats
    #pragma unroll
    for (int mt = 0; mt < 2; ++mt)
        #pragma unroll
        for (int nt = 0; nt < 4; ++nt)
            #pragma unroll
            for (int r = 0; r < 4; ++r)
                sF[(mt * 16 + quad * 4 + r) * FP + wave * 64 + nt * 16 + col] =
                    macc[mt][nt][r];
    if (tid < 32)
        sPv[tid] = sRedW[0][tid] + sRedW[1][tid] + sRedW[2][tid] + sRedW[3][tid]
                 + bc2[0];
    __syncthreads();

    // ---- segmented flush: one atomic per (distinct dst x column) ----
    {
        const int c = tid;               // 256 threads = 256 columns
        float av = 0.f;
        int dprev = sDst[0];
        for (int row = 0; row < 32; ++row) {
            const int d = sDst[row];     // uniform across block -> no divergence
            if (d != dprev) {
                atomicAdd(&aggr[(size_t)dprev * HD + c], av);
                av = 0.f; dprev = d;
            }
            av += sF[row * FP + c];
        }
        atomicAdd(&aggr[(size_t)dprev * HD + c], av);
    }
    if (tid < 3) {
        const int c = tid;
        float av = 0.f;
        int dprev = sDst[0];
        for (int row = 0; row < 32; ++row) {
            const int d = sDst[row];
            if (d != dprev) {
                atomicAdd(&xsum[(size_t)dprev * 3 + c], av);
                av = 0.f; dprev = d;
            }
            av += sXrel[row][c] * sPv[row];
        }
        atomicAdd(&xsum[(size_t)dprev * 3 + c], av);
    }
}

// ---------------------------------------------------------------------------
// Node MFMA kernel: 32 nodes/block (unchanged).
__global__ __launch_bounds__(256, 4) void node_mfma(
    const float* __restrict__ aggr, const float* __restrict__ cnt,
    const __hip_bfloat16* __restrict__ cross, const float* __restrict__ orig,
    const float* __restrict__ hfeat,
    const __hip_bfloat16* __restrict__ WN1s, const float* __restrict__ b1,
    const __hip_bfloat16* __restrict__ WN2s, const float* __restrict__ b2,
    float* __restrict__ out)
{
    __shared__ unsigned short sXn[32][XPN];
    __shared__ float sInv[32];

    const int tid  = threadIdx.x;
    const int lane = tid & 63;
    const int wave = tid >> 6;
    const int col  = lane & 15;
    const int quad = lane >> 4;
    const int r0   = blockIdx.x * 32;

    if (tid < 32) sInv[tid] = 1.f / fmaxf(cnt[r0 + tid], 1.f);
    __syncthreads();

    for (int i = tid; i < 32 * 64; i += 256) {
        const int row = i >> 6, c4 = i & 63;
        const float inv = sInv[row];
        const float4 v = *reinterpret_cast<const float4*>(
            &aggr[(size_t)(r0 + row) * HD + c4 * 4]);
        ushort4 u = { f2bu(v.x * inv), f2bu(v.y * inv), f2bu(v.z * inv), f2bu(v.w * inv) };
        *reinterpret_cast<ushort4*>(&sXn[row][c4 * 4]) = u;
    }
    for (int i = tid; i < 32 * 64; i += 256) {
        const int row = i >> 6, c4 = i & 63;
        const ushort4 u = *reinterpret_cast<const ushort4*>(
            &cross[(size_t)(r0 + row) * HD + c4 * 4]);
        *reinterpret_cast<ushort4*>(&sXn[row][256 + c4 * 4]) = u;
    }
    for (int i = tid; i < 32 * 16; i += 256) {
        const int row = i >> 4, c4 = i & 15;
        const float4 v = *reinterpret_cast<const float4*>(
            &orig[(size_t)(r0 + row) * ORIGD + c4 * 4]);
        ushort4 u = { f2bu(v.x), f2bu(v.y), f2bu(v.z), f2bu(v.w) };
        *reinterpret_cast<ushort4*>(&sXn[row][512 + c4 * 4]) = u;
    }
    __syncthreads();

    f32x4 acc[2][4];

    #pragma unroll
    for (int nt = 0; nt < 4; ++nt) {
        const float bv = b1[wave * 64 + nt * 16 + col];
        acc[0][nt] = { bv, bv, bv, bv };
        acc[1][nt] = { bv, bv, bv, bv };
    }
    mfma_gemm(&sXn[0][0], XPN, WN1s + (size_t)(wave * 4) * 18 * 512, 18, lane, acc);
    __syncthreads();
    #pragma unroll
    for (int mt = 0; mt < 2; ++mt)
        #pragma unroll
        for (int nt = 0; nt < 4; ++nt)
            #pragma unroll
            for (int r = 0; r < 4; ++r)
                sXn[mt * 16 + quad * 4 + r][wave * 64 + nt * 16 + col] =
                    f2bu(lrelu(acc[mt][nt][r]));
    __syncthreads();

    #pragma unroll
    for (int nt = 0; nt < 4; ++nt) {
        const float bv = b2[wave * 64 + nt * 16 + col];
        acc[0][nt] = { bv, bv, bv, bv };
        acc[1][nt] = { bv, bv, bv, bv };
    }
    mfma_gemm(&sXn[0][0], XPN, WN2s + (size_t)(wave * 4) * 8 * 512, 8, lane, acc);
    #pragma unroll
    for (int mt = 0; mt < 2; ++mt)
        #pragma unroll
        for (int nt = 0; nt < 4; ++nt)
            #pragma unroll
            for (int r = 0; r < 4; ++r) {
                const int g = r0 + mt * 16 + quad * 4 + r;
                const int n = wave * 64 + nt * 16 + col;
                out[(size_t)g * HD + n] =
                    0.5f * acc[mt][nt][r] + 0.5f * hfeat[(size_t)g * HD + n];
            }
}

// ---------------------------------------------------------------------------
// Fused Q/K/V projection: stage X once, run 3 GEMMs from the same LDS tile.
// K and V are written DIRECTLY in the attention fragment-blob layouts.
__global__ __launch_bounds__(256, 4) void qkv_proj(
    const __hip_bfloat16* __restrict__ Xb,
    const __hip_bfloat16* __restrict__ Wq, const __hip_bfloat16* __restrict__ Wk,
    const __hip_bfloat16* __restrict__ Wv,
    __hip_bfloat16* __restrict__ Q, __hip_bfloat16* __restrict__ Kz,
    __hip_bfloat16* __restrict__ Vz)
{
    __shared__ unsigned short sXp[32][XPP];
    const int tid  = threadIdx.x;
    const int lane = tid & 63;
    const int wave = tid >> 6;
    const int col  = lane & 15;
    const int quad = lane >> 4;
    const int r0   = blockIdx.x * 32;

    for (int i = tid; i < 32 * 32; i += 256) {
        const int row = i >> 5, c = i & 31;
        *reinterpret_cast<uint4*>(&sXp[row][c * 8]) =
            *reinterpret_cast<const uint4*>(&Xb[(size_t)(r0 + row) * HD + c * 8]);
    }
    __syncthreads();

    f32x4 acc[2][4];
    #pragma unroll
    for (int p = 0; p < 3; ++p) {
        const __hip_bfloat16* Ws = (p == 0) ? Wq : (p == 1) ? Wk : Wv;
        #pragma unroll
        for (int nt = 0; nt < 4; ++nt) {
            acc[0][nt] = { 0.f, 0.f, 0.f, 0.f };
            acc[1][nt] = { 0.f, 0.f, 0.f, 0.f };
        }
        mfma_gemm(&sXp[0][0], XPP, Ws + (size_t)(wave * 4) * 8 * 512, 8, lane, acc);
        #pragma unroll
        for (int mt = 0; mt < 2; ++mt)
            #pragma unroll
            for (int nt = 0; nt < 4; ++nt)
                #pragma unroll
                for (int r = 0; r < 4; ++r) {
                    float v = acc[mt][nt][r];
                    const int row = r0 + mt * 16 + quad * 4 + r;
                    const int c   = wave * 64 + nt * 16 + col;
                    if (p == 0) {
                        Q[(size_t)row * HD + c] = __float2bfloat16(lrelu(v));
                    } else if (p == 1) {
                        // K blob: ((kt*8+s)*512 + (cc8*16+rr)*8 + j)
                        const int kt = row >> 4, rr = row & 15;
                        const int s  = c >> 5, cc8 = (c >> 3) & 3, j = c & 7;
                        Kz[(size_t)(kt * 8 + s) * 512 + (cc8 * 16 + rr) * 8 + j] =
                            __float2bfloat16(lrelu(v));
                    } else {
                        // V blob: (((jt*16+dt)*64 + (rowin>>3)*16 + cc)*8 + (rowin&7))
                        const int jt = row >> 5, rowin = row & 31;
                        const int dt = c >> 4, cc = c & 15;
                        Vz[((size_t)(jt * 16 + dt) * 64 + (rowin >> 3) * 16 + cc) * 8
                           + (rowin & 7)] = __float2bfloat16(v);
                    }
                }
    }
}

// ---------------------------------------------------------------------------
// One 32-key tile with defer-max online softmax (THR=8); l kept as per-lane
// partials (reduced once at kernel end). Mask handled via the 32x32 any-zero
// flag grid: all-ones tiles (block-uniform test) skip all mask loads/FMAs.
__device__ __forceinline__ void attn_tile(
    const unsigned short* sK, const unsigned short* sV,
    unsigned short (*sPw)[40], const bf16x8 qf[8],
    const float* __restrict__ maskG, const int* __restrict__ Fz,
    int transposed, int R0, int j0,
    int lane, int wave, int col, int quad, f32x4 o[16], float m[4], float l[4])
{
    // ---- S = Q K^T ----
    f32x4 sacc[2];
    sacc[0][0]=0.f; sacc[0][1]=0.f; sacc[0][2]=0.f; sacc[0][3]=0.f;
    sacc[1][0]=0.f; sacc[1][1]=0.f; sacc[1][2]=0.f; sacc[1][3]=0.f;
    #pragma unroll
    for (int t = 0; t < 2; ++t) {
        #pragma unroll
        for (int s = 0; s < 8; ++s) {
            bf16x8 kf = *reinterpret_cast<const bf16x8*>(
                &sK[(t * 8 + s) * 512 + lane * 8]);
            sacc[t] = __builtin_amdgcn_mfma_f32_16x16x32_bf16(qf[s], kf, sacc[t], 0, 0, 0);
        }
    }

    // ---- mask (flag-gated; block-uniform branch) ----
    int anyz;
    if (!transposed) {
        // q rows = lig R0..R0+127 (4 row32 groups), keys = rec j0..j0+31
        const int base = (R0 >> 5) * FCOLS + (j0 >> 5);
        anyz = Fz[base] | Fz[base + FCOLS] | Fz[base + 2 * FCOLS]
             | Fz[base + 3 * FCOLS];
    } else {
        // keys = lig j0..j0+31 (1 row32 group), q cols = rec R0..R0+127
        const int base = (j0 >> 5) * FCOLS + (R0 >> 5);
        anyz = Fz[base] | Fz[base + 1] | Fz[base + 2] | Fz[base + 3];
    }
    float a[2][4];
    if (anyz) {
        #pragma unroll
        for (int t = 0; t < 2; ++t)
            #pragma unroll
            for (int r = 0; r < 4; ++r) {
                float mv;
                if (!transposed)
                    mv = maskG[(size_t)(R0 + wave * 16 + quad * 4 + r) * N_REC
                               + j0 + col + 16 * t];
                else
                    mv = maskG[(size_t)(j0 + col + 16 * t) * N_REC
                               + R0 + wave * 16 + quad * 4 + r];
                a[t][r] = mv * sacc[t][r] - 1000.f * (1.f - mv);
            }
    } else {
        #pragma unroll
        for (int t = 0; t < 2; ++t)
            #pragma unroll
            for (int r = 0; r < 4; ++r)
                a[t][r] = sacc[t][r];
    }

    // ---- defer-max: rescale only when local max grows past m+8 ----
    float lm[4];
    #pragma unroll
    for (int r = 0; r < 4; ++r) lm[r] = fmaxf(a[0][r], a[1][r]);
    float w = lm[0] - m[0];
    #pragma unroll
    for (int r = 1; r < 4; ++r) w = fmaxf(w, lm[r] - m[r]);
    if (!__all(w <= 8.f)) {
        #pragma unroll
        for (int r = 0; r < 4; ++r) {
            float mx = lm[r];
            #pragma unroll
            for (int off = 1; off < 16; off <<= 1)
                mx = fmaxf(mx, __shfl_xor(mx, off));
            const float mn = fmaxf(m[r], mx);
            const float c  = __expf(m[r] - mn);
            m[r] = mn;
            l[r] *= c;
            #pragma unroll
            for (int dt = 0; dt < 16; ++dt) o[dt][r] *= c;
        }
    }

    // ---- P = exp(a - m), per-lane l partials ----
    #pragma unroll
    for (int r = 0; r < 4; ++r) {
        const float p0 = __expf(a[0][r] - m[r]);
        const float p1 = __expf(a[1][r] - m[r]);
        sPw[quad * 4 + r][col]      = f2bu(p0);
        sPw[quad * 4 + r][col + 16] = f2bu(p1);
        l[r] += p0 + p1;
    }

    // ---- O += P V ----
    bf16x8 pf = *reinterpret_cast<const bf16x8*>(&sPw[col][quad * 8]);
    #pragma unroll
    for (int dt = 0; dt < 16; ++dt) {
        bf16x8 vf = *reinterpret_cast<const bf16x8*>(&sV[dt * 512 + lane * 8]);
        o[dt] = __builtin_amdgcn_mfma_f32_16x16x32_bf16(pf, vf, o[dt], 0, 0, 0);
    }
}

// ---------------------------------------------------------------------------
// MFMA flash attention partial. 128 q-rows/block (8 waves x 16), 32-key
// tiles. K/V double-buffered in LDS via global_load_lds. Mask via flag grid.
__global__ __launch_bounds__(512) void attn_mfma(
    const __hip_bfloat16* __restrict__ Qb, const __hip_bfloat16* __restrict__ Kz,
    const __hip_bfloat16* __restrict__ Vz, const float* __restrict__ maskG,
    const int* __restrict__ Fz,
    float* __restrict__ PO, float* __restrict__ PM, float* __restrict__ PL,
    int M, int chunkKeys, int transposed)
{
    __shared__ unsigned short sKb[2][8192];   // 2 x 16 KB
    __shared__ unsigned short sVb[2][8192];   // 2 x 16 KB
    __shared__ unsigned short sP[8][16][40];  // 10 KB

    const int tid  = threadIdx.x;
    const int lane = tid & 63;
    const int wave = tid >> 6;
    const int col  = lane & 15;
    const int quad = lane >> 4;
    const int R0   = blockIdx.x * 128;
    const int split = blockIdx.y;
    const int jbase = split * chunkKeys;

    bf16x8 qf[8];
    {
        const __hip_bfloat16* qp =
            Qb + (size_t)(R0 + wave * 16 + col) * HD + quad * 8;
        #pragma unroll
        for (int s = 0; s < 8; ++s)
            qf[s] = *reinterpret_cast<const bf16x8*>(qp + 32 * s);
    }

    f32x4 o[16];
    #pragma unroll
    for (int dt = 0; dt < 16; ++dt) { o[dt][0]=0.f; o[dt][1]=0.f; o[dt][2]=0.f; o[dt][3]=0.f; }
    float m[4], l[4];
    #pragma unroll
    for (int r = 0; r < 4; ++r) { m[r] = -INFINITY; l[r] = 0.f; }

    // ---- prologue: tile 0 -> buf0 ----
    stage_tile(Kz + (size_t)jbase * 256, &sKb[0][0], wave, lane);
    stage_tile(Vz + (size_t)jbase * 256, &sVb[0][0], wave, lane);

    for (int jt = 0; jt < chunkKeys; jt += 64) {
        // ===== phase A: compute tile jt (buf0); stage jt+32 =====
        asm volatile("s_waitcnt vmcnt(0)" ::: "memory");
        __builtin_amdgcn_s_barrier();
        __builtin_amdgcn_sched_barrier(0);
        stage_tile(Kz + (size_t)(jbase + jt + 32) * 256, &sKb[1][0], wave, lane);
        stage_tile(Vz + (size_t)(jbase + jt + 32) * 256, &sVb[1][0], wave, lane);
        __builtin_amdgcn_sched_barrier(0);
        attn_tile(&sKb[0][0], &sVb[0][0], sP[wave], qf,
                  maskG, Fz, transposed, R0, jbase + jt,
                  lane, wave, col, quad, o, m, l);

        // ===== phase B: compute tile jt+32 (buf1); stage jt+64 =====
        asm volatile("s_waitcnt vmcnt(0)" ::: "memory");
        __builtin_amdgcn_s_barrier();
        __builtin_amdgcn_sched_barrier(0);
        if (jt + 64 < chunkKeys) {
            stage_tile(Kz + (size_t)(jbase + jt + 64) * 256, &sKb[0][0], wave, lane);
            stage_tile(Vz + (size_t)(jbase + jt + 64) * 256, &sVb[0][0], wave, lane);
        }
        __builtin_amdgcn_sched_barrier(0);
        attn_tile(&sKb[1][0], &sVb[1][0], sP[wave], qf,
                  maskG, Fz, transposed, R0, jbase + jt + 32,
                  lane, wave, col, quad, o, m, l);
    }

    // ---- final l reduction (per-lane partials -> 16-lane row sums) ----
    #pragma unroll
    for (int r = 0; r < 4; ++r) {
        #pragma unroll
        for (int off = 1; off < 16; off <<= 1)
            l[r] += __shfl_xor(l[r], off);
    }

    #pragma unroll
    for (int dt = 0; dt < 16; ++dt)
        #pragma unroll
        for (int r = 0; r < 4; ++r) {
            const int row = R0 + wave * 16 + quad * 4 + r;
            PO[((size_t)split * M + row) * HD + dt * 16 + col] = o[dt][r];
        }
    if (col == 0) {
        #pragma unroll
        for (int r = 0; r < 4; ++r) {
            const int row = R0 + wave * 16 + quad * 4 + r;
            PM[(size_t)split * M + row] = m[r];
            PL[(size_t)split * M + row] = l[r];
        }
    }
}

// ---------------------------------------------------------------------------
__global__ void attn_combine(
    const float* __restrict__ PO, const float* __restrict__ PM,
    const float* __restrict__ PL, __hip_bfloat16* __restrict__ Out,
    int M, int nchunks)
{
    const int idx = blockIdx.x * 256 + threadIdx.x;
    const int row = idx >> 8;
    float mmax = -INFINITY;
    for (int c = 0; c < nchunks; ++c) mmax = fmaxf(mmax, PM[(size_t)c * M + row]);
    float denom = 0.f, acc = 0.f;
    for (int c = 0; c < nchunks; ++c) {
        const float w = __expf(PM[(size_t)c * M + row] - mmax);
        denom += PL[(size_t)c * M + row] * w;
        acc   += PO[(size_t)c * M * HD + idx] * w;
    }
    Out[idx] = __float2bfloat16(acc / denom);
}

// ---------------------------------------------------------------------------
__global__ void coords_fin(
    const float* __restrict__ coords, const float* __restrict__ origc,
    const float* __restrict__ xsum, const float* __restrict__ cnt,
    float* __restrict__ out, int n)
{
    const int i = blockIdx.x * 256 + threadIdx.x;
    if (i >= n * 3) return;
    const int node = i / 3;
    const float inv = 1.f / fmaxf(cnt[node], 1.f);
    out[i] = 0.25f * origc[i] + 0.75f * coords[i] + xsum[i] * inv;
}

// ---------------------------------------------------------------------------
extern "C" void kernel_launch(void* const* d_in, const int* in_sizes, int n_in,
                              void* d_out, int out_size, void* d_ws, size_t ws_size,
                              hipStream_t stream)
{
    const float* coords_lig = (const float*)d_in[0];
    const float* h_lig      = (const float*)d_in[1];
    const float* orig_lig   = (const float*)d_in[2];
    const float* origc_lig  = (const float*)d_in[3];
    const float* coords_rec = (const float*)d_in[4];
    const float* h_rec      = (const float*)d_in[5];
    const float* orig_rec   = (const float*)d_in[6];
    const float* origc_rec  = (const float*)d_in[7];
    const float* mask       = (const float*)d_in[8];
    const float* lig_ef     = (const float*)d_in[9];
    const float* rec_ef     = (const float*)d_in[10];
    const int* lig_src = (const int*)d_in[11];
    const int* lig_dst = (const int*)d_in[12];
    const int* rec_src = (const int*)d_in[13];
    const int* rec_dst = (const int*)d_in[14];
    const float* le_w1 = (const float*)d_in[15];
    const float* le_b1 = (const float*)d_in[16];
    const float* le_w2 = (const float*)d_in[17];
    const float* le_b2 = (const float*)d_in[18];
    const float* re_w1 = (const float*)d_in[19];
    const float* re_b1 = (const float*)d_in[20];
    const float* re_w2 = (const float*)d_in[21];
    const float* re_b2 = (const float*)d_in[22];
    const float* aql_w = (const float*)d_in[23];
    const float* akl_w = (const float*)d_in[24];
    const float* avl_w = (const float*)d_in[25];
    const float* aqr_w = (const float*)d_in[26];
    const float* akr_w = (const float*)d_in[27];
    const float* avr_w = (const float*)d_in[28];
    const float* nl_w1 = (const float*)d_in[29];
    const float* nl_b1 = (const float*)d_in[30];
    const float* nl_w2 = (const float*)d_in[31];
    const float* nl_b2 = (const float*)d_in[32];
    const float* nr_w1 = (const float*)d_in[33];
    const float* nr_b1 = (const float*)d_in[34];
    const float* nr_w2 = (const float*)d_in[35];
    const float* nr_b2 = (const float*)d_in[36];
    const float* cl_w1 = (const float*)d_in[37];
    const float* cl_b1 = (const float*)d_in[38];
    const float* cl_w2 = (const float*)d_in[39];
    const float* cl_b2 = (const float*)d_in[40];
    const float* cr_w1 = (const float*)d_in[41];
    const float* cr_b1 = (const float*)d_in[42];
    const float* cr_w2 = (const float*)d_in[43];
    const float* cr_b2 = (const float*)d_in[44];

    float* out = (float*)d_out;
    float* wsf = (float*)d_ws;

    // ---- fp32 accumulator + CSR + mask-flag zone ----
    const size_t AGGRL = 0;
    const size_t AGGRR = AGGRL + (size_t)N_LIG * HD;
    const size_t CNTL  = AGGRR + (size_t)N_REC * HD;
    const size_t CNTR  = CNTL + N_LIG;
    const size_t XSUML = CNTR + N_REC;
    const size_t XSUMR = XSUML + (size_t)N_LIG * 3;
    const size_t HISTL = XSUMR + (size_t)N_REC * 3;
    const size_t CURL  = HISTL + N_LIG;
    const size_t HISTR = CURL + N_LIG;
    const size_t CURR  = HISTR + N_REC;
    const size_t FLAGS = CURR + N_REC;              // int[128][512] mask flags
    const size_t ZEND  = FLAGS + (size_t)(N_LIG / 32) * FCOLS;   // zeroed
    const size_t ELISTL = ZEND;                     // not zeroed
    const size_t ELISTR = ELISTL + E_LIG_N;
    const size_t FEND   = ELISTR + E_REC_N;

    // ---- bf16 zone ----
    __hip_bfloat16* wsb = (__hip_bfloat16*)(wsf + FEND);
    const size_t QL  = 0;
    const size_t KL  = QL + (size_t)N_LIG * HD;   // unused (kept for layout)
    const size_t VL  = KL + (size_t)N_LIG * HD;   // unused
    const size_t QR  = VL + (size_t)N_LIG * HD;
    const size_t KR  = QR + (size_t)N_REC * HD;   // unused
    const size_t VR  = KR + (size_t)N_REC * HD;   // unused
    const size_t CRL = VR + (size_t)N_REC * HD;
    const size_t CRR = CRL + (size_t)N_LIG * HD;
    const size_t KZL = CRR + (size_t)N_REC * HD;          // K swizzled lig
    const size_t VZL = KZL + (size_t)N_LIG * HD;          // V swizzled lig
    const size_t KZR = VZL + (size_t)N_LIG * HD;          // K swizzled rec
    const size_t VZR = KZR + (size_t)N_REC * HD;          // V swizzled rec
    const size_t EW1SZ = (size_t)16 * 17 * 512;
    const size_t KW256 = (size_t)16 * 8 * 512;
    const size_t NW1SZ = (size_t)16 * 18 * 512;
    const size_t SW_EL1 = VZR + (size_t)N_REC * HD;
    const size_t SW_EL2 = SW_EL1 + EW1SZ;
    const size_t SW_EC1 = SW_EL2 + KW256;
    const size_t SW_NL1 = SW_EC1 + KW256;
    const size_t SW_NL2 = SW_NL1 + NW1SZ;
    const size_t SW_ER1 = SW_NL2 + KW256;
    const size_t SW_ER2 = SW_ER1 + EW1SZ;
    const size_t SW_EC1R = SW_ER2 + KW256;
    const size_t SW_NR1 = SW_EC1R + KW256;
    const size_t SW_NR2 = SW_NR1 + NW1SZ;
    const size_t SW_PQL = SW_NR2 + KW256;
    const size_t SW_PKL = SW_PQL + KW256;
    const size_t SW_PVL = SW_PKL + KW256;
    const size_t SW_PQR = SW_PVL + KW256;
    const size_t SW_PKR = SW_PQR + KW256;
    const size_t SW_PVR = SW_PKR + KW256;
    // pre-converted bf16 operand blobs
    const size_t HB_L  = SW_PVR + KW256;
    const size_t HB_R  = HB_L + (size_t)N_LIG * HD;
    const size_t EFB_L = HB_R + (size_t)N_REC * HD;
    const size_t EFB_R = EFB_L + (size_t)E_LIG_N * EFD;
    const size_t BF_END = EFB_R + (size_t)E_REC_N * EFD;

    // ---- split-K partial zone (fp32), dynamic splits ----
    float* wsp = (float*)(wsb + ((BF_END + 1) & ~(size_t)1));
    const size_t baseBytes = (size_t)((char*)wsp - (char*)d_ws);
    int SL = 16, SR = 4;
    {
        const size_t poElems16 = (size_t)16 * N_LIG * HD;
        const size_t need16 = baseBytes +
            (poElems16 + 2 * (size_t)16 * N_LIG) * sizeof(float);
        if (ws_size < need16) { SL = 8; SR = 2; }
    }
    const size_t PO_ = 0;
    const size_t PM_ = PO_ + (size_t)SL * N_LIG * HD;
    const size_t PL_ = PM_ + (size_t)SL * N_LIG;

    const size_t O_XL = 0;
    const size_t O_HL = O_XL + (size_t)N_LIG * 3;
    const size_t O_XR = O_HL + (size_t)N_LIG * HD;
    const size_t O_HR = O_XR + (size_t)N_REC * 3;

    // 1) zero atomic accumulators + CSR hist/cursors + mask flags
    zero_kernel<<<((int)ZEND + 255) / 256, 256, 0, stream>>>(wsf, (int)ZEND);

    // 1a) mask flag scan (one coalesced pass over the fp32 mask)
    scanmask_kernel<<<(N_LIG * (N_REC / 16)) / 256, 256, 0, stream>>>(
        mask, (int*)(wsf + FLAGS));

    // 1b) fp32 -> bf16 operand blobs (h and edge features)
    f2b_kernel<<<(N_LIG * HD / 8 + 255) / 256, 256, 0, stream>>>(
        h_lig, wsb + HB_L, N_LIG * HD / 8);
    f2b_kernel<<<(N_REC * HD / 8 + 255) / 256, 256, 0, stream>>>(
        h_rec, wsb + HB_R, N_REC * HD / 8);
    f2b_kernel<<<(E_LIG_N * EFD / 8 + 255) / 256, 256, 0, stream>>>(
        lig_ef, wsb + EFB_L, E_LIG_N * EFD / 8);
    f2b_kernel<<<(E_REC_N * EFD / 8 + 255) / 256, 256, 0, stream>>>(
        rec_ef, wsb + EFB_R, E_REC_N * EFD / 8);

    // 1c) CSR build: dst-sorted edge permutations (also produces fp32 counts)
    hist_kernel<<<E_LIG_N / 256, 256, 0, stream>>>(lig_dst, (int*)(wsf + HISTL), E_LIG_N);
    hist_kernel<<<E_REC_N / 256, 256, 0, stream>>>(rec_dst, (int*)(wsf + HISTR), E_REC_N);
    scan_kernel<<<1, 256, 0, stream>>>((int*)(wsf + HISTL), (int*)(wsf + CURL),
                                       wsf + CNTL, N_LIG);
    scan_kernel<<<1, 256, 0, stream>>>((int*)(wsf + HISTR), (int*)(wsf + CURR),
                                       wsf + CNTR, N_REC);
    scatter_kernel<<<E_LIG_N / 256, 256, 0, stream>>>(
        lig_dst, (int*)(wsf + CURL), (int*)(wsf + ELISTL), E_LIG_N);
    scatter_kernel<<<E_REC_N / 256, 256, 0, stream>>>(
        rec_dst, (int*)(wsf + CURR), (int*)(wsf + ELISTR), E_REC_N);

    // 2) weight swizzles
    wt_swz<<<16 * 17, 256, 0, stream>>>(le_w1, wsb + SW_EL1, EIN, 17);
    wt_swz<<<16 * 8,  256, 0, stream>>>(le_w2, wsb + SW_EL2, 256, 8);
    wt_swz<<<16 * 8,  256, 0, stream>>>(cl_w1, wsb + SW_EC1, 256, 8);
    wt_swz<<<16 * 18, 256, 0, stream>>>(nl_w1, wsb + SW_NL1, 576, 18);
    wt_swz<<<16 * 8,  256, 0, stream>>>(nl_w2, wsb + SW_NL2, 256, 8);
    wt_swz<<<16 * 17, 256, 0, stream>>>(re_w1, wsb + SW_ER1, EIN, 17);
    wt_swz<<<16 * 8,  256, 0, stream>>>(re_w2, wsb + SW_ER2, 256, 8);
    wt_swz<<<16 * 8,  256, 0, stream>>>(cr_w1, wsb + SW_EC1R, 256, 8);
    wt_swz<<<16 * 18, 256, 0, stream>>>(nr_w1, wsb + SW_NR1, 576, 18);
    wt_swz<<<16 * 8,  256, 0, stream>>>(nr_w2, wsb + SW_NR2, 256, 8);
    wt_swz<<<16 * 8,  256, 0, stream>>>(aql_w, wsb + SW_PQL, 256, 8);
    wt_swz<<<16 * 8,  256, 0, stream>>>(akl_w, wsb + SW_PKL, 256, 8);
    wt_swz<<<16 * 8,  256, 0, stream>>>(avl_w, wsb + SW_PVL, 256, 8);
    wt_swz<<<16 * 8,  256, 0, stream>>>(aqr_w, wsb + SW_PQR, 256, 8);
    wt_swz<<<16 * 8,  256, 0, stream>>>(akr_w, wsb + SW_PKR, 256, 8);
    wt_swz<<<16 * 8,  256, 0, stream>>>(avr_w, wsb + SW_PVR, 256, 8);

    // 3) edge MFMA kernels (32 edges/block, dst-sorted, segmented atomics)
    edge_mfma<<<E_LIG_N / 32, 256, 0, stream>>>(
        coords_lig, wsb + HB_L, wsb + EFB_L, lig_src, lig_dst,
        (const int*)(wsf + ELISTL),
        wsb + SW_EL1, le_b1, wsb + SW_EL2, le_b2, wsb + SW_EC1, cl_b1, cl_w2, cl_b2,
        wsf + AGGRL, wsf + XSUML);
    edge_mfma<<<E_REC_N / 32, 256, 0, stream>>>(
        coords_rec, wsb + HB_R, wsb + EFB_R, rec_src, rec_dst,
        (const int*)(wsf + ELISTR),
        wsb + SW_ER1, re_b1, wsb + SW_ER2, re_b2, wsb + SW_EC1R, cr_b1, cr_w2, cr_b2,
        wsf + AGGRR, wsf + XSUMR);

    // 4) fused q/k/v projections (K/V written directly in fragment-blob order)
    qkv_proj<<<N_LIG / 32, 256, 0, stream>>>(
        wsb + HB_L, wsb + SW_PQL, wsb + SW_PKL, wsb + SW_PVL,
        wsb + QL, wsb + KZL, wsb + VZL);
    qkv_proj<<<N_REC / 32, 256, 0, stream>>>(
        wsb + HB_R, wsb + SW_PQR, wsb + SW_PKR, wsb + SW_PVR,
        wsb + QR, wsb + KZR, wsb + VZR);

    // 5) MFMA flash attention, split-K + combine
    {
        dim3 gl(N_LIG / 128, SL);
        attn_mfma<<<gl, 512, 0, stream>>>(wsb + QL, wsb + KZR, wsb + VZR, mask,
                                          (const int*)(wsf + FLAGS),
                                          wsp + PO_, wsp + PM_, wsp + PL_,
                                          N_LIG, N_REC / SL, 0);
        attn_combine<<<N_LIG, 256, 0, stream>>>(
            wsp + PO_, wsp + PM_, wsp + PL_, wsb + CRL, N_LIG, SL);

        dim3 gr(N_REC / 128, SR);
        attn_mfma<<<gr, 512, 0, stream>>>(wsb + QR, wsb + KZL, wsb + VZL, mask,
                                          (const int*)(wsf + FLAGS),
                                          wsp + PO_, wsp + PM_, wsp + PL_,
                                          N_REC, N_LIG / SR, 1);
        attn_combine<<<N_REC, 256, 0, stream>>>(
            wsp + PO_, wsp + PM_, wsp + PL_, wsb + CRR, N_REC, SR);
    }

    // 6) coordinate outputs
    coords_fin<<<(N_LIG * 3 + 255) / 256, 256, 0, stream>>>(
        coords_lig, origc_lig, wsf + XSUML, wsf + CNTL, out + O_XL, N_LIG);
    coords_fin<<<(N_REC * 3 + 255) / 256, 256, 0, stream>>>(
        coords_rec, origc_rec, wsf + XSUMR, wsf + CNTR, out + O_XR, N_REC);

    // 7) node MFMA kernels
    node_mfma<<<N_LIG / 32, 256, 0, stream>>>(
        wsf + AGGRL, wsf + CNTL, wsb + CRL, orig_lig, h_lig,
        wsb + SW_NL1, nl_b1, wsb + SW_NL2, nl_b2, out + O_HL);
    node_mfma<<<N_REC / 32, 256, 0, stream>>>(
        wsf + AGGRR, wsf + CNTR, wsb + CRR, orig_rec, h_rec,
        wsb + SW_NR1, nr_b1, wsb + SW_NR2, nr_b2, out + O_HR);

    (void)in_sizes; (void)n_in; (void)out_size;
}

// Round 16
// 1261.475 us; speedup vs baseline: 1.0644x; 1.0236x over previous
//
#include <hip/hip_runtime.h>
#include <hip/hip_bf16.h>

// ---------------------------------------------------------------------------
// IEGMN layer, MI355X round-24: r23 (best, 1291.3 us) + T5 s_setprio(1/0)
// around MFMA clusters in mfma_gemm (edge/node/qkv) and in attention's
// QK^T / PV loops. Pure scheduler hint (bit-identical math); catalog
// precedent: +4-7% on role-split attention (m191), null on lockstep (m190).
//  * mask-sparsity flag grid (r23): attn tiles skip mask loads when all-ones
//  * mfma_gemm: even/odd depth-2 prefetch (r19, proven)
//  * edge_mfma: 32 edges/block, dst-sorted CSR order, segmented atomics
//  * qkv_proj: fused Q/K/V, K/V stored directly in fragment-blob order
//  * attn_mfma: 8 waves x 16 q-rows, glds LDS double-buffer, defer-max
// ---------------------------------------------------------------------------

#define N_LIG   4096
#define N_REC   16384
#define E_LIG_N 65536
#define E_REC_N 262144
#define HD      256
#define ORIGD   64
#define EFD     16
#define NSIG    15
#define EIN     543      // 2*HD + EFD + NSIG
#define XP      552      // edge sX pitch (bf16 elems), 544 used
#define XPN     584      // node sX pitch, 576 used
#define XPP     264      // proj sX pitch, 256 used
#define FP      264      // fp32 reuse pitch inside sX (floats)
#define FCOLS   (N_REC / 32)   // 512 flag columns (rec 32-groups)

typedef __bf16 bf16x8 __attribute__((ext_vector_type(8)));
typedef float  f32x4  __attribute__((ext_vector_type(4)));

__device__ __forceinline__ float lrelu(float x) { return x > 0.f ? x : 0.01f * x; }
__device__ __forceinline__ unsigned short f2bu(float f) {
    __hip_bfloat16 h = __float2bfloat16(f);
    return *reinterpret_cast<unsigned short*>(&h);
}

// Direct global->LDS async copy, 16B per lane.
__device__ __forceinline__ void glds16(const void* g, void* l) {
    __builtin_amdgcn_global_load_lds(
        (const __attribute__((address_space(1))) void*)g,
        (__attribute__((address_space(3))) void*)l,
        16, 0, 0);
}

// Stage 16KB (one 32-key K or V tile) into LDS with 512 threads: 2 glds/thr.
__device__ __forceinline__ void stage_tile(
    const __hip_bfloat16* g, unsigned short* l, int wave, int lane)
{
    #pragma unroll
    for (int i = 0; i < 2; ++i) {
        const __hip_bfloat16* gp = g + (size_t)(i * 512 + wave * 64 + lane) * 8;
        unsigned short* lp = l + (i * 512 + wave * 64) * 8;  // wave-uniform base
        glds16(gp, lp);
    }
}

// ---------------------------------------------------------------------------
// Shared 32xKx256 GEMM core. Even/odd depth-2 pipeline; MFMA clusters are
// wrapped in s_setprio(1)/(0) (T5) so the scheduler favors matrix-feeding
// waves while co-resident waves issue loads.
__device__ __forceinline__ void mfma_gemm(
    const unsigned short* sA, int pitch,
    const __hip_bfloat16* Wswz, int KS, int lane, f32x4 acc[2][4])
{
    const int col = lane & 15, quad = lane >> 4;
    const unsigned short* a0p = sA + (size_t)col * pitch + quad * 8;
    const unsigned short* a1p = sA + (size_t)(16 + col) * pitch + quad * 8;
    const __hip_bfloat16* wp = Wswz + lane * 8;

    bf16x8 bE[4], bO[4], aE0, aE1, aO0, aO1;
    #pragma unroll
    for (int nt = 0; nt < 4; ++nt) {
        bE[nt] = *reinterpret_cast<const bf16x8*>(wp + (size_t)nt * KS * 512);
        bO[nt] = *reinterpret_cast<const bf16x8*>(wp + ((size_t)nt * KS + 1) * 512);
    }
    aE0 = *reinterpret_cast<const bf16x8*>(a0p);
    aE1 = *reinterpret_cast<const bf16x8*>(a1p);
    aO0 = *reinterpret_cast<const bf16x8*>(a0p + 32);
    aO1 = *reinterpret_cast<const bf16x8*>(a1p + 32);

    int ks = 0;
    for (; ks + 2 <= KS; ks += 2) {
        // ---- even step: compute ks, prefetch ks+2 ----
        __builtin_amdgcn_s_setprio(1);
        #pragma unroll
        for (int nt = 0; nt < 4; ++nt) {
            acc[0][nt] = __builtin_amdgcn_mfma_f32_16x16x32_bf16(aE0, bE[nt], acc[0][nt], 0, 0, 0);
            acc[1][nt] = __builtin_amdgcn_mfma_f32_16x16x32_bf16(aE1, bE[nt], acc[1][nt], 0, 0, 0);
        }
        __builtin_amdgcn_s_setprio(0);
        if (ks + 2 < KS) {
            #pragma unroll
            for (int nt = 0; nt < 4; ++nt)
                bE[nt] = *reinterpret_cast<const bf16x8*>(
                    wp + ((size_t)nt * KS + ks + 2) * 512);
            aE0 = *reinterpret_cast<const bf16x8*>(a0p + (ks + 2) * 32);
            aE1 = *reinterpret_cast<const bf16x8*>(a1p + (ks + 2) * 32);
        }
        // ---- odd step: compute ks+1, prefetch ks+3 ----
        __builtin_amdgcn_s_setprio(1);
        #pragma unroll
        for (int nt = 0; nt < 4; ++nt) {
            acc[0][nt] = __builtin_amdgcn_mfma_f32_16x16x32_bf16(aO0, bO[nt], acc[0][nt], 0, 0, 0);
            acc[1][nt] = __builtin_amdgcn_mfma_f32_16x16x32_bf16(aO1, bO[nt], acc[1][nt], 0, 0, 0);
        }
        __builtin_amdgcn_s_setprio(0);
        if (ks + 3 < KS) {
            #pragma unroll
            for (int nt = 0; nt < 4; ++nt)
                bO[nt] = *reinterpret_cast<const bf16x8*>(
                    wp + ((size_t)nt * KS + ks + 3) * 512);
            aO0 = *reinterpret_cast<const bf16x8*>(a0p + (ks + 3) * 32);
            aO1 = *reinterpret_cast<const bf16x8*>(a1p + (ks + 3) * 32);
        }
    }
    if (ks < KS) {   // odd-KS tail (even slot)
        __builtin_amdgcn_s_setprio(1);
        #pragma unroll
        for (int nt = 0; nt < 4; ++nt) {
            acc[0][nt] = __builtin_amdgcn_mfma_f32_16x16x32_bf16(aE0, bE[nt], acc[0][nt], 0, 0, 0);
            acc[1][nt] = __builtin_amdgcn_mfma_f32_16x16x32_bf16(aE1, bE[nt], acc[1][nt], 0, 0, 0);
        }
        __builtin_amdgcn_s_setprio(0);
    }
}

// ---------------------------------------------------------------------------
__global__ void zero_kernel(float* __restrict__ p, int n) {
    int i = blockIdx.x * 256 + threadIdx.x;
    if (i < n) p[i] = 0.f;
}

// ---------------------------------------------------------------------------
// Mask scan: set F[ligRow32][recCol32] = 1 if any element of the 32x32 mask
// tile differs from 1.0. 16 contiguous floats per thread (fits one tile).
__global__ void scanmask_kernel(const float* __restrict__ mask,
                                int* __restrict__ F)
{
    const size_t t = (size_t)blockIdx.x * 256 + threadIdx.x;
    const int r  = (int)(t >> 10);            // N_REC/16 = 1024 chunks per row
    const int c0 = ((int)t & 1023) * 16;
    const float4* p = reinterpret_cast<const float4*>(
        &mask[(size_t)r * N_REC + c0]);
    bool ok = true;
    #pragma unroll
    for (int i = 0; i < 4; ++i) {
        const float4 v = p[i];
        ok = ok && (v.x == 1.f) && (v.y == 1.f) && (v.z == 1.f) && (v.w == 1.f);
    }
    if (!ok) atomicOr(&F[(r >> 5) * FCOLS + (c0 >> 5)], 1);
}

// ---------------------------------------------------------------------------
// fp32 -> bf16 blob, 8 elems/thread (vectorized).
__global__ void f2b_kernel(const float* __restrict__ src,
                           __hip_bfloat16* __restrict__ dst, int n8) {
    const int i = blockIdx.x * 256 + threadIdx.x;
    if (i >= n8) return;
    const float4 a = *reinterpret_cast<const float4*>(src + (size_t)i * 8);
    const float4 b = *reinterpret_cast<const float4*>(src + (size_t)i * 8 + 4);
    ushort4 u0 = { f2bu(a.x), f2bu(a.y), f2bu(a.z), f2bu(a.w) };
    ushort4 u1 = { f2bu(b.x), f2bu(b.y), f2bu(b.z), f2bu(b.w) };
    unsigned short* d = (unsigned short*)dst + (size_t)i * 8;
    *reinterpret_cast<ushort4*>(d)     = u0;
    *reinterpret_cast<ushort4*>(d + 4) = u1;
}

// ---------------------------------------------------------------------------
// CSR build: histogram -> scan -> scatter (dst-sorted edge permutation).
__global__ void hist_kernel(const int* __restrict__ dst, int* __restrict__ hist, int n) {
    int i = blockIdx.x * 256 + threadIdx.x;
    if (i < n) atomicAdd(&hist[dst[i]], 1);
}

__global__ __launch_bounds__(256) void scan_kernel(
    const int* __restrict__ hist, int* __restrict__ cur,
    float* __restrict__ cntf, int n)
{
    __shared__ int part[256];
    const int tid = threadIdx.x;
    const int per = n >> 8;            // n is 4096 or 16384
    const int base = tid * per;
    int s = 0;
    for (int i = 0; i < per; ++i) s += hist[base + i];
    part[tid] = s;
    __syncthreads();
    #pragma unroll
    for (int off = 1; off < 256; off <<= 1) {
        int v = (tid >= off) ? part[tid - off] : 0;
        __syncthreads();
        part[tid] += v;
        __syncthreads();
    }
    int run = part[tid] - s;           // exclusive prefix of this chunk
    for (int i = 0; i < per; ++i) {
        const int h = hist[base + i];
        cur[base + i]  = run;
        cntf[base + i] = (float)h;
        run += h;
    }
}

__global__ void scatter_kernel(const int* __restrict__ dst, int* __restrict__ cur,
                               int* __restrict__ elist, int n) {
    int i = blockIdx.x * 256 + threadIdx.x;
    if (i < n) { int p = atomicAdd(&cur[dst[i]], 1); elist[p] = i; }
}

// ---------------------------------------------------------------------------
__global__ void wt_swz(const float* __restrict__ src,
                       __hip_bfloat16* __restrict__ dst, int K, int KS) {
    const int g  = blockIdx.x / KS;
    const int ks = blockIdx.x % KS;
    for (int i = threadIdx.x; i < 512; i += 256) {
        const int lane = i >> 3, j = i & 7;
        const int n = g * 16 + (lane & 15);
        const int k = ks * 32 + (lane >> 4) * 8 + j;
        const float v = (k < K) ? src[(size_t)k * 256 + n] : 0.f;
        dst[((size_t)(g * KS + ks) * 64 + lane) * 8 + j] = __float2bfloat16(v);
    }
}

// ---------------------------------------------------------------------------
// Edge MFMA kernel: 32 edges/block, edges taken in dst-sorted order (elist).
// (r15 structure; measured 232-236 us rec / MfmaUtil 27%.)
__global__ __launch_bounds__(256, 4) void edge_mfma(
    const float* __restrict__ coords, const __hip_bfloat16* __restrict__ hb,
    const __hip_bfloat16* __restrict__ efb,
    const int* __restrict__ src, const int* __restrict__ dst,
    const int* __restrict__ elist,
    const __hip_bfloat16* __restrict__ W1s, const float* __restrict__ b1,
    const __hip_bfloat16* __restrict__ W2s, const float* __restrict__ b2,
    const __hip_bfloat16* __restrict__ Wc1s, const float* __restrict__ bc1,
    const float* __restrict__ wc2v, const float* __restrict__ bc2,
    float* __restrict__ aggr, float* __restrict__ xsum)
{
    __shared__ unsigned short sX[32][XP];     // also reused as fp32 [32][FP]
    __shared__ float sXrel[32][3];
    __shared__ int   sDst[32];
    __shared__ int   sSrc[32];
    __shared__ int   sE[32];
    __shared__ float sRedW[4][32];
    __shared__ float sPv[32];

    const int tid  = threadIdx.x;
    const int lane = tid & 63;
    const int wave = tid >> 6;
    const int col  = lane & 15;
    const int quad = lane >> 4;
    const int e0   = blockIdx.x * 32;

    // ---- edge meta: permuted id, endpoints, x_rel, RBF ----
    if (tid < 32) {
        const int e = elist[e0 + tid];
        const int s = src[e], d = dst[e];
        sE[tid] = e; sSrc[tid] = s; sDst[tid] = d;
        float d2 = 0.f;
        #pragma unroll
        for (int c = 0; c < 3; ++c) {
            const float xr = coords[s * 3 + c] - coords[d * 3 + c];
            sXrel[tid][c] = xr;
            d2 += xr * xr;
        }
        float sig = 1.0f;
        #pragma unroll
        for (int si = 0; si < NSIG; ++si) {
            sX[tid][528 + si] = f2bu(__expf(-d2 / sig));
            sig *= 1.5f;
        }
        sX[tid][543] = 0;
    }
    __syncthreads();

    // ---- gather h[src], h[dst] (bf16, uint4 copies) ----
    for (int i = tid; i < 32 * 64; i += 256) {
        const int row = i >> 6, c = i & 63;
        const int node = (c < 32) ? sSrc[row] : sDst[row];
        const int chunk = c & 31;
        *reinterpret_cast<uint4*>(&sX[row][(c < 32 ? 0 : 256) + chunk * 8]) =
            *reinterpret_cast<const uint4*>(&hb[(size_t)node * HD + chunk * 8]);
    }
    // ---- gather edge features (bf16, permuted rows) ----
    if (tid < 64) {
        const int row = tid >> 1, hh = tid & 1;
        *reinterpret_cast<uint4*>(&sX[row][512 + hh * 8]) =
            *reinterpret_cast<const uint4*>(&efb[(size_t)sE[row] * EFD + hh * 8]);
    }
    __syncthreads();

    f32x4 acc[2][4];
    f32x4 macc[2][4];   // message accumulators, survive the coords GEMM

    // ---- GEMM1: [32 x 544] @ W1 -> hidden, lrelu ----
    #pragma unroll
    for (int nt = 0; nt < 4; ++nt) {
        const float bv = b1[wave * 64 + nt * 16 + col];
        acc[0][nt] = { bv, bv, bv, bv };
        acc[1][nt] = { bv, bv, bv, bv };
    }
    mfma_gemm(&sX[0][0], XP, W1s + (size_t)(wave * 4) * 17 * 512, 17, lane, acc);
    __syncthreads();
    #pragma unroll
    for (int mt = 0; mt < 2; ++mt)
        #pragma unroll
        for (int nt = 0; nt < 4; ++nt)
            #pragma unroll
            for (int r = 0; r < 4; ++r)
                sX[mt * 16 + quad * 4 + r][wave * 64 + nt * 16 + col] =
                    f2bu(lrelu(acc[mt][nt][r]));
    __syncthreads();

    // ---- GEMM2: hidden @ W2 -> msg (kept fp32 in macc) ----
    #pragma unroll
    for (int nt = 0; nt < 4; ++nt) {
        const float bv = b2[wave * 64 + nt * 16 + col];
        macc[0][nt] = { bv, bv, bv, bv };
        macc[1][nt] = { bv, bv, bv, bv };
    }
    mfma_gemm(&sX[0][0], XP, W2s + (size_t)(wave * 4) * 8 * 512, 8, lane, macc);
    __syncthreads();
    #pragma unroll
    for (int mt = 0; mt < 2; ++mt)
        #pragma unroll
        for (int nt = 0; nt < 4; ++nt)
            #pragma unroll
            for (int r = 0; r < 4; ++r)
                sX[mt * 16 + quad * 4 + r][wave * 64 + nt * 16 + col] =
                    f2bu(macc[mt][nt][r]);
    __syncthreads();

    // ---- GEMM3: msg @ Wc1 -> lrelu -> dot wc2 (per-edge scalar p) ----
    #pragma unroll
    for (int nt = 0; nt < 4; ++nt) {
        const float bv = bc1[wave * 64 + nt * 16 + col];
        acc[0][nt] = { bv, bv, bv, bv };
        acc[1][nt] = { bv, bv, bv, bv };
    }
    mfma_gemm(&sX[0][0], XP, Wc1s + (size_t)(wave * 4) * 8 * 512, 8, lane, acc);
    float w2l[4];
    #pragma unroll
    for (int nt = 0; nt < 4; ++nt) w2l[nt] = wc2v[wave * 64 + nt * 16 + col];
    #pragma unroll
    for (int mt = 0; mt < 2; ++mt) {
        float pr[4] = { 0.f, 0.f, 0.f, 0.f };
        #pragma unroll
        for (int nt = 0; nt < 4; ++nt)
            #pragma unroll
            for (int r = 0; r < 4; ++r)
                pr[r] += lrelu(acc[mt][nt][r]) * w2l[nt];
        #pragma unroll
        for (int r = 0; r < 4; ++r) {
            #pragma unroll
            for (int off = 1; off < 16; off <<= 1) pr[r] += __shfl_xor(pr[r], off);
        }
        if (col == 0)
            #pragma unroll
            for (int r = 0; r < 4; ++r)
                sRedW[wave][mt * 16 + quad * 4 + r] = pr[r];
    }
    __syncthreads();

    // ---- dump fp32 messages into LDS (reuse sX), gather p per edge ----
    float* sF = reinterpret_cast<float*>(&sX[0][0]);   // [32][FP] floats
    #pragma unroll
    for (int mt = 0; mt < 2; ++mt)
        #pragma unroll
        for (int nt = 0; nt < 4; ++nt)
            #pragma unroll
            for (int r = 0; r < 4; ++r)
                sF[(mt * 16 + quad * 4 + r) * FP + wave * 64 + nt * 16 + col] =
                    macc[mt][nt][r];
    if (tid < 32)
        sPv[tid] = sRedW[0][tid] + sRedW[1][tid] + sRedW[2][tid] + sRedW[3][tid]
                 + bc2[0];
    __syncthreads();

    // ---- segmented flush: one atomic per (distinct dst x column) ----
    {
        const int c = tid;               // 256 threads = 256 columns
        float av = 0.f;
        int dprev = sDst[0];
        for (int row = 0; row < 32; ++row) {
            const int d = sDst[row];     // uniform across block -> no divergence
            if (d != dprev) {
                atomicAdd(&aggr[(size_t)dprev * HD + c], av);
                av = 0.f; dprev = d;
            }
            av += sF[row * FP + c];
        }
        atomicAdd(&aggr[(size_t)dprev * HD + c], av);
    }
    if (tid < 3) {
        const int c = tid;
        float av = 0.f;
        int dprev = sDst[0];
        for (int row = 0; row < 32; ++row) {
            const int d = sDst[row];
            if (d != dprev) {
                atomicAdd(&xsum[(size_t)dprev * 3 + c], av);
                av = 0.f; dprev = d;
            }
            av += sXrel[row][c] * sPv[row];
        }
        atomicAdd(&xsum[(size_t)dprev * 3 + c], av);
    }
}

// ---------------------------------------------------------------------------
// Node MFMA kernel: 32 nodes/block (unchanged).
__global__ __launch_bounds__(256, 4) void node_mfma(
    const float* __restrict__ aggr, const float* __restrict__ cnt,
    const __hip_bfloat16* __restrict__ cross, const float* __restrict__ orig,
    const float* __restrict__ hfeat,
    const __hip_bfloat16* __restrict__ WN1s, const float* __restrict__ b1,
    const __hip_bfloat16* __restrict__ WN2s, const float* __restrict__ b2,
    float* __restrict__ out)
{
    __shared__ unsigned short sXn[32][XPN];
    __shared__ float sInv[32];

    const int tid  = threadIdx.x;
    const int lane = tid & 63;
    const int wave = tid >> 6;
    const int col  = lane & 15;
    const int quad = lane >> 4;
    const int r0   = blockIdx.x * 32;

    if (tid < 32) sInv[tid] = 1.f / fmaxf(cnt[r0 + tid], 1.f);
    __syncthreads();

    for (int i = tid; i < 32 * 64; i += 256) {
        const int row = i >> 6, c4 = i & 63;
        const float inv = sInv[row];
        const float4 v = *reinterpret_cast<const float4*>(
            &aggr[(size_t)(r0 + row) * HD + c4 * 4]);
        ushort4 u = { f2bu(v.x * inv), f2bu(v.y * inv), f2bu(v.z * inv), f2bu(v.w * inv) };
        *reinterpret_cast<ushort4*>(&sXn[row][c4 * 4]) = u;
    }
    for (int i = tid; i < 32 * 64; i += 256) {
        const int row = i >> 6, c4 = i & 63;
        const ushort4 u = *reinterpret_cast<const ushort4*>(
            &cross[(size_t)(r0 + row) * HD + c4 * 4]);
        *reinterpret_cast<ushort4*>(&sXn[row][256 + c4 * 4]) = u;
    }
    for (int i = tid; i < 32 * 16; i += 256) {
        const int row = i >> 4, c4 = i & 15;
        const float4 v = *reinterpret_cast<const float4*>(
            &orig[(size_t)(r0 + row) * ORIGD + c4 * 4]);
        ushort4 u = { f2bu(v.x), f2bu(v.y), f2bu(v.z), f2bu(v.w) };
        *reinterpret_cast<ushort4*>(&sXn[row][512 + c4 * 4]) = u;
    }
    __syncthreads();

    f32x4 acc[2][4];

    #pragma unroll
    for (int nt = 0; nt < 4; ++nt) {
        const float bv = b1[wave * 64 + nt * 16 + col];
        acc[0][nt] = { bv, bv, bv, bv };
        acc[1][nt] = { bv, bv, bv, bv };
    }
    mfma_gemm(&sXn[0][0], XPN, WN1s + (size_t)(wave * 4) * 18 * 512, 18, lane, acc);
    __syncthreads();
    #pragma unroll
    for (int mt = 0; mt < 2; ++mt)
        #pragma unroll
        for (int nt = 0; nt < 4; ++nt)
            #pragma unroll
            for (int r = 0; r < 4; ++r)
                sXn[mt * 16 + quad * 4 + r][wave * 64 + nt * 16 + col] =
                    f2bu(lrelu(acc[mt][nt][r]));
    __syncthreads();

    #pragma unroll
    for (int nt = 0; nt < 4; ++nt) {
        const float bv = b2[wave * 64 + nt * 16 + col];
        acc[0][nt] = { bv, bv, bv, bv };
        acc[1][nt] = { bv, bv, bv, bv };
    }
    mfma_gemm(&sXn[0][0], XPN, WN2s + (size_t)(wave * 4) * 8 * 512, 8, lane, acc);
    #pragma unroll
    for (int mt = 0; mt < 2; ++mt)
        #pragma unroll
        for (int nt = 0; nt < 4; ++nt)
            #pragma unroll
            for (int r = 0; r < 4; ++r) {
                const int g = r0 + mt * 16 + quad * 4 + r;
                const int n = wave * 64 + nt * 16 + col;
                out[(size_t)g * HD + n] =
                    0.5f * acc[mt][nt][r] + 0.5f * hfeat[(size_t)g * HD + n];
            }
}

// ---------------------------------------------------------------------------
// Fused Q/K/V projection: stage X once, run 3 GEMMs from the same LDS tile.
// K and V are written DIRECTLY in the attention fragment-blob layouts.
__global__ __launch_bounds__(256, 4) void qkv_proj(
    const __hip_bfloat16* __restrict__ Xb,
    const __hip_bfloat16* __restrict__ Wq, const __hip_bfloat16* __restrict__ Wk,
    const __hip_bfloat16* __restrict__ Wv,
    __hip_bfloat16* __restrict__ Q, __hip_bfloat16* __restrict__ Kz,
    __hip_bfloat16* __restrict__ Vz)
{
    __shared__ unsigned short sXp[32][XPP];
    const int tid  = threadIdx.x;
    const int lane = tid & 63;
    const int wave = tid >> 6;
    const int col  = lane & 15;
    const int quad = lane >> 4;
    const int r0   = blockIdx.x * 32;

    for (int i = tid; i < 32 * 32; i += 256) {
        const int row = i >> 5, c = i & 31;
        *reinterpret_cast<uint4*>(&sXp[row][c * 8]) =
            *reinterpret_cast<const uint4*>(&Xb[(size_t)(r0 + row) * HD + c * 8]);
    }
    __syncthreads();

    f32x4 acc[2][4];
    #pragma unroll
    for (int p = 0; p < 3; ++p) {
        const __hip_bfloat16* Ws = (p == 0) ? Wq : (p == 1) ? Wk : Wv;
        #pragma unroll
        for (int nt = 0; nt < 4; ++nt) {
            acc[0][nt] = { 0.f, 0.f, 0.f, 0.f };
            acc[1][nt] = { 0.f, 0.f, 0.f, 0.f };
        }
        mfma_gemm(&sXp[0][0], XPP, Ws + (size_t)(wave * 4) * 8 * 512, 8, lane, acc);
        #pragma unroll
        for (int mt = 0; mt < 2; ++mt)
            #pragma unroll
            for (int nt = 0; nt < 4; ++nt)
                #pragma unroll
                for (int r = 0; r < 4; ++r) {
                    float v = acc[mt][nt][r];
                    const int row = r0 + mt * 16 + quad * 4 + r;
                    const int c   = wave * 64 + nt * 16 + col;
                    if (p == 0) {
                        Q[(size_t)row * HD + c] = __float2bfloat16(lrelu(v));
                    } else if (p == 1) {
                        // K blob: ((kt*8+s)*512 + (cc8*16+rr)*8 + j)
                        const int kt = row >> 4, rr = row & 15;
                        const int s  = c >> 5, cc8 = (c >> 3) & 3, j = c & 7;
                        Kz[(size_t)(kt * 8 + s) * 512 + (cc8 * 16 + rr) * 8 + j] =
                            __float2bfloat16(lrelu(v));
                    } else {
                        // V blob: (((jt*16+dt)*64 + (rowin>>3)*16 + cc)*8 + (rowin&7))
                        const int jt = row >> 5, rowin = row & 31;
                        const int dt = c >> 4, cc = c & 15;
                        Vz[((size_t)(jt * 16 + dt) * 64 + (rowin >> 3) * 16 + cc) * 8
                           + (rowin & 7)] = __float2bfloat16(v);
                    }
                }
    }
}

// ---------------------------------------------------------------------------
// One 32-key tile with defer-max online softmax (THR=8); l kept as per-lane
// partials (reduced once at kernel end). Mask handled via the 32x32 any-zero
// flag grid: all-ones tiles (block-uniform test) skip all mask loads/FMAs.
// MFMA clusters wrapped in s_setprio (T5).
__device__ __forceinline__ void attn_tile(
    const unsigned short* sK, const unsigned short* sV,
    unsigned short (*sPw)[40], const bf16x8 qf[8],
    const float* __restrict__ maskG, const int* __restrict__ Fz,
    int transposed, int R0, int j0,
    int lane, int wave, int col, int quad, f32x4 o[16], float m[4], float l[4])
{
    // ---- S = Q K^T ----
    f32x4 sacc[2];
    sacc[0][0]=0.f; sacc[0][1]=0.f; sacc[0][2]=0.f; sacc[0][3]=0.f;
    sacc[1][0]=0.f; sacc[1][1]=0.f; sacc[1][2]=0.f; sacc[1][3]=0.f;
    __builtin_amdgcn_s_setprio(1);
    #pragma unroll
    for (int t = 0; t < 2; ++t) {
        #pragma unroll
        for (int s = 0; s < 8; ++s) {
            bf16x8 kf = *reinterpret_cast<const bf16x8*>(
                &sK[(t * 8 + s) * 512 + lane * 8]);
            sacc[t] = __builtin_amdgcn_mfma_f32_16x16x32_bf16(qf[s], kf, sacc[t], 0, 0, 0);
        }
    }
    __builtin_amdgcn_s_setprio(0);

    // ---- mask (flag-gated; block-uniform branch) ----
    int anyz;
    if (!transposed) {
        // q rows = lig R0..R0+127 (4 row32 groups), keys = rec j0..j0+31
        const int base = (R0 >> 5) * FCOLS + (j0 >> 5);
        anyz = Fz[base] | Fz[base + FCOLS] | Fz[base + 2 * FCOLS]
             | Fz[base + 3 * FCOLS];
    } else {
        // keys = lig j0..j0+31 (1 row32 group), q cols = rec R0..R0+127
        const int base = (j0 >> 5) * FCOLS + (R0 >> 5);
        anyz = Fz[base] | Fz[base + 1] | Fz[base + 2] | Fz[base + 3];
    }
    float a[2][4];
    if (anyz) {
        #pragma unroll
        for (int t = 0; t < 2; ++t)
            #pragma unroll
            for (int r = 0; r < 4; ++r) {
                float mv;
                if (!transposed)
                    mv = maskG[(size_t)(R0 + wave * 16 + quad * 4 + r) * N_REC
                               + j0 + col + 16 * t];
                else
                    mv = maskG[(size_t)(j0 + col + 16 * t) * N_REC
                               + R0 + wave * 16 + quad * 4 + r];
                a[t][r] = mv * sacc[t][r] - 1000.f * (1.f - mv);
            }
    } else {
        #pragma unroll
        for (int t = 0; t < 2; ++t)
            #pragma unroll
            for (int r = 0; r < 4; ++r)
                a[t][r] = sacc[t][r];
    }

    // ---- defer-max: rescale only when local max grows past m+8 ----
    float lm[4];
    #pragma unroll
    for (int r = 0; r < 4; ++r) lm[r] = fmaxf(a[0][r], a[1][r]);
    float w = lm[0] - m[0];
    #pragma unroll
    for (int r = 1; r < 4; ++r) w = fmaxf(w, lm[r] - m[r]);
    if (!__all(w <= 8.f)) {
        #pragma unroll
        for (int r = 0; r < 4; ++r) {
            float mx = lm[r];
            #pragma unroll
            for (int off = 1; off < 16; off <<= 1)
                mx = fmaxf(mx, __shfl_xor(mx, off));
            const float mn = fmaxf(m[r], mx);
            const float c  = __expf(m[r] - mn);
            m[r] = mn;
            l[r] *= c;
            #pragma unroll
            for (int dt = 0; dt < 16; ++dt) o[dt][r] *= c;
        }
    }

    // ---- P = exp(a - m), per-lane l partials ----
    #pragma unroll
    for (int r = 0; r < 4; ++r) {
        const float p0 = __expf(a[0][r] - m[r]);
        const float p1 = __expf(a[1][r] - m[r]);
        sPw[quad * 4 + r][col]      = f2bu(p0);
        sPw[quad * 4 + r][col + 16] = f2bu(p1);
        l[r] += p0 + p1;
    }

    // ---- O += P V ----
    bf16x8 pf = *reinterpret_cast<const bf16x8*>(&sPw[col][quad * 8]);
    __builtin_amdgcn_s_setprio(1);
    #pragma unroll
    for (int dt = 0; dt < 16; ++dt) {
        bf16x8 vf = *reinterpret_cast<const bf16x8*>(&sV[dt * 512 + lane * 8]);
        o[dt] = __builtin_amdgcn_mfma_f32_16x16x32_bf16(pf, vf, o[dt], 0, 0, 0);
    }
    __builtin_amdgcn_s_setprio(0);
}

// ---------------------------------------------------------------------------
// MFMA flash attention partial. 128 q-rows/block (8 waves x 16), 32-key
// tiles. K/V double-buffered in LDS via global_load_lds. Mask via flag grid.
__global__ __launch_bounds__(512) void attn_mfma(
    const __hip_bfloat16* __restrict__ Qb, const __hip_bfloat16* __restrict__ Kz,
    const __hip_bfloat16* __restrict__ Vz, const float* __restrict__ maskG,
    const int* __restrict__ Fz,
    float* __restrict__ PO, float* __restrict__ PM, float* __restrict__ PL,
    int M, int chunkKeys, int transposed)
{
    __shared__ unsigned short sKb[2][8192];   // 2 x 16 KB
    __shared__ unsigned short sVb[2][8192];   // 2 x 16 KB
    __shared__ unsigned short sP[8][16][40];  // 10 KB

    const int tid  = threadIdx.x;
    const int lane = tid & 63;
    const int wave = tid >> 6;
    const int col  = lane & 15;
    const int quad = lane >> 4;
    const int R0   = blockIdx.x * 128;
    const int split = blockIdx.y;
    const int jbase = split * chunkKeys;

    bf16x8 qf[8];
    {
        const __hip_bfloat16* qp =
            Qb + (size_t)(R0 + wave * 16 + col) * HD + quad * 8;
        #pragma unroll
        for (int s = 0; s < 8; ++s)
            qf[s] = *reinterpret_cast<const bf16x8*>(qp + 32 * s);
    }

    f32x4 o[16];
    #pragma unroll
    for (int dt = 0; dt < 16; ++dt) { o[dt][0]=0.f; o[dt][1]=0.f; o[dt][2]=0.f; o[dt][3]=0.f; }
    float m[4], l[4];
    #pragma unroll
    for (int r = 0; r < 4; ++r) { m[r] = -INFINITY; l[r] = 0.f; }

    // ---- prologue: tile 0 -> buf0 ----
    stage_tile(Kz + (size_t)jbase * 256, &sKb[0][0], wave, lane);
    stage_tile(Vz + (size_t)jbase * 256, &sVb[0][0], wave, lane);

    for (int jt = 0; jt < chunkKeys; jt += 64) {
        // ===== phase A: compute tile jt (buf0); stage jt+32 =====
        asm volatile("s_waitcnt vmcnt(0)" ::: "memory");
        __builtin_amdgcn_s_barrier();
        __builtin_amdgcn_sched_barrier(0);
        stage_tile(Kz + (size_t)(jbase + jt + 32) * 256, &sKb[1][0], wave, lane);
        stage_tile(Vz + (size_t)(jbase + jt + 32) * 256, &sVb[1][0], wave, lane);
        __builtin_amdgcn_sched_barrier(0);
        attn_tile(&sKb[0][0], &sVb[0][0], sP[wave], qf,
                  maskG, Fz, transposed, R0, jbase + jt,
                  lane, wave, col, quad, o, m, l);

        // ===== phase B: compute tile jt+32 (buf1); stage jt+64 =====
        asm volatile("s_waitcnt vmcnt(0)" ::: "memory");
        __builtin_amdgcn_s_barrier();
        __builtin_amdgcn_sched_barrier(0);
        if (jt + 64 < chunkKeys) {
            stage_tile(Kz + (size_t)(jbase + jt + 64) * 256, &sKb[0][0], wave, lane);
            stage_tile(Vz + (size_t)(jbase + jt + 64) * 256, &sVb[0][0], wave, lane);
        }
        __builtin_amdgcn_sched_barrier(0);
        attn_tile(&sKb[1][0], &sVb[1][0], sP[wave], qf,
                  maskG, Fz, transposed, R0, jbase + jt + 32,
                  lane, wave, col, quad, o, m, l);
    }

    // ---- final l reduction (per-lane partials -> 16-lane row sums) ----
    #pragma unroll
    for (int r = 0; r < 4; ++r) {
        #pragma unroll
        for (int off = 1; off < 16; off <<= 1)
            l[r] += __shfl_xor(l[r], off);
    }

    #pragma unroll
    for (int dt = 0; dt < 16; ++dt)
        #pragma unroll
        for (int r = 0; r < 4; ++r) {
            const int row = R0 + wave * 16 + quad * 4 + r;
            PO[((size_t)split * M + row) * HD + dt * 16 + col] = o[dt][r];
        }
    if (col == 0) {
        #pragma unroll
        for (int r = 0; r < 4; ++r) {
            const int row = R0 + wave * 16 + quad * 4 + r;
            PM[(size_t)split * M + row] = m[r];
            PL[(size_t)split * M + row] = l[r];
        }
    }
}

// ---------------------------------------------------------------------------
__global__ void attn_combine(
    const float* __restrict__ PO, const float* __restrict__ PM,
    const float* __restrict__ PL, __hip_bfloat16* __restrict__ Out,
    int M, int nchunks)
{
    const int idx = blockIdx.x * 256 + threadIdx.x;
    const int row = idx >> 8;
    float mmax = -INFINITY;
    for (int c = 0; c < nchunks; ++c) mmax = fmaxf(mmax, PM[(size_t)c * M + row]);
    float denom = 0.f, acc = 0.f;
    for (int c = 0; c < nchunks; ++c) {
        const float w = __expf(PM[(size_t)c * M + row] - mmax);
        denom += PL[(size_t)c * M + row] * w;
        acc   += PO[(size_t)c * M * HD + idx] * w;
    }
    Out[idx] = __float2bfloat16(acc / denom);
}

// ---------------------------------------------------------------------------
__global__ void coords_fin(
    const float* __restrict__ coords, const float* __restrict__ origc,
    const float* __restrict__ xsum, const float* __restrict__ cnt,
    float* __restrict__ out, int n)
{
    const int i = blockIdx.x * 256 + threadIdx.x;
    if (i >= n * 3) return;
    const int node = i / 3;
    const float inv = 1.f / fmaxf(cnt[node], 1.f);
    out[i] = 0.25f * origc[i] + 0.75f * coords[i] + xsum[i] * inv;
}

// ---------------------------------------------------------------------------
extern "C" void kernel_launch(void* const* d_in, const int* in_sizes, int n_in,
                              void* d_out, int out_size, void* d_ws, size_t ws_size,
                              hipStream_t stream)
{
    const float* coords_lig = (const float*)d_in[0];
    const float* h_lig      = (const float*)d_in[1];
    const float* orig_lig   = (const float*)d_in[2];
    const float* origc_lig  = (const float*)d_in[3];
    const float* coords_rec = (const float*)d_in[4];
    const float* h_rec      = (const float*)d_in[5];
    const float* orig_rec   = (const float*)d_in[6];
    const float* origc_rec  = (const float*)d_in[7];
    const float* mask       = (const float*)d_in[8];
    const float* lig_ef     = (const float*)d_in[9];
    const float* rec_ef     = (const float*)d_in[10];
    const int* lig_src = (const int*)d_in[11];
    const int* lig_dst = (const int*)d_in[12];
    const int* rec_src = (const int*)d_in[13];
    const int* rec_dst = (const int*)d_in[14];
    const float* le_w1 = (const float*)d_in[15];
    const float* le_b1 = (const float*)d_in[16];
    const float* le_w2 = (const float*)d_in[17];
    const float* le_b2 = (const float*)d_in[18];
    const float* re_w1 = (const float*)d_in[19];
    const float* re_b1 = (const float*)d_in[20];
    const float* re_w2 = (const float*)d_in[21];
    const float* re_b2 = (const float*)d_in[22];
    const float* aql_w = (const float*)d_in[23];
    const float* akl_w = (const float*)d_in[24];
    const float* avl_w = (const float*)d_in[25];
    const float* aqr_w = (const float*)d_in[26];
    const float* akr_w = (const float*)d_in[27];
    const float* avr_w = (const float*)d_in[28];
    const float* nl_w1 = (const float*)d_in[29];
    const float* nl_b1 = (const float*)d_in[30];
    const float* nl_w2 = (const float*)d_in[31];
    const float* nl_b2 = (const float*)d_in[32];
    const float* nr_w1 = (const float*)d_in[33];
    const float* nr_b1 = (const float*)d_in[34];
    const float* nr_w2 = (const float*)d_in[35];
    const float* nr_b2 = (const float*)d_in[36];
    const float* cl_w1 = (const float*)d_in[37];
    const float* cl_b1 = (const float*)d_in[38];
    const float* cl_w2 = (const float*)d_in[39];
    const float* cl_b2 = (const float*)d_in[40];
    const float* cr_w1 = (const float*)d_in[41];
    const float* cr_b1 = (const float*)d_in[42];
    const float* cr_w2 = (const float*)d_in[43];
    const float* cr_b2 = (const float*)d_in[44];

    float* out = (float*)d_out;
    float* wsf = (float*)d_ws;

    // ---- fp32 accumulator + CSR + mask-flag zone ----
    const size_t AGGRL = 0;
    const size_t AGGRR = AGGRL + (size_t)N_LIG * HD;
    const size_t CNTL  = AGGRR + (size_t)N_REC * HD;
    const size_t CNTR  = CNTL + N_LIG;
    const size_t XSUML = CNTR + N_REC;
    const size_t XSUMR = XSUML + (size_t)N_LIG * 3;
    const size_t HISTL = XSUMR + (size_t)N_REC * 3;
    const size_t CURL  = HISTL + N_LIG;
    const size_t HISTR = CURL + N_LIG;
    const size_t CURR  = HISTR + N_REC;
    const size_t FLAGS = CURR + N_REC;              // int[128][512] mask flags
    const size_t ZEND  = FLAGS + (size_t)(N_LIG / 32) * FCOLS;   // zeroed
    const size_t ELISTL = ZEND;                     // not zeroed
    const size_t ELISTR = ELISTL + E_LIG_N;
    const size_t FEND   = ELISTR + E_REC_N;

    // ---- bf16 zone ----
    __hip_bfloat16* wsb = (__hip_bfloat16*)(wsf + FEND);
    const size_t QL  = 0;
    const size_t KL  = QL + (size_t)N_LIG * HD;   // unused (kept for layout)
    const size_t VL  = KL + (size_t)N_LIG * HD;   // unused
    const size_t QR  = VL + (size_t)N_LIG * HD;
    const size_t KR  = QR + (size_t)N_REC * HD;   // unused
    const size_t VR  = KR + (size_t)N_REC * HD;   // unused
    const size_t CRL = VR + (size_t)N_REC * HD;
    const size_t CRR = CRL + (size_t)N_LIG * HD;
    const size_t KZL = CRR + (size_t)N_REC * HD;          // K swizzled lig
    const size_t VZL = KZL + (size_t)N_LIG * HD;          // V swizzled lig
    const size_t KZR = VZL + (size_t)N_LIG * HD;          // K swizzled rec
    const size_t VZR = KZR + (size_t)N_REC * HD;          // V swizzled rec
    const size_t EW1SZ = (size_t)16 * 17 * 512;
    const size_t KW256 = (size_t)16 * 8 * 512;
    const size_t NW1SZ = (size_t)16 * 18 * 512;
    const size_t SW_EL1 = VZR + (size_t)N_REC * HD;
    const size_t SW_EL2 = SW_EL1 + EW1SZ;
    const size_t SW_EC1 = SW_EL2 + KW256;
    const size_t SW_NL1 = SW_EC1 + KW256;
    const size_t SW_NL2 = SW_NL1 + NW1SZ;
    const size_t SW_ER1 = SW_NL2 + KW256;
    const size_t SW_ER2 = SW_ER1 + EW1SZ;
    const size_t SW_EC1R = SW_ER2 + KW256;
    const size_t SW_NR1 = SW_EC1R + KW256;
    const size_t SW_NR2 = SW_NR1 + NW1SZ;
    const size_t SW_PQL = SW_NR2 + KW256;
    const size_t SW_PKL = SW_PQL + KW256;
    const size_t SW_PVL = SW_PKL + KW256;
    const size_t SW_PQR = SW_PVL + KW256;
    const size_t SW_PKR = SW_PQR + KW256;
    const size_t SW_PVR = SW_PKR + KW256;
    // pre-converted bf16 operand blobs
    const size_t HB_L  = SW_PVR + KW256;
    const size_t HB_R  = HB_L + (size_t)N_LIG * HD;
    const size_t EFB_L = HB_R + (size_t)N_REC * HD;
    const size_t EFB_R = EFB_L + (size_t)E_LIG_N * EFD;
    const size_t BF_END = EFB_R + (size_t)E_REC_N * EFD;

    // ---- split-K partial zone (fp32), dynamic splits ----
    float* wsp = (float*)(wsb + ((BF_END + 1) & ~(size_t)1));
    const size_t baseBytes = (size_t)((char*)wsp - (char*)d_ws);
    int SL = 16, SR = 4;
    {
        const size_t poElems16 = (size_t)16 * N_LIG * HD;
        const size_t need16 = baseBytes +
            (poElems16 + 2 * (size_t)16 * N_LIG) * sizeof(float);
        if (ws_size < need16) { SL = 8; SR = 2; }
    }
    const size_t PO_ = 0;
    const size_t PM_ = PO_ + (size_t)SL * N_LIG * HD;
    const size_t PL_ = PM_ + (size_t)SL * N_LIG;

    const size_t O_XL = 0;
    const size_t O_HL = O_XL + (size_t)N_LIG * 3;
    const size_t O_XR = O_HL + (size_t)N_LIG * HD;
    const size_t O_HR = O_XR + (size_t)N_REC * 3;

    // 1) zero atomic accumulators + CSR hist/cursors + mask flags
    zero_kernel<<<((int)ZEND + 255) / 256, 256, 0, stream>>>(wsf, (int)ZEND);

    // 1a) mask flag scan (one coalesced pass over the fp32 mask)
    scanmask_kernel<<<(N_LIG * (N_REC / 16)) / 256, 256, 0, stream>>>(
        mask, (int*)(wsf + FLAGS));

    // 1b) fp32 -> bf16 operand blobs (h and edge features)
    f2b_kernel<<<(N_LIG * HD / 8 + 255) / 256, 256, 0, stream>>>(
        h_lig, wsb + HB_L, N_LIG * HD / 8);
    f2b_kernel<<<(N_REC * HD / 8 + 255) / 256, 256, 0, stream>>>(
        h_rec, wsb + HB_R, N_REC * HD / 8);
    f2b_kernel<<<(E_LIG_N * EFD / 8 + 255) / 256, 256, 0, stream>>>(
        lig_ef, wsb + EFB_L, E_LIG_N * EFD / 8);
    f2b_kernel<<<(E_REC_N * EFD / 8 + 255) / 256, 256, 0, stream>>>(
        rec_ef, wsb + EFB_R, E_REC_N * EFD / 8);

    // 1c) CSR build: dst-sorted edge permutations (also produces fp32 counts)
    hist_kernel<<<E_LIG_N / 256, 256, 0, stream>>>(lig_dst, (int*)(wsf + HISTL), E_LIG_N);
    hist_kernel<<<E_REC_N / 256, 256, 0, stream>>>(rec_dst, (int*)(wsf + HISTR), E_REC_N);
    scan_kernel<<<1, 256, 0, stream>>>((int*)(wsf + HISTL), (int*)(wsf + CURL),
                                       wsf + CNTL, N_LIG);
    scan_kernel<<<1, 256, 0, stream>>>((int*)(wsf + HISTR), (int*)(wsf + CURR),
                                       wsf + CNTR, N_REC);
    scatter_kernel<<<E_LIG_N / 256, 256, 0, stream>>>(
        lig_dst, (int*)(wsf + CURL), (int*)(wsf + ELISTL), E_LIG_N);
    scatter_kernel<<<E_REC_N / 256, 256, 0, stream>>>(
        rec_dst, (int*)(wsf + CURR), (int*)(wsf + ELISTR), E_REC_N);

    // 2) weight swizzles
    wt_swz<<<16 * 17, 256, 0, stream>>>(le_w1, wsb + SW_EL1, EIN, 17);
    wt_swz<<<16 * 8,  256, 0, stream>>>(le_w2, wsb + SW_EL2, 256, 8);
    wt_swz<<<16 * 8,  256, 0, stream>>>(cl_w1, wsb + SW_EC1, 256, 8);
    wt_swz<<<16 * 18, 256, 0, stream>>>(nl_w1, wsb + SW_NL1, 576, 18);
    wt_swz<<<16 * 8,  256, 0, stream>>>(nl_w2, wsb + SW_NL2, 256, 8);
    wt_swz<<<16 * 17, 256, 0, stream>>>(re_w1, wsb + SW_ER1, EIN, 17);
    wt_swz<<<16 * 8,  256, 0, stream>>>(re_w2, wsb + SW_ER2, 256, 8);
    wt_swz<<<16 * 8,  256, 0, stream>>>(cr_w1, wsb + SW_EC1R, 256, 8);
    wt_swz<<<16 * 18, 256, 0, stream>>>(nr_w1, wsb + SW_NR1, 576, 18);
    wt_swz<<<16 * 8,  256, 0, stream>>>(nr_w2, wsb + SW_NR2, 256, 8);
    wt_swz<<<16 * 8,  256, 0, stream>>>(aql_w, wsb + SW_PQL, 256, 8);
    wt_swz<<<16 * 8,  256, 0, stream>>>(akl_w, wsb + SW_PKL, 256, 8);
    wt_swz<<<16 * 8,  256, 0, stream>>>(avl_w, wsb + SW_PVL, 256, 8);
    wt_swz<<<16 * 8,  256, 0, stream>>>(aqr_w, wsb + SW_PQR, 256, 8);
    wt_swz<<<16 * 8,  256, 0, stream>>>(akr_w, wsb + SW_PKR, 256, 8);
    wt_swz<<<16 * 8,  256, 0, stream>>>(avr_w, wsb + SW_PVR, 256, 8);

    // 3) edge MFMA kernels (32 edges/block, dst-sorted, segmented atomics)
    edge_mfma<<<E_LIG_N / 32, 256, 0, stream>>>(
        coords_lig, wsb + HB_L, wsb + EFB_L, lig_src, lig_dst,
        (const int*)(wsf + ELISTL),
        wsb + SW_EL1, le_b1, wsb + SW_EL2, le_b2, wsb + SW_EC1, cl_b1, cl_w2, cl_b2,
        wsf + AGGRL, wsf + XSUML);
    edge_mfma<<<E_REC_N / 32, 256, 0, stream>>>(
        coords_rec, wsb + HB_R, wsb + EFB_R, rec_src, rec_dst,
        (const int*)(wsf + ELISTR),
        wsb + SW_ER1, re_b1, wsb + SW_ER2, re_b2, wsb + SW_EC1R, cr_b1, cr_w2, cr_b2,
        wsf + AGGRR, wsf + XSUMR);

    // 4) fused q/k/v projections (K/V written directly in fragment-blob order)
    qkv_proj<<<N_LIG / 32, 256, 0, stream>>>(
        wsb + HB_L, wsb + SW_PQL, wsb + SW_PKL, wsb + SW_PVL,
        wsb + QL, wsb + KZL, wsb + VZL);
    qkv_proj<<<N_REC / 32, 256, 0, stream>>>(
        wsb + HB_R, wsb + SW_PQR, wsb + SW_PKR, wsb + SW_PVR,
        wsb + QR, wsb + KZR, wsb + VZR);

    // 5) MFMA flash attention, split-K + combine
    {
        dim3 gl(N_LIG / 128, SL);
        attn_mfma<<<gl, 512, 0, stream>>>(wsb + QL, wsb + KZR, wsb + VZR, mask,
                                          (const int*)(wsf + FLAGS),
                                          wsp + PO_, wsp + PM_, wsp + PL_,
                                          N_LIG, N_REC / SL, 0);
        attn_combine<<<N_LIG, 256, 0, stream>>>(
            wsp + PO_, wsp + PM_, wsp + PL_, wsb + CRL, N_LIG, SL);

        dim3 gr(N_REC / 128, SR);
        attn_mfma<<<gr, 512, 0, stream>>>(wsb + QR, wsb + KZL, wsb + VZL, mask,
                                          (const int*)(wsf + FLAGS),
                                          wsp + PO_, wsp + PM_, wsp + PL_,
                                          N_REC, N_LIG / SR, 1);
        attn_combine<<<N_REC, 256, 0, stream>>>(
            wsp + PO_, wsp + PM_, wsp + PL_, wsb + CRR, N_REC, SR);
    }

    // 6) coordinate outputs
    coords_fin<<<(N_LIG * 3 + 255) / 256, 256, 0, stream>>>(
        coords_lig, origc_lig, wsf + XSUML, wsf + CNTL, out + O_XL, N_LIG);
    coords_fin<<<(N_REC * 3 + 255) / 256, 256, 0, stream>>>(
        coords_rec, origc_rec, wsf + XSUMR, wsf + CNTR, out + O_XR, N_REC);

    // 7) node MFMA kernels
    node_mfma<<<N_LIG / 32, 256, 0, stream>>>(
        wsf + AGGRL, wsf + CNTL, wsb + CRL, orig_lig, h_lig,
        wsb + SW_NL1, nl_b1, wsb + SW_NL2, nl_b2, out + O_HL);
    node_mfma<<<N_REC / 32, 256, 0, stream>>>(
        wsf + AGGRR, wsf + CNTR, wsb + CRR, orig_rec, h_rec,
        wsb + SW_NR1, nr_b1, wsb + SW_NR2, nr_b2, out + O_HR);

    (void)in_sizes; (void)n_in; (void)out_size;
}

// Round 17
// 1185.896 us; speedup vs baseline: 1.1323x; 1.0637x over previous
//
#include <hip/hip_runtime.h>
#include <hip/hip_bf16.h>

// ---------------------------------------------------------------------------
// IEGMN layer, MI355X round-25: r24 (best, 1261.5 us) + dispatch fusion.
// Kernel BODIES unchanged (r24 proven); independent lig/rec dispatch pairs
// and the 16 tiny wt_swz / 4 f2b / CSR kernels are merged via block-range
// branches (params in by-value structs). 38 -> 17 dispatches, removing
// ~23 launch/tail overheads. Attention + combine stay split (PO zone reuse).
// ---------------------------------------------------------------------------

#define N_LIG   4096
#define N_REC   16384
#define E_LIG_N 65536
#define E_REC_N 262144
#define HD      256
#define ORIGD   64
#define EFD     16
#define NSIG    15
#define EIN     543
#define XP      552
#define XPN     584
#define XPP     264
#define FP      264
#define FCOLS   (N_REC / 32)

typedef __bf16 bf16x8 __attribute__((ext_vector_type(8)));
typedef float  f32x4  __attribute__((ext_vector_type(4)));

__device__ __forceinline__ float lrelu(float x) { return x > 0.f ? x : 0.01f * x; }
__device__ __forceinline__ unsigned short f2bu(float f) {
    __hip_bfloat16 h = __float2bfloat16(f);
    return *reinterpret_cast<unsigned short*>(&h);
}

__device__ __forceinline__ void glds16(const void* g, void* l) {
    __builtin_amdgcn_global_load_lds(
        (const __attribute__((address_space(1))) void*)g,
        (__attribute__((address_space(3))) void*)l,
        16, 0, 0);
}

__device__ __forceinline__ void stage_tile(
    const __hip_bfloat16* g, unsigned short* l, int wave, int lane)
{
    #pragma unroll
    for (int i = 0; i < 2; ++i) {
        const __hip_bfloat16* gp = g + (size_t)(i * 512 + wave * 64 + lane) * 8;
        unsigned short* lp = l + (i * 512 + wave * 64) * 8;
        glds16(gp, lp);
    }
}

// ---------------------------------------------------------------------------
// Shared 32xKx256 GEMM core. Even/odd depth-2 pipeline + T5 setprio.
__device__ __forceinline__ void mfma_gemm(
    const unsigned short* sA, int pitch,
    const __hip_bfloat16* Wswz, int KS, int lane, f32x4 acc[2][4])
{
    const int col = lane & 15, quad = lane >> 4;
    const unsigned short* a0p = sA + (size_t)col * pitch + quad * 8;
    const unsigned short* a1p = sA + (size_t)(16 + col) * pitch + quad * 8;
    const __hip_bfloat16* wp = Wswz + lane * 8;

    bf16x8 bE[4], bO[4], aE0, aE1, aO0, aO1;
    #pragma unroll
    for (int nt = 0; nt < 4; ++nt) {
        bE[nt] = *reinterpret_cast<const bf16x8*>(wp + (size_t)nt * KS * 512);
        bO[nt] = *reinterpret_cast<const bf16x8*>(wp + ((size_t)nt * KS + 1) * 512);
    }
    aE0 = *reinterpret_cast<const bf16x8*>(a0p);
    aE1 = *reinterpret_cast<const bf16x8*>(a1p);
    aO0 = *reinterpret_cast<const bf16x8*>(a0p + 32);
    aO1 = *reinterpret_cast<const bf16x8*>(a1p + 32);

    int ks = 0;
    for (; ks + 2 <= KS; ks += 2) {
        __builtin_amdgcn_s_setprio(1);
        #pragma unroll
        for (int nt = 0; nt < 4; ++nt) {
            acc[0][nt] = __builtin_amdgcn_mfma_f32_16x16x32_bf16(aE0, bE[nt], acc[0][nt], 0, 0, 0);
            acc[1][nt] = __builtin_amdgcn_mfma_f32_16x16x32_bf16(aE1, bE[nt], acc[1][nt], 0, 0, 0);
        }
        __builtin_amdgcn_s_setprio(0);
        if (ks + 2 < KS) {
            #pragma unroll
            for (int nt = 0; nt < 4; ++nt)
                bE[nt] = *reinterpret_cast<const bf16x8*>(
                    wp + ((size_t)nt * KS + ks + 2) * 512);
            aE0 = *reinterpret_cast<const bf16x8*>(a0p + (ks + 2) * 32);
            aE1 = *reinterpret_cast<const bf16x8*>(a1p + (ks + 2) * 32);
        }
        __builtin_amdgcn_s_setprio(1);
        #pragma unroll
        for (int nt = 0; nt < 4; ++nt) {
            acc[0][nt] = __builtin_amdgcn_mfma_f32_16x16x32_bf16(aO0, bO[nt], acc[0][nt], 0, 0, 0);
            acc[1][nt] = __builtin_amdgcn_mfma_f32_16x16x32_bf16(aO1, bO[nt], acc[1][nt], 0, 0, 0);
        }
        __builtin_amdgcn_s_setprio(0);
        if (ks + 3 < KS) {
            #pragma unroll
            for (int nt = 0; nt < 4; ++nt)
                bO[nt] = *reinterpret_cast<const bf16x8*>(
                    wp + ((size_t)nt * KS + ks + 3) * 512);
            aO0 = *reinterpret_cast<const bf16x8*>(a0p + (ks + 3) * 32);
            aO1 = *reinterpret_cast<const bf16x8*>(a1p + (ks + 3) * 32);
        }
    }
    if (ks < KS) {
        __builtin_amdgcn_s_setprio(1);
        #pragma unroll
        for (int nt = 0; nt < 4; ++nt) {
            acc[0][nt] = __builtin_amdgcn_mfma_f32_16x16x32_bf16(aE0, bE[nt], acc[0][nt], 0, 0, 0);
            acc[1][nt] = __builtin_amdgcn_mfma_f32_16x16x32_bf16(aE1, bE[nt], acc[1][nt], 0, 0, 0);
        }
        __builtin_amdgcn_s_setprio(0);
    }
}

// ---------------------------------------------------------------------------
__global__ void zero_kernel(float* __restrict__ p, int n) {
    int i = blockIdx.x * 256 + threadIdx.x;
    if (i < n) p[i] = 0.f;
}

// ---------------------------------------------------------------------------
// Mask scan (r23): F[lig32][rec32] = 1 if any mask elem != 1.0.
__global__ void scanmask_kernel(const float* __restrict__ mask,
                                int* __restrict__ F)
{
    const size_t t = (size_t)blockIdx.x * 256 + threadIdx.x;
    const int r  = (int)(t >> 10);
    const int c0 = ((int)t & 1023) * 16;
    const float4* p = reinterpret_cast<const float4*>(
        &mask[(size_t)r * N_REC + c0]);
    bool ok = true;
    #pragma unroll
    for (int i = 0; i < 4; ++i) {
        const float4 v = p[i];
        ok = ok && (v.x == 1.f) && (v.y == 1.f) && (v.z == 1.f) && (v.w == 1.f);
    }
    if (!ok) atomicOr(&F[(r >> 5) * FCOLS + (c0 >> 5)], 1);
}

// ---------------------------------------------------------------------------
// Merged fp32->bf16 conversions (4 jobs).
struct F2bJobs {
    const float* src[4];
    __hip_bfloat16* dst[4];
    int n8[4];
    int blk0[5];
};
__global__ void f2b_all(F2bJobs J) {
    int j = 0;
    #pragma unroll
    for (int k = 1; k < 4; ++k) if ((int)blockIdx.x >= J.blk0[k]) j = k;
    const int i = (blockIdx.x - J.blk0[j]) * 256 + threadIdx.x;
    if (i >= J.n8[j]) return;
    const float* src = J.src[j];
    const float4 a = *reinterpret_cast<const float4*>(src + (size_t)i * 8);
    const float4 b = *reinterpret_cast<const float4*>(src + (size_t)i * 8 + 4);
    ushort4 u0 = { f2bu(a.x), f2bu(a.y), f2bu(a.z), f2bu(a.w) };
    ushort4 u1 = { f2bu(b.x), f2bu(b.y), f2bu(b.z), f2bu(b.w) };
    unsigned short* d = (unsigned short*)J.dst[j] + (size_t)i * 8;
    *reinterpret_cast<ushort4*>(d)     = u0;
    *reinterpret_cast<ushort4*>(d + 4) = u1;
}

// ---------------------------------------------------------------------------
// Merged CSR build kernels (lig + rec in one dispatch each).
__global__ void hist_all(const int* __restrict__ dL, int* __restrict__ hL,
                         const int* __restrict__ dR, int* __restrict__ hR,
                         int nLigBlk, int nL, int nR) {
    const int isR = (int)blockIdx.x >= nLigBlk;
    const int* dst = isR ? dR : dL;
    int* hist = isR ? hR : hL;
    const int n = isR ? nR : nL;
    const int i = (blockIdx.x - (isR ? nLigBlk : 0)) * 256 + threadIdx.x;
    if (i < n) atomicAdd(&hist[dst[i]], 1);
}

__global__ __launch_bounds__(256) void scan_all(
    const int* __restrict__ hL, int* __restrict__ cL, float* __restrict__ fL,
    const int* __restrict__ hR, int* __restrict__ cR, float* __restrict__ fR)
{
    const int isR = blockIdx.x;          // 0 = lig, 1 = rec
    const int* hist = isR ? hR : hL;
    int* cur = isR ? cR : cL;
    float* cntf = isR ? fR : fL;
    const int n = isR ? N_REC : N_LIG;

    __shared__ int part[256];
    const int tid = threadIdx.x;
    const int per = n >> 8;
    const int base = tid * per;
    int s = 0;
    for (int i = 0; i < per; ++i) s += hist[base + i];
    part[tid] = s;
    __syncthreads();
    #pragma unroll
    for (int off = 1; off < 256; off <<= 1) {
        int v = (tid >= off) ? part[tid - off] : 0;
        __syncthreads();
        part[tid] += v;
        __syncthreads();
    }
    int run = part[tid] - s;
    for (int i = 0; i < per; ++i) {
        const int h = hist[base + i];
        cur[base + i]  = run;
        cntf[base + i] = (float)h;
        run += h;
    }
}

__global__ void scatter_all(const int* __restrict__ dL, int* __restrict__ cL,
                            int* __restrict__ eL,
                            const int* __restrict__ dR, int* __restrict__ cR,
                            int* __restrict__ eR,
                            int nLigBlk, int nL, int nR) {
    const int isR = (int)blockIdx.x >= nLigBlk;
    const int* dst = isR ? dR : dL;
    int* cur = isR ? cR : cL;
    int* elist = isR ? eR : eL;
    const int n = isR ? nR : nL;
    const int i = (blockIdx.x - (isR ? nLigBlk : 0)) * 256 + threadIdx.x;
    if (i < n) { int p = atomicAdd(&cur[dst[i]], 1); elist[p] = i; }
}

// ---------------------------------------------------------------------------
// Merged weight swizzles: 16 jobs in one dispatch.
#define NSWZ 16
struct SwzJobs {
    const float* src[NSWZ];
    __hip_bfloat16* dst[NSWZ];
    int K[NSWZ];
    int KS[NSWZ];
    int blk0[NSWZ + 1];
};
__global__ void wt_swz_all(SwzJobs J) {
    int j = 0;
    for (int k = 1; k < NSWZ; ++k) if ((int)blockIdx.x >= J.blk0[k]) j = k;
    const int b  = blockIdx.x - J.blk0[j];
    const int KS = J.KS[j], K = J.K[j];
    const float* src = J.src[j];
    __hip_bfloat16* dst = J.dst[j];
    const int g  = b / KS;
    const int ks = b % KS;
    for (int i = threadIdx.x; i < 512; i += 256) {
        const int lane = i >> 3, jj = i & 7;
        const int n = g * 16 + (lane & 15);
        const int k = ks * 32 + (lane >> 4) * 8 + jj;
        const float v = (k < K) ? src[(size_t)k * 256 + n] : 0.f;
        dst[((size_t)(g * KS + ks) * 64 + lane) * 8 + jj] = __float2bfloat16(v);
    }
}

// ---------------------------------------------------------------------------
// Edge MFMA kernel (merged lig+rec): body identical to r24.
struct EdgeParams {
    const float* coords; const __hip_bfloat16* hb; const __hip_bfloat16* efb;
    const int* src; const int* dst; const int* elist;
    const __hip_bfloat16* W1s; const float* b1;
    const __hip_bfloat16* W2s; const float* b2;
    const __hip_bfloat16* Wc1s; const float* bc1;
    const float* wc2v; const float* bc2;
    float* aggr; float* xsum;
};
__global__ __launch_bounds__(256, 4) void edge_mfma(
    EdgeParams Lp, EdgeParams Rp, int nLigBlk)
{
    const int isR = (int)blockIdx.x >= nLigBlk;
    const EdgeParams& P = isR ? Rp : Lp;
    const int bx = blockIdx.x - (isR ? nLigBlk : 0);

    __shared__ unsigned short sX[32][XP];
    __shared__ float sXrel[32][3];
    __shared__ int   sDst[32];
    __shared__ int   sSrc[32];
    __shared__ int   sE[32];
    __shared__ float sRedW[4][32];
    __shared__ float sPv[32];

    const int tid  = threadIdx.x;
    const int lane = tid & 63;
    const int wave = tid >> 6;
    const int col  = lane & 15;
    const int quad = lane >> 4;
    const int e0   = bx * 32;

    if (tid < 32) {
        const int e = P.elist[e0 + tid];
        const int s = P.src[e], d = P.dst[e];
        sE[tid] = e; sSrc[tid] = s; sDst[tid] = d;
        float d2 = 0.f;
        #pragma unroll
        for (int c = 0; c < 3; ++c) {
            const float xr = P.coords[s * 3 + c] - P.coords[d * 3 + c];
            sXrel[tid][c] = xr;
            d2 += xr * xr;
        }
        float sig = 1.0f;
        #pragma unroll
        for (int si = 0; si < NSIG; ++si) {
            sX[tid][528 + si] = f2bu(__expf(-d2 / sig));
            sig *= 1.5f;
        }
        sX[tid][543] = 0;
    }
    __syncthreads();

    for (int i = tid; i < 32 * 64; i += 256) {
        const int row = i >> 6, c = i & 63;
        const int node = (c < 32) ? sSrc[row] : sDst[row];
        const int chunk = c & 31;
        *reinterpret_cast<uint4*>(&sX[row][(c < 32 ? 0 : 256) + chunk * 8]) =
            *reinterpret_cast<const uint4*>(&P.hb[(size_t)node * HD + chunk * 8]);
    }
    if (tid < 64) {
        const int row = tid >> 1, hh = tid & 1;
        *reinterpret_cast<uint4*>(&sX[row][512 + hh * 8]) =
            *reinterpret_cast<const uint4*>(&P.efb[(size_t)sE[row] * EFD + hh * 8]);
    }
    __syncthreads();

    f32x4 acc[2][4];
    f32x4 macc[2][4];

    #pragma unroll
    for (int nt = 0; nt < 4; ++nt) {
        const float bv = P.b1[wave * 64 + nt * 16 + col];
        acc[0][nt] = { bv, bv, bv, bv };
        acc[1][nt] = { bv, bv, bv, bv };
    }
    mfma_gemm(&sX[0][0], XP, P.W1s + (size_t)(wave * 4) * 17 * 512, 17, lane, acc);
    __syncthreads();
    #pragma unroll
    for (int mt = 0; mt < 2; ++mt)
        #pragma unroll
        for (int nt = 0; nt < 4; ++nt)
            #pragma unroll
            for (int r = 0; r < 4; ++r)
                sX[mt * 16 + quad * 4 + r][wave * 64 + nt * 16 + col] =
                    f2bu(lrelu(acc[mt][nt][r]));
    __syncthreads();

    #pragma unroll
    for (int nt = 0; nt < 4; ++nt) {
        const float bv = P.b2[wave * 64 + nt * 16 + col];
        macc[0][nt] = { bv, bv, bv, bv };
        macc[1][nt] = { bv, bv, bv, bv };
    }
    mfma_gemm(&sX[0][0], XP, P.W2s + (size_t)(wave * 4) * 8 * 512, 8, lane, macc);
    __syncthreads();
    #pragma unroll
    for (int mt = 0; mt < 2; ++mt)
        #pragma unroll
        for (int nt = 0; nt < 4; ++nt)
            #pragma unroll
            for (int r = 0; r < 4; ++r)
                sX[mt * 16 + quad * 4 + r][wave * 64 + nt * 16 + col] =
                    f2bu(macc[mt][nt][r]);
    __syncthreads();

    #pragma unroll
    for (int nt = 0; nt < 4; ++nt) {
        const float bv = P.bc1[wave * 64 + nt * 16 + col];
        acc[0][nt] = { bv, bv, bv, bv };
        acc[1][nt] = { bv, bv, bv, bv };
    }
    mfma_gemm(&sX[0][0], XP, P.Wc1s + (size_t)(wave * 4) * 8 * 512, 8, lane, acc);
    float w2l[4];
    #pragma unroll
    for (int nt = 0; nt < 4; ++nt) w2l[nt] = P.wc2v[wave * 64 + nt * 16 + col];
    #pragma unroll
    for (int mt = 0; mt < 2; ++mt) {
        float pr[4] = { 0.f, 0.f, 0.f, 0.f };
        #pragma unroll
        for (int nt = 0; nt < 4; ++nt)
            #pragma unroll
            for (int r = 0; r < 4; ++r)
                pr[r] += lrelu(acc[mt][nt][r]) * w2l[nt];
        #pragma unroll
        for (int r = 0; r < 4; ++r) {
            #pragma unroll
            for (int off = 1; off < 16; off <<= 1) pr[r] += __shfl_xor(pr[r], off);
        }
        if (col == 0)
            #pragma unroll
            for (int r = 0; r < 4; ++r)
                sRedW[wave][mt * 16 + quad * 4 + r] = pr[r];
    }
    __syncthreads();

    float* sF = reinterpret_cast<float*>(&sX[0][0]);
    #pragma unroll
    for (int mt = 0; mt < 2; ++mt)
        #pragma unroll
        for (int nt = 0; nt < 4; ++nt)
            #pragma unroll
            for (int r = 0; r < 4; ++r)
                sF[(mt * 16 + quad * 4 + r) * FP + wave * 64 + nt * 16 + col] =
                    macc[mt][nt][r];
    if (tid < 32)
        sPv[tid] = sRedW[0][tid] + sRedW[1][tid] + sRedW[2][tid] + sRedW[3][tid]
                 + P.bc2[0];
    __syncthreads();

    {
        const int c = tid;
        float av = 0.f;
        int dprev = sDst[0];
        for (int row = 0; row < 32; ++row) {
            const int d = sDst[row];
            if (d != dprev) {
                atomicAdd(&P.aggr[(size_t)dprev * HD + c], av);
                av = 0.f; dprev = d;
            }
            av += sF[row * FP + c];
        }
        atomicAdd(&P.aggr[(size_t)dprev * HD + c], av);
    }
    if (tid < 3) {
        const int c = tid;
        float av = 0.f;
        int dprev = sDst[0];
        for (int row = 0; row < 32; ++row) {
            const int d = sDst[row];
            if (d != dprev) {
                atomicAdd(&P.xsum[(size_t)dprev * 3 + c], av);
                av = 0.f; dprev = d;
            }
            av += sXrel[row][c] * sPv[row];
        }
        atomicAdd(&P.xsum[(size_t)dprev * 3 + c], av);
    }
}

// ---------------------------------------------------------------------------
// Node MFMA kernel (merged lig+rec): body identical to r24.
struct NodeParams {
    const float* aggr; const float* cnt; const __hip_bfloat16* cross;
    const float* orig; const float* hfeat;
    const __hip_bfloat16* WN1s; const float* b1;
    const __hip_bfloat16* WN2s; const float* b2;
    float* out;
};
__global__ __launch_bounds__(256, 4) void node_mfma(
    NodeParams Lp, NodeParams Rp, int nLigBlk)
{
    const int isR = (int)blockIdx.x >= nLigBlk;
    const NodeParams& P = isR ? Rp : Lp;
    const int bx = blockIdx.x - (isR ? nLigBlk : 0);

    __shared__ unsigned short sXn[32][XPN];
    __shared__ float sInv[32];

    const int tid  = threadIdx.x;
    const int lane = tid & 63;
    const int wave = tid >> 6;
    const int col  = lane & 15;
    const int quad = lane >> 4;
    const int r0   = bx * 32;

    if (tid < 32) sInv[tid] = 1.f / fmaxf(P.cnt[r0 + tid], 1.f);
    __syncthreads();

    for (int i = tid; i < 32 * 64; i += 256) {
        const int row = i >> 6, c4 = i & 63;
        const float inv = sInv[row];
        const float4 v = *reinterpret_cast<const float4*>(
            &P.aggr[(size_t)(r0 + row) * HD + c4 * 4]);
        ushort4 u = { f2bu(v.x * inv), f2bu(v.y * inv), f2bu(v.z * inv), f2bu(v.w * inv) };
        *reinterpret_cast<ushort4*>(&sXn[row][c4 * 4]) = u;
    }
    for (int i = tid; i < 32 * 64; i += 256) {
        const int row = i >> 6, c4 = i & 63;
        const ushort4 u = *reinterpret_cast<const ushort4*>(
            &P.cross[(size_t)(r0 + row) * HD + c4 * 4]);
        *reinterpret_cast<ushort4*>(&sXn[row][256 + c4 * 4]) = u;
    }
    for (int i = tid; i < 32 * 16; i += 256) {
        const int row = i >> 4, c4 = i & 15;
        const float4 v = *reinterpret_cast<const float4*>(
            &P.orig[(size_t)(r0 + row) * ORIGD + c4 * 4]);
        ushort4 u = { f2bu(v.x), f2bu(v.y), f2bu(v.z), f2bu(v.w) };
        *reinterpret_cast<ushort4*>(&sXn[row][512 + c4 * 4]) = u;
    }
    __syncthreads();

    f32x4 acc[2][4];

    #pragma unroll
    for (int nt = 0; nt < 4; ++nt) {
        const float bv = P.b1[wave * 64 + nt * 16 + col];
        acc[0][nt] = { bv, bv, bv, bv };
        acc[1][nt] = { bv, bv, bv, bv };
    }
    mfma_gemm(&sXn[0][0], XPN, P.WN1s + (size_t)(wave * 4) * 18 * 512, 18, lane, acc);
    __syncthreads();
    #pragma unroll
    for (int mt = 0; mt < 2; ++mt)
        #pragma unroll
        for (int nt = 0; nt < 4; ++nt)
            #pragma unroll
            for (int r = 0; r < 4; ++r)
                sXn[mt * 16 + quad * 4 + r][wave * 64 + nt * 16 + col] =
                    f2bu(lrelu(acc[mt][nt][r]));
    __syncthreads();

    #pragma unroll
    for (int nt = 0; nt < 4; ++nt) {
        const float bv = P.b2[wave * 64 + nt * 16 + col];
        acc[0][nt] = { bv, bv, bv, bv };
        acc[1][nt] = { bv, bv, bv, bv };
    }
    mfma_gemm(&sXn[0][0], XPN, P.WN2s + (size_t)(wave * 4) * 8 * 512, 8, lane, acc);
    #pragma unroll
    for (int mt = 0; mt < 2; ++mt)
        #pragma unroll
        for (int nt = 0; nt < 4; ++nt)
            #pragma unroll
            for (int r = 0; r < 4; ++r) {
                const int g = r0 + mt * 16 + quad * 4 + r;
                const int n = wave * 64 + nt * 16 + col;
                P.out[(size_t)g * HD + n] =
                    0.5f * acc[mt][nt][r] + 0.5f * P.hfeat[(size_t)g * HD + n];
            }
}

// ---------------------------------------------------------------------------
// Fused Q/K/V projection (merged lig+rec): body identical to r24.
struct QkvParams {
    const __hip_bfloat16* Xb;
    const __hip_bfloat16* Wq; const __hip_bfloat16* Wk; const __hip_bfloat16* Wv;
    __hip_bfloat16* Q; __hip_bfloat16* Kz; __hip_bfloat16* Vz;
};
__global__ __launch_bounds__(256, 4) void qkv_proj(
    QkvParams Lp, QkvParams Rp, int nLigBlk)
{
    const int isR = (int)blockIdx.x >= nLigBlk;
    const QkvParams& P = isR ? Rp : Lp;
    const int bx = blockIdx.x - (isR ? nLigBlk : 0);

    __shared__ unsigned short sXp[32][XPP];
    const int tid  = threadIdx.x;
    const int lane = tid & 63;
    const int wave = tid >> 6;
    const int col  = lane & 15;
    const int quad = lane >> 4;
    const int r0   = bx * 32;

    for (int i = tid; i < 32 * 32; i += 256) {
        const int row = i >> 5, c = i & 31;
        *reinterpret_cast<uint4*>(&sXp[row][c * 8]) =
            *reinterpret_cast<const uint4*>(&P.Xb[(size_t)(r0 + row) * HD + c * 8]);
    }
    __syncthreads();

    f32x4 acc[2][4];
    #pragma unroll
    for (int p = 0; p < 3; ++p) {
        const __hip_bfloat16* Ws = (p == 0) ? P.Wq : (p == 1) ? P.Wk : P.Wv;
        #pragma unroll
        for (int nt = 0; nt < 4; ++nt) {
            acc[0][nt] = { 0.f, 0.f, 0.f, 0.f };
            acc[1][nt] = { 0.f, 0.f, 0.f, 0.f };
        }
        mfma_gemm(&sXp[0][0], XPP, Ws + (size_t)(wave * 4) * 8 * 512, 8, lane, acc);
        #pragma unroll
        for (int mt = 0; mt < 2; ++mt)
            #pragma unroll
            for (int nt = 0; nt < 4; ++nt)
                #pragma unroll
                for (int r = 0; r < 4; ++r) {
                    float v = acc[mt][nt][r];
                    const int row = r0 + mt * 16 + quad * 4 + r;
                    const int c   = wave * 64 + nt * 16 + col;
                    if (p == 0) {
                        P.Q[(size_t)row * HD + c] = __float2bfloat16(lrelu(v));
                    } else if (p == 1) {
                        const int kt = row >> 4, rr = row & 15;
                        const int s  = c >> 5, cc8 = (c >> 3) & 3, j = c & 7;
                        P.Kz[(size_t)(kt * 8 + s) * 512 + (cc8 * 16 + rr) * 8 + j] =
                            __float2bfloat16(lrelu(v));
                    } else {
                        const int jt = row >> 5, rowin = row & 31;
                        const int dt = c >> 4, cc = c & 15;
                        P.Vz[((size_t)(jt * 16 + dt) * 64 + (rowin >> 3) * 16 + cc) * 8
                           + (rowin & 7)] = __float2bfloat16(v);
                    }
                }
    }
}

// ---------------------------------------------------------------------------
// Attention tile (r24: defer-max, flag-gated mask, setprio).
__device__ __forceinline__ void attn_tile(
    const unsigned short* sK, const unsigned short* sV,
    unsigned short (*sPw)[40], const bf16x8 qf[8],
    const float* __restrict__ maskG, const int* __restrict__ Fz,
    int transposed, int R0, int j0,
    int lane, int wave, int col, int quad, f32x4 o[16], float m[4], float l[4])
{
    f32x4 sacc[2];
    sacc[0][0]=0.f; sacc[0][1]=0.f; sacc[0][2]=0.f; sacc[0][3]=0.f;
    sacc[1][0]=0.f; sacc[1][1]=0.f; sacc[1][2]=0.f; sacc[1][3]=0.f;
    __builtin_amdgcn_s_setprio(1);
    #pragma unroll
    for (int t = 0; t < 2; ++t) {
        #pragma unroll
        for (int s = 0; s < 8; ++s) {
            bf16x8 kf = *reinterpret_cast<const bf16x8*>(
                &sK[(t * 8 + s) * 512 + lane * 8]);
            sacc[t] = __builtin_amdgcn_mfma_f32_16x16x32_bf16(qf[s], kf, sacc[t], 0, 0, 0);
        }
    }
    __builtin_amdgcn_s_setprio(0);

    int anyz;
    if (!transposed) {
        const int base = (R0 >> 5) * FCOLS + (j0 >> 5);
        anyz = Fz[base] | Fz[base + FCOLS] | Fz[base + 2 * FCOLS]
             | Fz[base + 3 * FCOLS];
    } else {
        const int base = (j0 >> 5) * FCOLS + (R0 >> 5);
        anyz = Fz[base] | Fz[base + 1] | Fz[base + 2] | Fz[base + 3];
    }
    float a[2][4];
    if (anyz) {
        #pragma unroll
        for (int t = 0; t < 2; ++t)
            #pragma unroll
            for (int r = 0; r < 4; ++r) {
                float mv;
                if (!transposed)
                    mv = maskG[(size_t)(R0 + wave * 16 + quad * 4 + r) * N_REC
                               + j0 + col + 16 * t];
                else
                    mv = maskG[(size_t)(j0 + col + 16 * t) * N_REC
                               + R0 + wave * 16 + quad * 4 + r];
                a[t][r] = mv * sacc[t][r] - 1000.f * (1.f - mv);
            }
    } else {
        #pragma unroll
        for (int t = 0; t < 2; ++t)
            #pragma unroll
            for (int r = 0; r < 4; ++r)
                a[t][r] = sacc[t][r];
    }

    float lm[4];
    #pragma unroll
    for (int r = 0; r < 4; ++r) lm[r] = fmaxf(a[0][r], a[1][r]);
    float w = lm[0] - m[0];
    #pragma unroll
    for (int r = 1; r < 4; ++r) w = fmaxf(w, lm[r] - m[r]);
    if (!__all(w <= 8.f)) {
        #pragma unroll
        for (int r = 0; r < 4; ++r) {
            float mx = lm[r];
            #pragma unroll
            for (int off = 1; off < 16; off <<= 1)
                mx = fmaxf(mx, __shfl_xor(mx, off));
            const float mn = fmaxf(m[r], mx);
            const float c  = __expf(m[r] - mn);
            m[r] = mn;
            l[r] *= c;
            #pragma unroll
            for (int dt = 0; dt < 16; ++dt) o[dt][r] *= c;
        }
    }

    #pragma unroll
    for (int r = 0; r < 4; ++r) {
        const float p0 = __expf(a[0][r] - m[r]);
        const float p1 = __expf(a[1][r] - m[r]);
        sPw[quad * 4 + r][col]      = f2bu(p0);
        sPw[quad * 4 + r][col + 16] = f2bu(p1);
        l[r] += p0 + p1;
    }

    bf16x8 pf = *reinterpret_cast<const bf16x8*>(&sPw[col][quad * 8]);
    __builtin_amdgcn_s_setprio(1);
    #pragma unroll
    for (int dt = 0; dt < 16; ++dt) {
        bf16x8 vf = *reinterpret_cast<const bf16x8*>(&sV[dt * 512 + lane * 8]);
        o[dt] = __builtin_amdgcn_mfma_f32_16x16x32_bf16(pf, vf, o[dt], 0, 0, 0);
    }
    __builtin_amdgcn_s_setprio(0);
}

// ---------------------------------------------------------------------------
// MFMA flash attention partial (r24 structure, unchanged).
__global__ __launch_bounds__(512) void attn_mfma(
    const __hip_bfloat16* __restrict__ Qb, const __hip_bfloat16* __restrict__ Kz,
    const __hip_bfloat16* __restrict__ Vz, const float* __restrict__ maskG,
    const int* __restrict__ Fz,
    float* __restrict__ PO, float* __restrict__ PM, float* __restrict__ PL,
    int M, int chunkKeys, int transposed)
{
    __shared__ unsigned short sKb[2][8192];
    __shared__ unsigned short sVb[2][8192];
    __shared__ unsigned short sP[8][16][40];

    const int tid  = threadIdx.x;
    const int lane = tid & 63;
    const int wave = tid >> 6;
    const int col  = lane & 15;
    const int quad = lane >> 4;
    const int R0   = blockIdx.x * 128;
    const int split = blockIdx.y;
    const int jbase = split * chunkKeys;

    bf16x8 qf[8];
    {
        const __hip_bfloat16* qp =
            Qb + (size_t)(R0 + wave * 16 + col) * HD + quad * 8;
        #pragma unroll
        for (int s = 0; s < 8; ++s)
            qf[s] = *reinterpret_cast<const bf16x8*>(qp + 32 * s);
    }

    f32x4 o[16];
    #pragma unroll
    for (int dt = 0; dt < 16; ++dt) { o[dt][0]=0.f; o[dt][1]=0.f; o[dt][2]=0.f; o[dt][3]=0.f; }
    float m[4], l[4];
    #pragma unroll
    for (int r = 0; r < 4; ++r) { m[r] = -INFINITY; l[r] = 0.f; }

    stage_tile(Kz + (size_t)jbase * 256, &sKb[0][0], wave, lane);
    stage_tile(Vz + (size_t)jbase * 256, &sVb[0][0], wave, lane);

    for (int jt = 0; jt < chunkKeys; jt += 64) {
        asm volatile("s_waitcnt vmcnt(0)" ::: "memory");
        __builtin_amdgcn_s_barrier();
        __builtin_amdgcn_sched_barrier(0);
        stage_tile(Kz + (size_t)(jbase + jt + 32) * 256, &sKb[1][0], wave, lane);
        stage_tile(Vz + (size_t)(jbase + jt + 32) * 256, &sVb[1][0], wave, lane);
        __builtin_amdgcn_sched_barrier(0);
        attn_tile(&sKb[0][0], &sVb[0][0], sP[wave], qf,
                  maskG, Fz, transposed, R0, jbase + jt,
                  lane, wave, col, quad, o, m, l);

        asm volatile("s_waitcnt vmcnt(0)" ::: "memory");
        __builtin_amdgcn_s_barrier();
        __builtin_amdgcn_sched_barrier(0);
        if (jt + 64 < chunkKeys) {
            stage_tile(Kz + (size_t)(jbase + jt + 64) * 256, &sKb[0][0], wave, lane);
            stage_tile(Vz + (size_t)(jbase + jt + 64) * 256, &sVb[0][0], wave, lane);
        }
        __builtin_amdgcn_sched_barrier(0);
        attn_tile(&sKb[1][0], &sVb[1][0], sP[wave], qf,
                  maskG, Fz, transposed, R0, jbase + jt + 32,
                  lane, wave, col, quad, o, m, l);
    }

    #pragma unroll
    for (int r = 0; r < 4; ++r) {
        #pragma unroll
        for (int off = 1; off < 16; off <<= 1)
            l[r] += __shfl_xor(l[r], off);
    }

    #pragma unroll
    for (int dt = 0; dt < 16; ++dt)
        #pragma unroll
        for (int r = 0; r < 4; ++r) {
            const int row = R0 + wave * 16 + quad * 4 + r;
            PO[((size_t)split * M + row) * HD + dt * 16 + col] = o[dt][r];
        }
    if (col == 0) {
        #pragma unroll
        for (int r = 0; r < 4; ++r) {
            const int row = R0 + wave * 16 + quad * 4 + r;
            PM[(size_t)split * M + row] = m[r];
            PL[(size_t)split * M + row] = l[r];
        }
    }
}

// ---------------------------------------------------------------------------
__global__ void attn_combine(
    const float* __restrict__ PO, const float* __restrict__ PM,
    const float* __restrict__ PL, __hip_bfloat16* __restrict__ Out,
    int M, int nchunks)
{
    const int idx = blockIdx.x * 256 + threadIdx.x;
    const int row = idx >> 8;
    float mmax = -INFINITY;
    for (int c = 0; c < nchunks; ++c) mmax = fmaxf(mmax, PM[(size_t)c * M + row]);
    float denom = 0.f, acc = 0.f;
    for (int c = 0; c < nchunks; ++c) {
        const float w = __expf(PM[(size_t)c * M + row] - mmax);
        denom += PL[(size_t)c * M + row] * w;
        acc   += PO[(size_t)c * M * HD + idx] * w;
    }
    Out[idx] = __float2bfloat16(acc / denom);
}

// ---------------------------------------------------------------------------
// Merged coordinate outputs (lig + rec).
__global__ void coords_all(
    const float* __restrict__ cL, const float* __restrict__ ocL,
    const float* __restrict__ xL, const float* __restrict__ nL,
    float* __restrict__ oL,
    const float* __restrict__ cR, const float* __restrict__ ocR,
    const float* __restrict__ xR, const float* __restrict__ nR,
    float* __restrict__ oR)
{
    int i = blockIdx.x * 256 + threadIdx.x;
    if (i < N_LIG * 3) {
        const int node = i / 3;
        const float inv = 1.f / fmaxf(nL[node], 1.f);
        oL[i] = 0.25f * ocL[i] + 0.75f * cL[i] + xL[i] * inv;
    } else {
        i -= N_LIG * 3;
        if (i >= N_REC * 3) return;
        const int node = i / 3;
        const float inv = 1.f / fmaxf(nR[node], 1.f);
        oR[i] = 0.25f * ocR[i] + 0.75f * cR[i] + xR[i] * inv;
    }
}

// ---------------------------------------------------------------------------
extern "C" void kernel_launch(void* const* d_in, const int* in_sizes, int n_in,
                              void* d_out, int out_size, void* d_ws, size_t ws_size,
                              hipStream_t stream)
{
    const float* coords_lig = (const float*)d_in[0];
    const float* h_lig      = (const float*)d_in[1];
    const float* orig_lig   = (const float*)d_in[2];
    const float* origc_lig  = (const float*)d_in[3];
    const float* coords_rec = (const float*)d_in[4];
    const float* h_rec      = (const float*)d_in[5];
    const float* orig_rec   = (const float*)d_in[6];
    const float* origc_rec  = (const float*)d_in[7];
    const float* mask       = (const float*)d_in[8];
    const float* lig_ef     = (const float*)d_in[9];
    const float* rec_ef     = (const float*)d_in[10];
    const int* lig_src = (const int*)d_in[11];
    const int* lig_dst = (const int*)d_in[12];
    const int* rec_src = (const int*)d_in[13];
    const int* rec_dst = (const int*)d_in[14];
    const float* le_w1 = (const float*)d_in[15];
    const float* le_b1 = (const float*)d_in[16];
    const float* le_w2 = (const float*)d_in[17];
    const float* le_b2 = (const float*)d_in[18];
    const float* re_w1 = (const float*)d_in[19];
    const float* re_b1 = (const float*)d_in[20];
    const float* re_w2 = (const float*)d_in[21];
    const float* re_b2 = (const float*)d_in[22];
    const float* aql_w = (const float*)d_in[23];
    const float* akl_w = (const float*)d_in[24];
    const float* avl_w = (const float*)d_in[25];
    const float* aqr_w = (const float*)d_in[26];
    const float* akr_w = (const float*)d_in[27];
    const float* avr_w = (const float*)d_in[28];
    const float* nl_w1 = (const float*)d_in[29];
    const float* nl_b1 = (const float*)d_in[30];
    const float* nl_w2 = (const float*)d_in[31];
    const float* nl_b2 = (const float*)d_in[32];
    const float* nr_w1 = (const float*)d_in[33];
    const float* nr_b1 = (const float*)d_in[34];
    const float* nr_w2 = (const float*)d_in[35];
    const float* nr_b2 = (const float*)d_in[36];
    const float* cl_w1 = (const float*)d_in[37];
    const float* cl_b1 = (const float*)d_in[38];
    const float* cl_w2 = (const float*)d_in[39];
    const float* cl_b2 = (const float*)d_in[40];
    const float* cr_w1 = (const float*)d_in[41];
    const float* cr_b1 = (const float*)d_in[42];
    const float* cr_w2 = (const float*)d_in[43];
    const float* cr_b2 = (const float*)d_in[44];

    float* out = (float*)d_out;
    float* wsf = (float*)d_ws;

    // ---- fp32 accumulator + CSR + mask-flag zone ----
    const size_t AGGRL = 0;
    const size_t AGGRR = AGGRL + (size_t)N_LIG * HD;
    const size_t CNTL  = AGGRR + (size_t)N_REC * HD;
    const size_t CNTR  = CNTL + N_LIG;
    const size_t XSUML = CNTR + N_REC;
    const size_t XSUMR = XSUML + (size_t)N_LIG * 3;
    const size_t HISTL = XSUMR + (size_t)N_REC * 3;
    const size_t CURL  = HISTL + N_LIG;
    const size_t HISTR = CURL + N_LIG;
    const size_t CURR  = HISTR + N_REC;
    const size_t FLAGS = CURR + N_REC;
    const size_t ZEND  = FLAGS + (size_t)(N_LIG / 32) * FCOLS;
    const size_t ELISTL = ZEND;
    const size_t ELISTR = ELISTL + E_LIG_N;
    const size_t FEND   = ELISTR + E_REC_N;

    // ---- bf16 zone ----
    __hip_bfloat16* wsb = (__hip_bfloat16*)(wsf + FEND);
    const size_t QL  = 0;
    const size_t KL  = QL + (size_t)N_LIG * HD;
    const size_t VL  = KL + (size_t)N_LIG * HD;
    const size_t QR  = VL + (size_t)N_LIG * HD;
    const size_t KR  = QR + (size_t)N_REC * HD;
    const size_t VR  = KR + (size_t)N_REC * HD;
    const size_t CRL = VR + (size_t)N_REC * HD;
    const size_t CRR = CRL + (size_t)N_LIG * HD;
    const size_t KZL = CRR + (size_t)N_REC * HD;
    const size_t VZL = KZL + (size_t)N_LIG * HD;
    const size_t KZR = VZL + (size_t)N_LIG * HD;
    const size_t VZR = KZR + (size_t)N_REC * HD;
    const size_t EW1SZ = (size_t)16 * 17 * 512;
    const size_t KW256 = (size_t)16 * 8 * 512;
    const size_t NW1SZ = (size_t)16 * 18 * 512;
    const size_t SW_EL1 = VZR + (size_t)N_REC * HD;
    const size_t SW_EL2 = SW_EL1 + EW1SZ;
    const size_t SW_EC1 = SW_EL2 + KW256;
    const size_t SW_NL1 = SW_EC1 + KW256;
    const size_t SW_NL2 = SW_NL1 + NW1SZ;
    const size_t SW_ER1 = SW_NL2 + KW256;
    const size_t SW_ER2 = SW_ER1 + EW1SZ;
    const size_t SW_EC1R = SW_ER2 + KW256;
    const size_t SW_NR1 = SW_EC1R + KW256;
    const size_t SW_NR2 = SW_NR1 + NW1SZ;
    const size_t SW_PQL = SW_NR2 + KW256;
    const size_t SW_PKL = SW_PQL + KW256;
    const size_t SW_PVL = SW_PKL + KW256;
    const size_t SW_PQR = SW_PVL + KW256;
    const size_t SW_PKR = SW_PQR + KW256;
    const size_t SW_PVR = SW_PKR + KW256;
    const size_t HB_L  = SW_PVR + KW256;
    const size_t HB_R  = HB_L + (size_t)N_LIG * HD;
    const size_t EFB_L = HB_R + (size_t)N_REC * HD;
    const size_t EFB_R = EFB_L + (size_t)E_LIG_N * EFD;
    const size_t BF_END = EFB_R + (size_t)E_REC_N * EFD;

    // ---- split-K partial zone (fp32), dynamic splits ----
    float* wsp = (float*)(wsb + ((BF_END + 1) & ~(size_t)1));
    const size_t baseBytes = (size_t)((char*)wsp - (char*)d_ws);
    int SL = 16, SR = 4;
    {
        const size_t poElems16 = (size_t)16 * N_LIG * HD;
        const size_t need16 = baseBytes +
            (poElems16 + 2 * (size_t)16 * N_LIG) * sizeof(float);
        if (ws_size < need16) { SL = 8; SR = 2; }
    }
    const size_t PO_ = 0;
    const size_t PM_ = PO_ + (size_t)SL * N_LIG * HD;
    const size_t PL_ = PM_ + (size_t)SL * N_LIG;

    const size_t O_XL = 0;
    const size_t O_HL = O_XL + (size_t)N_LIG * 3;
    const size_t O_XR = O_HL + (size_t)N_LIG * HD;
    const size_t O_HR = O_XR + (size_t)N_REC * 3;

    // 1) zero accumulators + CSR hist/cursors + mask flags
    zero_kernel<<<((int)ZEND + 255) / 256, 256, 0, stream>>>(wsf, (int)ZEND);

    // 1a) mask flag scan
    scanmask_kernel<<<(N_LIG * (N_REC / 16)) / 256, 256, 0, stream>>>(
        mask, (int*)(wsf + FLAGS));

    // 1b) fp32 -> bf16 blobs (merged: h_lig, h_rec, lig_ef, rec_ef)
    {
        F2bJobs J;
        J.src[0] = h_lig;  J.dst[0] = wsb + HB_L;  J.n8[0] = N_LIG * HD / 8;
        J.src[1] = h_rec;  J.dst[1] = wsb + HB_R;  J.n8[1] = N_REC * HD / 8;
        J.src[2] = lig_ef; J.dst[2] = wsb + EFB_L; J.n8[2] = E_LIG_N * EFD / 8;
        J.src[3] = rec_ef; J.dst[3] = wsb + EFB_R; J.n8[3] = E_REC_N * EFD / 8;
        int b = 0;
        for (int k = 0; k < 4; ++k) { J.blk0[k] = b; b += (J.n8[k] + 255) / 256; }
        J.blk0[4] = b;
        f2b_all<<<b, 256, 0, stream>>>(J);
    }

    // 1c) CSR build (merged hist / scan / scatter)
    hist_all<<<E_LIG_N / 256 + E_REC_N / 256, 256, 0, stream>>>(
        lig_dst, (int*)(wsf + HISTL), rec_dst, (int*)(wsf + HISTR),
        E_LIG_N / 256, E_LIG_N, E_REC_N);
    scan_all<<<2, 256, 0, stream>>>(
        (int*)(wsf + HISTL), (int*)(wsf + CURL), wsf + CNTL,
        (int*)(wsf + HISTR), (int*)(wsf + CURR), wsf + CNTR);
    scatter_all<<<E_LIG_N / 256 + E_REC_N / 256, 256, 0, stream>>>(
        lig_dst, (int*)(wsf + CURL), (int*)(wsf + ELISTL),
        rec_dst, (int*)(wsf + CURR), (int*)(wsf + ELISTR),
        E_LIG_N / 256, E_LIG_N, E_REC_N);

    // 2) weight swizzles (merged: 16 jobs, one dispatch)
    {
        SwzJobs J;
        const float* srcs[NSWZ] = { le_w1, le_w2, cl_w1, nl_w1, nl_w2,
                                    re_w1, re_w2, cr_w1, nr_w1, nr_w2,
                                    aql_w, akl_w, avl_w, aqr_w, akr_w, avr_w };
        __hip_bfloat16* dsts[NSWZ] = {
            wsb + SW_EL1, wsb + SW_EL2, wsb + SW_EC1, wsb + SW_NL1, wsb + SW_NL2,
            wsb + SW_ER1, wsb + SW_ER2, wsb + SW_EC1R, wsb + SW_NR1, wsb + SW_NR2,
            wsb + SW_PQL, wsb + SW_PKL, wsb + SW_PVL, wsb + SW_PQR, wsb + SW_PKR,
            wsb + SW_PVR };
        const int Ks[NSWZ]  = { EIN, 256, 256, 576, 256,
                                EIN, 256, 256, 576, 256,
                                256, 256, 256, 256, 256, 256 };
        const int KSs[NSWZ] = { 17, 8, 8, 18, 8,
                                17, 8, 8, 18, 8,
                                8, 8, 8, 8, 8, 8 };
        int b = 0;
        for (int k = 0; k < NSWZ; ++k) {
            J.src[k] = srcs[k]; J.dst[k] = dsts[k];
            J.K[k] = Ks[k]; J.KS[k] = KSs[k];
            J.blk0[k] = b; b += 16 * KSs[k];
        }
        J.blk0[NSWZ] = b;
        wt_swz_all<<<b, 256, 0, stream>>>(J);
    }

    // 3) edge MFMA (merged lig+rec)
    {
        EdgeParams L = { coords_lig, wsb + HB_L, wsb + EFB_L,
                         lig_src, lig_dst, (const int*)(wsf + ELISTL),
                         wsb + SW_EL1, le_b1, wsb + SW_EL2, le_b2,
                         wsb + SW_EC1, cl_b1, cl_w2, cl_b2,
                         wsf + AGGRL, wsf + XSUML };
        EdgeParams R = { coords_rec, wsb + HB_R, wsb + EFB_R,
                         rec_src, rec_dst, (const int*)(wsf + ELISTR),
                         wsb + SW_ER1, re_b1, wsb + SW_ER2, re_b2,
                         wsb + SW_EC1R, cr_b1, cr_w2, cr_b2,
                         wsf + AGGRR, wsf + XSUMR };
        edge_mfma<<<E_LIG_N / 32 + E_REC_N / 32, 256, 0, stream>>>(
            L, R, E_LIG_N / 32);
    }

    // 4) fused q/k/v projections (merged lig+rec)
    {
        QkvParams L = { wsb + HB_L, wsb + SW_PQL, wsb + SW_PKL, wsb + SW_PVL,
                        wsb + QL, wsb + KZL, wsb + VZL };
        QkvParams R = { wsb + HB_R, wsb + SW_PQR, wsb + SW_PKR, wsb + SW_PVR,
                        wsb + QR, wsb + KZR, wsb + VZR };
        qkv_proj<<<N_LIG / 32 + N_REC / 32, 256, 0, stream>>>(
            L, R, N_LIG / 32);
    }

    // 5) MFMA flash attention, split-K + combine (PO zone reused -> serial)
    {
        dim3 gl(N_LIG / 128, SL);
        attn_mfma<<<gl, 512, 0, stream>>>(wsb + QL, wsb + KZR, wsb + VZR, mask,
                                          (const int*)(wsf + FLAGS),
                                          wsp + PO_, wsp + PM_, wsp + PL_,
                                          N_LIG, N_REC / SL, 0);
        attn_combine<<<N_LIG, 256, 0, stream>>>(
            wsp + PO_, wsp + PM_, wsp + PL_, wsb + CRL, N_LIG, SL);

        dim3 gr(N_REC / 128, SR);
        attn_mfma<<<gr, 512, 0, stream>>>(wsb + QR, wsb + KZL, wsb + VZL, mask,
                                          (const int*)(wsf + FLAGS),
                                          wsp + PO_, wsp + PM_, wsp + PL_,
                                          N_REC, N_LIG / SR, 1);
        attn_combine<<<N_REC, 256, 0, stream>>>(
            wsp + PO_, wsp + PM_, wsp + PL_, wsb + CRR, N_REC, SR);
    }

    // 6) coordinate outputs (merged)
    coords_all<<<(N_LIG * 3 + N_REC * 3 + 255) / 256, 256, 0, stream>>>(
        coords_lig, origc_lig, wsf + XSUML, wsf + CNTL, out + O_XL,
        coords_rec, origc_rec, wsf + XSUMR, wsf + CNTR, out + O_XR);

    // 7) node MFMA (merged lig+rec)
    {
        NodeParams L = { wsf + AGGRL, wsf + CNTL, wsb + CRL, orig_lig, h_lig,
                         wsb + SW_NL1, nl_b1, wsb + SW_NL2, nl_b2, out + O_HL };
        NodeParams R = { wsf + AGGRR, wsf + CNTR, wsb + CRR, orig_rec, h_rec,
                         wsb + SW_NR1, nr_b1, wsb + SW_NR2, nr_b2, out + O_HR };
        node_mfma<<<N_LIG / 32 + N_REC / 32, 256, 0, stream>>>(
            L, R, N_LIG / 32);
    }

    (void)in_sizes; (void)n_in; (void)out_size;
}